// Round 13
// baseline (596.225 us; speedup 1.0000x reference)
//
#include <hip/hip_runtime.h>
#include <hip/hip_bf16.h>

#define N_DRUG 20000
#define N_DIS  20000
#define E_G    320000
#define BATCH  4096
#define N_MOL  65536
#define E_MOL  262144
#define DIN    128
#define DH     256
#define NF     9
#define NV     128
#define SPAN_P 20096           // 157 * 128 (pad per graph)
#define NP     40192           // 2 * SPAN_P

typedef short s16x8 __attribute__((ext_vector_type(8)));
typedef unsigned short u16x8 __attribute__((ext_vector_type(8)));
typedef float f32x4 __attribute__((ext_vector_type(4)));

typedef __attribute__((address_space(1))) const void gvoid_t;
typedef __attribute__((address_space(3))) void lvoid_t;

__device__ __forceinline__ float bfu2f(unsigned short u) {
    return __uint_as_float(((unsigned int)u) << 16);
}
__device__ __forceinline__ unsigned short f2bfu(float f) {
    __hip_bfloat16 b = __float2bfloat16(f);
    return *reinterpret_cast<unsigned short*>(&b);
}
__device__ __forceinline__ void atomAddF(float* p, float v) { unsafeAtomicAdd(p, v); }

// ---------------- misc ----------------
__global__ void k_sentinel(float* out, int n, float v) {
    int i = blockIdx.x * 256 + threadIdx.x;
    if (i < n) out[i] = v;
}

// merged drug+dis cast into padded bf16 [NP][128]; pad rows zero
__global__ void k_cast_pair(const float* __restrict__ a, const float* __restrict__ b,
                            unsigned short* __restrict__ out) {
    int i4 = blockIdx.x * 256 + threadIdx.x;      // NP*32 float4 slots
    if (i4 >= NP * 32) return;
    int row = i4 >> 5, c4 = (i4 & 31) * 4;
    float4 v = {0.f, 0.f, 0.f, 0.f};
    if (row < N_DRUG) v = *reinterpret_cast<const float4*>(a + (size_t)row * 128 + c4);
    else if (row >= SPAN_P && row < SPAN_P + N_DIS)
        v = *reinterpret_cast<const float4*>(b + (size_t)(row - SPAN_P) * 128 + c4);
    ushort4 o = {f2bfu(v.x), f2bfu(v.y), f2bfu(v.z), f2bfu(v.w)};
    *reinterpret_cast<ushort4*>(out + (size_t)row * 128 + c4) = o;
}

// 3 weight transposes: W[K][N] f32 -> Wt[N][K] bf16
__global__ void k_wcast3(const float* __restrict__ W0, const float* __restrict__ W1,
                         const float* __restrict__ W2,
                         unsigned short* __restrict__ T0, unsigned short* __restrict__ T1,
                         unsigned short* __restrict__ T2, int Cin) {
    int i = blockIdx.x * 256 + threadIdx.x;
    int t0 = Cin * 256, t1 = 256 * 256, t2 = 256 * 128;
    if (i < t0) {
        int k = i / 256, c = i - k * 256;
        T0[(size_t)c * Cin + k] = f2bfu(W0[i]);
    } else if (i < t0 + t1) {
        int e = i - t0;
        int k = e / 256, c = e - k * 256;
        T1[(size_t)c * 256 + k] = f2bfu(W1[e]);
    } else if (i < t0 + t1 + t2) {
        int e = i - t0 - t1;
        int k = e / 128, c = e - k * 128;
        T2[(size_t)c * 256 + k] = f2bfu(W2[e]);
    }
}

// ---------------- degree ----------------
__global__ void k_count(const int* __restrict__ dst, int* __restrict__ cnt, int E) {
    int e = blockIdx.x * 256 + threadIdx.x;
    if (e < E) atomicAdd(&cnt[dst[e]], 1);
}
// merged two-graph count (graph1 offset +SPAN_P)
__global__ void k_count2(const int* __restrict__ eiA, const int* __restrict__ eiB,
                         int* __restrict__ cnt) {
    int e = blockIdx.x * 256 + threadIdx.x;
    if (e >= 2 * E_G) return;
    int d = (e < E_G) ? eiA[E_G + e] : eiB[E_G + e - E_G] + SPAN_P;
    atomicAdd(&cnt[d], 1);
}

// ---------------- CSR build ----------------
__global__ void k_scan1(const int* __restrict__ cnt, int* __restrict__ rowStart,
                        int* __restrict__ bsum, float* __restrict__ dinv, int n) {
    __shared__ int sh[256];
    int i = blockIdx.x * 256 + threadIdx.x;
    int v = (i < n) ? cnt[i] : 0;
    if (i < n) dinv[i] = rsqrtf(1.0f + (float)v);
    sh[threadIdx.x] = v;
    __syncthreads();
    for (int off = 1; off < 256; off <<= 1) {
        int t = (threadIdx.x >= off) ? sh[threadIdx.x - off] : 0;
        __syncthreads();
        sh[threadIdx.x] += t;
        __syncthreads();
    }
    if (i < n) rowStart[i] = sh[threadIdx.x] - v;
    if (threadIdx.x == 255) bsum[blockIdx.x] = sh[255];
}
// scan3 with folded bsum-scan
__global__ void k_scan3(int* __restrict__ rowStart, int* __restrict__ cursor,
                        const int* __restrict__ bsum, int n, int nb, int E) {
    __shared__ int sh[256];
    int t = threadIdx.x;
    int v = (t < nb) ? bsum[t] : 0;
    sh[t] = v;
    __syncthreads();
    for (int off = 1; off < 256; off <<= 1) {
        int u = (t >= off) ? sh[t - off] : 0;
        __syncthreads();
        sh[t] += u;
        __syncthreads();
    }
    int pre = (blockIdx.x == 0) ? 0 : sh[blockIdx.x - 1];
    int i = blockIdx.x * 256 + t;
    if (i < n) {
        int r = rowStart[i] + pre;
        rowStart[i] = r;
        cursor[i] = r;
    }
    if (i == 0) rowStart[n] = E;
}
// fill (src, edge weight) pairs
__global__ void k_fill(const int* __restrict__ src, const int* __restrict__ dst,
                       const float* __restrict__ dinv,
                       int* __restrict__ cursor, int2* __restrict__ csr2, int E) {
    int e = blockIdx.x * 256 + threadIdx.x;
    if (e < E) {
        int s = src[e], d = dst[e];
        int p = atomicAdd(&cursor[d], 1);
        csr2[p] = make_int2(s, __float_as_int(dinv[s] * dinv[d]));
    }
}
__global__ void k_fill2(const int* __restrict__ eiA, const int* __restrict__ eiB,
                        const float* __restrict__ dinv,
                        int* __restrict__ cursor, int2* __restrict__ csr2) {
    int e = blockIdx.x * 256 + threadIdx.x;
    if (e >= 2 * E_G) return;
    int s, d;
    if (e < E_G) { s = eiA[e]; d = eiA[E_G + e]; }
    else { s = eiB[e - E_G] + SPAN_P; d = eiB[E_G + e - E_G] + SPAN_P; }
    int p = atomicAdd(&cursor[d], 1);
    csr2[p] = make_int2(s, __float_as_int(dinv[s] * dinv[d]));
}

// ---------------- MFMA GEMM: double-buffered LDS, prefetch overlaps MFMA ----------------
// BATCHED: graph g = blockIdx.y / (SPAN/128); per-graph Bt / coef / bnbuf select.
// AFFINE: A' = relu(scale*A+shift) at fragment read. STATS: col sum/sumsq of acc.
template<int AFFINE, int STATS, int BATCHED>
__global__ __launch_bounds__(256) void k_gemm_mfma(const unsigned short* __restrict__ A,
                                                   const unsigned short* __restrict__ Bt0,
                                                   const unsigned short* __restrict__ Bt1,
                                                   const float* __restrict__ coef,
                                                   unsigned short* __restrict__ Cout,
                                                   float* __restrict__ bnbuf,
                                                   int Mloc, int SPAN, int K, int N) {
    __shared__ unsigned short Al[2][4][128][8];
    __shared__ unsigned short Bl[2][4][128][8];
    __shared__ float csc[256], csh[256];
    const int tid = threadIdx.x;
    const int bm = blockIdx.y * 128;
    const int bn = blockIdx.x * 128;
    int g, lbm;
    if (BATCHED) { int tpg = SPAN >> 7; g = (int)blockIdx.y / tpg; lbm = bm - g * SPAN; }
    else { g = 0; lbm = bm; }
    const unsigned short* Bt = g ? Bt1 : Bt0;
    const int w = tid >> 6, l = tid & 63;
    const int wrow = (w >> 1) * 64, wcol = (w & 1) * 64;
    const int kg = l >> 4, lr = l & 15;

    if (AFFINE) {
        for (int i = tid; i < K; i += 256) {
            csc[i] = coef[g * 512 + i];
            csh[i] = coef[g * 512 + 256 + i];
        }
    }
    if (lbm + 128 > Mloc) {  // tail tile: pre-zero BOTH A buffers (pad rows never restaged)
        for (int s = tid; s < 1024; s += 256) {
            u16x8 z = {0, 0, 0, 0, 0, 0, 0, 0};
            *reinterpret_cast<u16x8*>(&Al[0][0][0][0] + s * 8) = z;
        }
    }
    __syncthreads();

    auto stage = [&](int buf, int k0) {
#pragma unroll
        for (int i = 0; i < 4; ++i) {
            int id = w * 4 + i;
            int koff = (id >> 1) & 3;
            int half = id & 1;
            int row = half * 64 + l;
            if (id < 8) {
                if (lbm + row < Mloc) {
                    const unsigned short* gs = A + (size_t)(bm + row) * K + k0 + koff * 8;
                    __builtin_amdgcn_global_load_lds((gvoid_t*)gs,
                        (lvoid_t*)&Al[buf][koff][half * 64][0], 16, 0, 0);
                }
            } else {
                const unsigned short* gs = Bt + (size_t)(bn + row) * K + k0 + koff * 8;
                __builtin_amdgcn_global_load_lds((gvoid_t*)gs,
                    (lvoid_t*)&Bl[buf][koff][half * 64][0], 16, 0, 0);
            }
        }
    };

    f32x4 acc[4][4];
#pragma unroll
    for (int fm = 0; fm < 4; ++fm)
#pragma unroll
        for (int fn = 0; fn < 4; ++fn) acc[fm][fn] = f32x4{0.f, 0.f, 0.f, 0.f};

    stage(0, 0);
    __syncthreads();                       // drains vmcnt(0): buf0 ready
    int nk = K >> 5;
    for (int t = 0; t < nk; ++t) {
        int cur = t & 1;
        if (t + 1 < nk) stage(cur ^ 1, (t + 1) * 32);   // prefetch overlaps MFMA below
        s16x8 a[4], b[4];
#pragma unroll
        for (int fm = 0; fm < 4; ++fm)
            a[fm] = *reinterpret_cast<const s16x8*>(&Al[cur][kg][wrow + fm * 16 + lr][0]);
        if (AFFINE) {
            int k0 = t * 32;
            float sc[8], sh[8];
#pragma unroll
            for (int e = 0; e < 8; ++e) {
                sc[e] = csc[k0 + kg * 8 + e];
                sh[e] = csh[k0 + kg * 8 + e];
            }
#pragma unroll
            for (int fm = 0; fm < 4; ++fm)
#pragma unroll
                for (int e = 0; e < 8; ++e) {
                    float f = bfu2f((unsigned short)a[fm][e]);
                    a[fm][e] = (short)f2bfu(fmaxf(fmaf(sc[e], f, sh[e]), 0.f));
                }
        }
#pragma unroll
        for (int fn = 0; fn < 4; ++fn)
            b[fn] = *reinterpret_cast<const s16x8*>(&Bl[cur][kg][wcol + fn * 16 + lr][0]);
#pragma unroll
        for (int fm = 0; fm < 4; ++fm)
#pragma unroll
            for (int fn = 0; fn < 4; ++fn)
                acc[fm][fn] = __builtin_amdgcn_mfma_f32_16x16x32_bf16(a[fm], b[fn], acc[fm][fn], 0, 0, 0);
        __syncthreads();                  // vmcnt(0) drain covers the prefetch; buf[cur^1] ready
    }
    // C/D layout: col = lane&15, row = (lane>>4)*4 + reg. Pad rows write acc=0.
#pragma unroll
    for (int fm = 0; fm < 4; ++fm)
#pragma unroll
        for (int r = 0; r < 4; ++r) {
            int row = bm + wrow + fm * 16 + kg * 4 + r;
#pragma unroll
            for (int fn = 0; fn < 4; ++fn) {
                int col = bn + wcol + fn * 16 + lr;
                Cout[(size_t)row * N + col] = f2bfu(acc[fm][fn][r]);
            }
        }
    if constexpr (STATS) {
        __shared__ float colS[128], colQ[128];
        if (tid < 128) { colS[tid] = 0.f; colQ[tid] = 0.f; }
        __syncthreads();
#pragma unroll
        for (int fn = 0; fn < 4; ++fn) {
            float s = 0.f, q = 0.f;
#pragma unroll
            for (int fm = 0; fm < 4; ++fm)
#pragma unroll
                for (int r = 0; r < 4; ++r) {
                    float v = acc[fm][fn][r];
                    s += v; q += v * v;
                }
            int cl = (w & 1) * 64 + fn * 16 + lr;
            atomicAdd(&colS[cl], s);
            atomicAdd(&colQ[cl], q);
        }
        __syncthreads();
        if (tid < 128) {
            atomAddF(&bnbuf[g * 512 + bn + tid], colS[tid]);
            atomAddF(&bnbuf[g * 512 + 256 + bn + tid], colQ[tid]);
        }
    }
}

// ---------------- CSR gather: 32-lane row groups, 8 rows/block, 4-deep unroll ----------------
template<int C, int BIAS, int OUTBF>
__global__ __launch_bounds__(256) void k_gather(const unsigned short* __restrict__ h,
                                                const float* __restrict__ dinv,
                                                const float* __restrict__ bias0,
                                                const float* __restrict__ bias1,
                                                const int2* __restrict__ csr2,
                                                const int* __restrict__ rowStart,
                                                void* __restrict__ outv, int n, int SPAN) {
    constexpr int PL = C / 32;
    int row = blockIdx.x * 8 + (threadIdx.x >> 5);
    if (row >= n) return;
    int lane = threadIdx.x & 31;
    int c0 = lane * PL;

    auto loadRow = [&](int r, float* d) {
        const unsigned short* base = h + (size_t)r * C + c0;
        if constexpr (PL == 8) {
            u16x8 v = *reinterpret_cast<const u16x8*>(base);
#pragma unroll
            for (int e = 0; e < 8; ++e) d[e] = bfu2f((unsigned short)v[e]);
        } else {
            ushort4 v = *reinterpret_cast<const ushort4*>(base);
            d[0] = bfu2f(v.x); d[1] = bfu2f(v.y); d[2] = bfu2f(v.z); d[3] = bfu2f(v.w);
        }
    };

    float dd = dinv[row], ws = dd * dd;
    int beg = rowStart[row], end = rowStart[row + 1];
    float a0[PL], a1[PL], a2[PL], a3[PL], t0[PL], t1[PL], t2[PL], t3[PL];
    loadRow(row, t0);
#pragma unroll
    for (int p = 0; p < PL; ++p) { a0[p] = t0[p] * ws; a1[p] = 0.f; a2[p] = 0.f; a3[p] = 0.f; }

    int j = beg;
    for (; j + 4 <= end; j += 4) {
        int2 e0 = csr2[j], e1 = csr2[j + 1], e2 = csr2[j + 2], e3 = csr2[j + 3];
        float w0 = __int_as_float(e0.y), w1 = __int_as_float(e1.y);
        float w2 = __int_as_float(e2.y), w3 = __int_as_float(e3.y);
        loadRow(e0.x, t0); loadRow(e1.x, t1); loadRow(e2.x, t2); loadRow(e3.x, t3);
#pragma unroll
        for (int p = 0; p < PL; ++p) {
            a0[p] += w0 * t0[p]; a1[p] += w1 * t1[p];
            a2[p] += w2 * t2[p]; a3[p] += w3 * t3[p];
        }
    }
    for (; j < end; ++j) {
        int2 e0 = csr2[j];
        float w = __int_as_float(e0.y);
        loadRow(e0.x, t0);
#pragma unroll
        for (int p = 0; p < PL; ++p) a0[p] += w * t0[p];
    }
    const float* bp = (BIAS && row >= SPAN) ? bias1 : bias0;
#pragma unroll
    for (int p = 0; p < PL; ++p) {
        a0[p] += (a1[p] + a2[p]) + a3[p];
        if (BIAS) a0[p] += bp[c0 + p];
    }
    if constexpr (OUTBF) {
        unsigned short* o = (unsigned short*)outv + (size_t)row * C + c0;
        if constexpr (PL == 8) {
            u16x8 ov;
#pragma unroll
            for (int e = 0; e < 8; ++e) ov[e] = f2bfu(a0[e]);
            *reinterpret_cast<u16x8*>(o) = ov;
        } else {
            ushort4 ov = {f2bfu(a0[0]), f2bfu(a0[1]), f2bfu(a0[2]), f2bfu(a0[3])};
            *reinterpret_cast<ushort4*>(o) = ov;
        }
    } else {
        float* o = (float*)outv + (size_t)row * C + c0;
#pragma unroll
        for (int q = 0; q < PL / 4; ++q) {
            float4 ov = {a0[q * 4 + 0], a0[q * 4 + 1], a0[q * 4 + 2], a0[q * 4 + 3]};
            *reinterpret_cast<float4*>(o + q * 4) = ov;
        }
    }
}

// ---------------- BatchNorm stats: per-graph (blockIdx.y), grid-stride, u16x8 ----------------
__global__ __launch_bounds__(256) void k_bn_stats_bf(const unsigned short* __restrict__ x,
                                                     float* __restrict__ bnbuf, int SPAN) {
    __shared__ float smS[8][256];
    __shared__ float smQ[8][256];
    int t = threadIdx.x;
    int y = blockIdx.y;
    int g = t >> 5;
    int lane = t & 31;
    int c0 = lane * 8;
    float s[8], q[8];
#pragma unroll
    for (int e = 0; e < 8; ++e) { s[e] = 0.f; q[e] = 0.f; }
    int stride = gridDim.x * 8;
    for (int r = blockIdx.x * 8 + g; r < SPAN; r += stride) {
        u16x8 v = *reinterpret_cast<const u16x8*>(x + ((size_t)y * SPAN + r) * 256 + c0);
#pragma unroll
        for (int e = 0; e < 8; ++e) {
            float f = bfu2f((unsigned short)v[e]);
            s[e] += f; q[e] += f * f;
        }
    }
#pragma unroll
    for (int e = 0; e < 8; ++e) { smS[g][c0 + e] = s[e]; smQ[g][c0 + e] = q[e]; }
    __syncthreads();
    float S = 0.f, Q = 0.f;
#pragma unroll
    for (int g2 = 0; g2 < 8; ++g2) { S += smS[g2][t]; Q += smQ[g2][t]; }
    atomAddF(&bnbuf[y * 512 + t], S);
    atomAddF(&bnbuf[y * 512 + 256 + t], Q);
}

// coef[g][j]=gamma*rstd, coef[g][256+j]=beta-mean*scale; self-zeroes bnbuf set
__global__ void k_bn_coef(float* __restrict__ bnbuf,
                          const float* __restrict__ gA, const float* __restrict__ beA,
                          const float* __restrict__ gB, const float* __restrict__ beB,
                          float* __restrict__ coef, float invN) {
    int gg = blockIdx.x;
    int j = threadIdx.x;
    const float* gp = gg ? gB : gA;
    const float* bp = gg ? beB : beA;
    float* s = bnbuf + gg * 512;
    float m = s[j] * invN;
    float v = s[256 + j] * invN - m * m;
    float r = rsqrtf(fmaxf(v, 0.f) + 1e-5f);
    float sc = gp[j] * r;
    coef[gg * 512 + j] = sc;
    coef[gg * 512 + 256 + j] = bp[j] - m * sc;
    s[j] = 0.f;
    s[256 + j] = 0.f;
}

// ---------------- atom encoder ----------------
__global__ __launch_bounds__(256) void k_atom_enc(const int* __restrict__ mol_x,
                                                  const float* __restrict__ emb,
                                                  unsigned short* __restrict__ h) {
    __shared__ int sidx[4][NF];
    int t = threadIdx.x;
    if (t < 4 * NF) sidx[t / NF][t % NF] = mol_x[(blockIdx.x * 4 + t / NF) * NF + t % NF];
    __syncthreads();
    int r = t >> 6, lane = t & 63;
    int c0 = lane * 4;
    int row = blockIdx.x * 4 + r;
    float4 s = {0.f, 0.f, 0.f, 0.f};
#pragma unroll
    for (int f = 0; f < NF; ++f) {
        const float4 v = *reinterpret_cast<const float4*>(emb + ((size_t)f * NV + sidx[r][f]) * DH + c0);
        s.x += v.x; s.y += v.y; s.z += v.z; s.w += v.w;
    }
    ushort4 ov = {f2bfu(s.x), f2bfu(s.y), f2bfu(s.z), f2bfu(s.w)};
    *reinterpret_cast<ushort4*>(h + (size_t)row * DH + c0) = ov;
}

// ---------------- segment pool ----------------
__global__ __launch_bounds__(128) void k_pool_seg(const unsigned short* __restrict__ mfeat,
                                                  const int* __restrict__ batch,
                                                  float* __restrict__ mpool) {
    __shared__ int sr[2];
    __shared__ float smS[8][128];
    int b = blockIdx.x, t = threadIdx.x;
    if (t < 2) {
        int target = b + t;
        int lo = 0, hi = N_MOL;
        while (lo < hi) {
            int mid = (lo + hi) >> 1;
            if (batch[mid] < target) lo = mid + 1; else hi = mid;
        }
        sr[t] = lo;
    }
    __syncthreads();
    int g = t >> 4;
    int lane = t & 15;
    int c0 = lane * 8;
    float s[8];
#pragma unroll
    for (int e = 0; e < 8; ++e) s[e] = 0.f;
    int e1 = sr[1];
    for (int i = sr[0] + g; i < e1; i += 8) {
        u16x8 v = *reinterpret_cast<const u16x8*>(mfeat + (size_t)i * 128 + c0);
#pragma unroll
        for (int e = 0; e < 8; ++e) s[e] += bfu2f((unsigned short)v[e]);
    }
#pragma unroll
    for (int e = 0; e < 8; ++e) smS[g][c0 + e] = s[e];
    __syncthreads();
    float S = 0.f;
#pragma unroll
    for (int g2 = 0; g2 < 8; ++g2) S += smS[g2][t];
    mpool[(size_t)b * 128 + t] = S;
}

// ---------------- head: conv1 ----------------
__global__ __launch_bounds__(64) void k_conv1(const float* __restrict__ dfeat,
                                              const float* __restrict__ mpool,
                                              const float* __restrict__ sfeat,
                                              const int* __restrict__ drug_idx,
                                              const int* __restrict__ dis_idx,
                                              const float* __restrict__ W,
                                              const float* __restrict__ bias,
                                              float* __restrict__ y1) {
    __shared__ float xs[3][128];
    __shared__ float w[54];
    __shared__ float bb[6];
    int b = blockIdx.x, t = threadIdx.x;
    int di = drug_idx[b], si = dis_idx[b];
    const float* r0 = dfeat + (size_t)di * 128;
    const float* r1 = mpool + (size_t)b * 128;
    const float* r2 = sfeat + (size_t)si * 128;
    xs[0][t] = r0[t]; xs[0][t + 64] = r0[t + 64];
    xs[1][t] = r1[t]; xs[1][t + 64] = r1[t + 64];
    xs[2][t] = r2[t]; xs[2][t + 64] = r2[t + 64];
    if (t < 54) w[t] = W[t];
    if (t < 6) bb[t] = bias[t];
    __syncthreads();
    int l0 = 2 * t, l1 = l0 + 1;
#pragma unroll
    for (int o = 0; o < 6; ++o) {
        float ya = bb[o], yb = bb[o];
#pragma unroll
        for (int i = 0; i < 3; ++i) {
            const float* wi = &w[(o * 3 + i) * 3];
            float xm1 = (l0 > 0) ? xs[i][l0 - 1] : 0.f;
            float x0 = xs[i][l0];
            float x1 = xs[i][l1];
            float x2 = (l1 < 127) ? xs[i][l1 + 1] : 0.f;
            ya += wi[0] * xm1 + wi[1] * x0 + wi[2] * x1;
            yb += wi[0] * x0 + wi[1] * x1 + wi[2] * x2;
        }
        y1[((size_t)b * 6 + o) * 64 + t] = fmaxf(ya, yb);
    }
}

// hb per 'which': [0..5]=sum [8..13]=sumsq [16..21]=mean [24..29]=rstd; grid (6,16)
__global__ __launch_bounds__(256) void k_head_stats(const float* __restrict__ y,
                                                    float* __restrict__ hb, int which, int L) {
    int o = blockIdx.x;
    int b0 = blockIdx.y * 256;
    int t = threadIdx.x;
    float s = 0.f, q = 0.f;
    int per = 256 * L;
    for (int idx = t; idx < per; idx += 256) {
        int b = b0 + idx / L;
        int l = idx - (idx / L) * L;
        float v = y[((size_t)b * 6 + o) * L + l];
        s += v; q += v * v;
    }
    __shared__ float sms[4], smq[4];
#pragma unroll
    for (int off = 32; off > 0; off >>= 1) {
        s += __shfl_down(s, off);
        q += __shfl_down(q, off);
    }
    if ((t & 63) == 0) { sms[t >> 6] = s; smq[t >> 6] = q; }
    __syncthreads();
    if (t == 0) {
        float S = 0.f, Q = 0.f;
        for (int i = 0; i < 4; ++i) { S += sms[i]; Q += smq[i]; }
        atomAddF(hb + which * 32 + o, S);
        atomAddF(hb + which * 32 + 8 + o, Q);
    }
}

__global__ void k_bn_fin(float* __restrict__ hb, int which, float invN) {
    int o = threadIdx.x;
    if (o >= 6) return;
    float* p = hb + which * 32;
    float m = p[o] * invN;
    float v = p[8 + o] * invN - m * m;
    p[16 + o] = m;
    p[24 + o] = rsqrtf(fmaxf(v, 0.f) + 1e-5f);
}

// ---------------- head: conv2 ----------------
__global__ __launch_bounds__(64) void k_conv2(const float* __restrict__ y1,
                                              const float* __restrict__ hb,
                                              const float* __restrict__ g1,
                                              const float* __restrict__ be1,
                                              const float* __restrict__ W,
                                              const float* __restrict__ bias,
                                              float* __restrict__ y2) {
    __shared__ float xs[6][64];
    __shared__ float w[108];
    __shared__ float bb[6];
    int b = blockIdx.x, t = threadIdx.x;
    const float* mean = hb + 16;
    const float* rstd = hb + 24;
    for (int idx = t; idx < 384; idx += 64) {
        int o = idx >> 6, l = idx & 63;
        float v = y1[((size_t)b * 6 + o) * 64 + l];
        v = g1[o] * (v - mean[o]) * rstd[o] + be1[o];
        xs[o][l] = fmaxf(v, 0.f);
    }
    for (int idx = t; idx < 108; idx += 64) w[idx] = W[idx];
    if (t < 6) bb[t] = bias[t];
    __syncthreads();
    if (t >= 32) return;
    int l0 = 2 * t, l1 = l0 + 1;
#pragma unroll
    for (int o = 0; o < 6; ++o) {
        float ya = bb[o], yb = bb[o];
#pragma unroll
        for (int i = 0; i < 6; ++i) {
            const float* wi = &w[(o * 6 + i) * 3];
            float xm1 = (l0 > 0) ? xs[i][l0 - 1] : 0.f;
            float x0 = xs[i][l0];
            float x1 = xs[i][l1];
            float x2 = (l1 < 63) ? xs[i][l1 + 1] : 0.f;
            ya += wi[0] * xm1 + wi[1] * x0 + wi[2] * x1;
            yb += wi[0] * x0 + wi[1] * x1 + wi[2] * x2;
        }
        y2[((size_t)b * 6 + o) * 32 + t] = fmaxf(ya, yb);
    }
}

// ---------------- head final ----------------
__global__ __launch_bounds__(128) void k_head(const float* __restrict__ y2,
                                              const float* __restrict__ hb,
                                              const float* __restrict__ g2,
                                              const float* __restrict__ be2,
                                              const float* __restrict__ l1W,
                                              const float* __restrict__ l1b,
                                              const float* __restrict__ l2W,
                                              const float* __restrict__ l2b,
                                              float* __restrict__ out) {
    __shared__ float fs[192];
    __shared__ float sm[2];
    int b = blockIdx.x, t = threadIdx.x;
    const float* mean = hb + 32 + 16;
    const float* rstd = hb + 32 + 24;
    for (int idx = t; idx < 192; idx += 128) {
        int o = idx >> 5, l = idx & 31;
        float v = y2[((size_t)b * 6 + o) * 32 + l];
        v = g2[o] * (v - mean[o]) * rstd[o] + be2[o];
        fs[idx] = fmaxf(v, 0.f);
    }
    __syncthreads();
    float h = l1b[t];
    for (int k = 0; k < 192; ++k)
        h += fs[k] * l1W[k * 128 + t];
    h = fmaxf(h, 0.f);
    float p = h * l2W[t];
#pragma unroll
    for (int off = 32; off > 0; off >>= 1) p += __shfl_down(p, off);
    if ((t & 63) == 0) sm[t >> 6] = p;
    __syncthreads();
    if (t == 0) out[b] = sm[0] + sm[1] + l2b[0];
}

extern "C" void kernel_launch(void* const* d_in, const int* in_sizes, int n_in,
                              void* d_out, int out_size, void* d_ws, size_t ws_size,
                              hipStream_t stream) {
    float* out = (float*)d_out;
    if (n_in != 52) { k_sentinel<<<16, 256, 0, stream>>>(out, out_size, -111.f); return; }
    if (in_sizes[0] != N_DRUG * DIN || in_sizes[29] != NF * NV * DH || in_sizes[48] != 192 * 128) {
        k_sentinel<<<16, 256, 0, stream>>>(out, out_size, -222.f); return;
    }

    char* w = (char*)d_ws;
    auto alloc = [&](size_t bytes) { char* p = w; w += (bytes + 255) & ~(size_t)255; return p; };
    unsigned short* xb    = (unsigned short*)alloc((size_t)N_MOL * 256 * 2);
    unsigned short* h_bf  = (unsigned short*)alloc((size_t)N_MOL * 256 * 2);
    unsigned short* xin   = (unsigned short*)alloc((size_t)N_MOL * 256 * 2);
    float* outDS = (float*)alloc((size_t)NP * 128 * 4);
    float* mpool = (float*)alloc((size_t)BATCH * 128 * 4);
    int*   cnt      = (int*)alloc((size_t)N_MOL * 4);
    float* dinv     = (float*)alloc((size_t)N_MOL * 4);
    int*   rowStart = (int*)alloc((size_t)(N_MOL + 1) * 4);
    int*   cursor   = (int*)alloc((size_t)N_MOL * 4);
    int2*  csr2     = (int2*)alloc((size_t)(2 * E_G) * 8);
    int*   bsum     = (int*)alloc(512 * 4);
    float* bnbuf    = (float*)alloc(1024 * 4);
    float* coef     = (float*)alloc(1024 * 4);
    unsigned short* wtA0 = (unsigned short*)alloc((size_t)256 * 256 * 2);
    unsigned short* wtA1 = (unsigned short*)alloc((size_t)256 * 256 * 2);
    unsigned short* wtA2 = (unsigned short*)alloc((size_t)256 * 256 * 2);
    unsigned short* wtB0 = (unsigned short*)alloc((size_t)256 * 256 * 2);
    unsigned short* wtB1 = (unsigned short*)alloc((size_t)256 * 256 * 2);
    unsigned short* wtB2 = (unsigned short*)alloc((size_t)256 * 256 * 2);
    float* hstat = (float*)alloc(64 * 4);
    float* y1    = (float*)alloc((size_t)BATCH * 6 * 64 * 4);
    float* y2    = (float*)alloc((size_t)BATCH * 6 * 32 * 4);
    if ((size_t)(w - (char*)d_ws) > ws_size) {
        k_sentinel<<<16, 256, 0, stream>>>(out, out_size, -333.f); return;
    }

    const float* drug_x  = (const float*)d_in[0];
    const int* drug_ei   = (const int*)d_in[1];
    const int* drug_idx  = (const int*)d_in[2];
    const float* dis_x   = (const float*)d_in[3];
    const int* dis_ei    = (const int*)d_in[4];
    const int* dis_idx   = (const int*)d_in[5];
    const int* mol_x     = (const int*)d_in[6];
    const int* mol_ei    = (const int*)d_in[7];
    const int* mol_b     = (const int*)d_in[8];
    const float *dr_W0 = (const float*)d_in[9], *dr_W1 = (const float*)d_in[10], *dr_W2 = (const float*)d_in[11];
    const float *dr_b2 = (const float*)d_in[14];
    const float *dr_g0 = (const float*)d_in[15], *dr_g1 = (const float*)d_in[16];
    const float *dr_be0 = (const float*)d_in[17], *dr_be1 = (const float*)d_in[18];
    const float *di_W0 = (const float*)d_in[19], *di_W1 = (const float*)d_in[20], *di_W2 = (const float*)d_in[21];
    const float *di_b2 = (const float*)d_in[24];
    const float *di_g0 = (const float*)d_in[25], *di_g1 = (const float*)d_in[26];
    const float *di_be0 = (const float*)d_in[27], *di_be1 = (const float*)d_in[28];
    const float* mol_emb = (const float*)d_in[29];
    const float *mo_W0 = (const float*)d_in[30], *mo_W1 = (const float*)d_in[31], *mo_W2 = (const float*)d_in[32];
    const float *mo_b2 = (const float*)d_in[35];
    const float *mo_g0 = (const float*)d_in[36], *mo_g1 = (const float*)d_in[37];
    const float *mo_be0 = (const float*)d_in[38], *mo_be1 = (const float*)d_in[39];
    const float *c1_W = (const float*)d_in[40], *c1_b = (const float*)d_in[41];
    const float *c1_g = (const float*)d_in[42], *c1_be = (const float*)d_in[43];
    const float *c2_W = (const float*)d_in[44], *c2_b = (const float*)d_in[45];
    const float *c2_g = (const float*)d_in[46], *c2_be = (const float*)d_in[47];
    const float *l1_W = (const float*)d_in[48], *l1_b = (const float*)d_in[49];
    const float *l2_W = (const float*)d_in[50], *l2_b = (const float*)d_in[51];

    hipMemsetAsync(bnbuf, 0, 1024 * sizeof(float), stream);  // bn_coef self-zeroes thereafter
    float invNP = 1.0f / (float)N_DRUG;
    float invNM = 1.0f / (float)N_MOL;

    // ======== batched drug+dis GCN (2 graphs, padded to SPAN_P rows each) ========
    k_cast_pair<<<(NP * 32 + 255) / 256, 256, 0, stream>>>(drug_x, dis_x, xin);
    hipMemsetAsync(cnt, 0, (size_t)NP * sizeof(int), stream);
    k_count2<<<(2 * E_G + 255) / 256, 256, 0, stream>>>(drug_ei, dis_ei, cnt);
    int nbP = (NP + 255) / 256;     // 158
    k_scan1<<<nbP, 256, 0, stream>>>(cnt, rowStart, bsum, dinv, NP);
    k_scan3<<<nbP, 256, 0, stream>>>(rowStart, cursor, bsum, NP, nbP, 2 * E_G);
    k_fill2<<<(2 * E_G + 255) / 256, 256, 0, stream>>>(drug_ei, dis_ei, dinv, cursor, csr2);
    int wtot = 128 * 256 + 256 * 256 + 256 * 128;
    k_wcast3<<<(wtot + 255) / 256, 256, 0, stream>>>(dr_W0, dr_W1, dr_W2, wtA0, wtA1, wtA2, 128);
    k_wcast3<<<(wtot + 255) / 256, 256, 0, stream>>>(di_W0, di_W1, di_W2, wtB0, wtB1, wtB2, 128);

    int gbP = NP / 8;               // 5024
    int tyP = NP / 128;             // 314
    // L0: gather(agg-first) -> GEMM(+stats)
    k_gather<128, 0, 1><<<gbP, 256, 0, stream>>>(xin, dinv, nullptr, nullptr, csr2, rowStart, xb, NP, SPAN_P);
    k_gemm_mfma<0, 1, 1><<<dim3(2, tyP), 256, 0, stream>>>(xb, wtA0, wtB0, nullptr, h_bf, bnbuf, N_DRUG, SPAN_P, 128, 256);
    k_bn_coef<<<2, 256, 0, stream>>>(bnbuf, dr_g0, dr_be0, di_g0, di_be0, coef, invNP);
    // L1: GEMM(BN0 fused) -> gather -> stats
    k_gemm_mfma<1, 0, 1><<<dim3(2, tyP), 256, 0, stream>>>(h_bf, wtA1, wtB1, coef, xb, nullptr, N_DRUG, SPAN_P, 256, 256);
    k_gather<256, 0, 1><<<gbP, 256, 0, stream>>>(xb, dinv, nullptr, nullptr, csr2, rowStart, h_bf, NP, SPAN_P);
    k_bn_stats_bf<<<dim3(256, 2), 256, 0, stream>>>(h_bf, bnbuf, SPAN_P);
    k_bn_coef<<<2, 256, 0, stream>>>(bnbuf, dr_g1, dr_be1, di_g1, di_be1, coef, invNP);
    // L2: GEMM(BN1 fused) -> gather+bias -> outDS f32
    k_gemm_mfma<1, 0, 1><<<dim3(1, tyP), 256, 0, stream>>>(h_bf, wtA2, wtB2, coef, xb, nullptr, N_DRUG, SPAN_P, 256, 128);
    k_gather<128, 1, 0><<<gbP, 256, 0, stream>>>(xb, dinv, dr_b2, di_b2, csr2, rowStart, outDS, NP, SPAN_P);

    // ======== mol GCN ========
    k_atom_enc<<<N_MOL / 4, 256, 0, stream>>>(mol_x, mol_emb, xin);
    hipMemsetAsync(cnt, 0, (size_t)N_MOL * sizeof(int), stream);
    k_count<<<(E_MOL + 255) / 256, 256, 0, stream>>>(mol_ei + E_MOL, cnt, E_MOL);
    int nbM = N_MOL / 256;          // 256
    k_scan1<<<nbM, 256, 0, stream>>>(cnt, rowStart, bsum, dinv, N_MOL);
    k_scan3<<<nbM, 256, 0, stream>>>(rowStart, cursor, bsum, N_MOL, nbM, E_MOL);
    k_fill<<<(E_MOL + 255) / 256, 256, 0, stream>>>(mol_ei, mol_ei + E_MOL, dinv, cursor, csr2, E_MOL);
    int wtotM = 256 * 256 + 256 * 256 + 256 * 128;
    k_wcast3<<<(wtotM + 255) / 256, 256, 0, stream>>>(mo_W0, mo_W1, mo_W2, wtA0, wtA1, wtA2, 256);

    int gbM = N_MOL / 8;
    int tyM = N_MOL / 128;          // 512
    k_gather<256, 0, 1><<<gbM, 256, 0, stream>>>(xin, dinv, nullptr, nullptr, csr2, rowStart, xb, N_MOL, N_MOL);
    k_gemm_mfma<0, 1, 0><<<dim3(2, tyM), 256, 0, stream>>>(xb, wtA0, wtA0, nullptr, h_bf, bnbuf, N_MOL, N_MOL, 256, 256);
    k_bn_coef<<<1, 256, 0, stream>>>(bnbuf, mo_g0, mo_be0, mo_g0, mo_be0, coef, invNM);
    k_gemm_mfma<1, 0, 0><<<dim3(2, tyM), 256, 0, stream>>>(h_bf, wtA1, wtA1, coef, xb, nullptr, N_MOL, N_MOL, 256, 256);
    k_gather<256, 0, 1><<<gbM, 256, 0, stream>>>(xb, dinv, nullptr, nullptr, csr2, rowStart, h_bf, N_MOL, N_MOL);
    k_bn_stats_bf<<<dim3(256, 1), 256, 0, stream>>>(h_bf, bnbuf, N_MOL);
    k_bn_coef<<<1, 256, 0, stream>>>(bnbuf, mo_g1, mo_be1, mo_g1, mo_be1, coef, invNM);
    k_gemm_mfma<1, 0, 0><<<dim3(1, tyM), 256, 0, stream>>>(h_bf, wtA2, wtA2, coef, xb, nullptr, N_MOL, N_MOL, 256, 128);
    k_gather<128, 1, 1><<<gbM, 256, 0, stream>>>(xb, dinv, mo_b2, mo_b2, csr2, rowStart, h_bf, N_MOL, N_MOL);
    k_pool_seg<<<BATCH, 128, 0, stream>>>(h_bf, mol_b, mpool);

    // ======== head ========
    const float* dfeat = outDS;
    const float* sfeat = outDS + (size_t)SPAN_P * 128;
    hipMemsetAsync(hstat, 0, 64 * 4, stream);
    k_conv1<<<BATCH, 64, 0, stream>>>(dfeat, mpool, sfeat, drug_idx, dis_idx, c1_W, c1_b, y1);
    k_head_stats<<<dim3(6, BATCH / 256), 256, 0, stream>>>(y1, hstat, 0, 64);
    k_bn_fin<<<1, 8, 0, stream>>>(hstat, 0, 1.0f / (BATCH * 64.0f));
    k_conv2<<<BATCH, 64, 0, stream>>>(y1, hstat, c1_g, c1_be, c2_W, c2_b, y2);
    k_head_stats<<<dim3(6, BATCH / 256), 256, 0, stream>>>(y2, hstat, 1, 32);
    k_bn_fin<<<1, 8, 0, stream>>>(hstat, 1, 1.0f / (BATCH * 32.0f));
    k_head<<<BATCH, 128, 0, stream>>>(y2, hstat, c2_g, c2_be, l1_W, l1_b, l2_W, l2_b, out);
}

// Round 14
// 561.757 us; speedup vs baseline: 1.0614x; 1.0614x over previous
//
#include <hip/hip_runtime.h>
#include <hip/hip_bf16.h>

#define N_DRUG 20000
#define N_DIS  20000
#define E_G    320000
#define BATCH  4096
#define N_MOL  65536
#define E_MOL  262144
#define NF     9
#define NV     128
#define DH     256
#define SPAN_P 20096                 // 157*128 pad per drug/dis graph
#define NP     40192                 // 2*SPAN_P
#define NTOT   105728                // NP + N_MOL
#define ETOT   902144                // 2*E_G + E_MOL

typedef short s16x8 __attribute__((ext_vector_type(8)));
typedef unsigned short u16x8 __attribute__((ext_vector_type(8)));
typedef float f32x4 __attribute__((ext_vector_type(4)));

typedef __attribute__((address_space(1))) const void gvoid_t;
typedef __attribute__((address_space(3))) void lvoid_t;

__device__ __forceinline__ float bfu2f(unsigned short u) {
    return __uint_as_float(((unsigned int)u) << 16);
}
__device__ __forceinline__ unsigned short f2bfu(float f) {
    __hip_bfloat16 b = __float2bfloat16(f);
    return *reinterpret_cast<unsigned short*>(&b);
}
__device__ __forceinline__ void atomAddF(float* p, float v) { unsafeAtomicAdd(p, v); }

// ---------------- misc ----------------
__global__ void k_sentinel(float* out, int n, float v) {
    int i = blockIdx.x * 256 + threadIdx.x;
    if (i < n) out[i] = v;
}

// drug+dis cast into padded bf16 [NP][128] at buffer start; pad rows zero
__global__ void k_cast_pair(const float* __restrict__ a, const float* __restrict__ b,
                            unsigned short* __restrict__ out) {
    int i4 = blockIdx.x * 256 + threadIdx.x;
    if (i4 >= NP * 32) return;
    int row = i4 >> 5, c4 = (i4 & 31) * 4;
    float4 v = {0.f, 0.f, 0.f, 0.f};
    if (row < N_DRUG) v = *reinterpret_cast<const float4*>(a + (size_t)row * 128 + c4);
    else if (row >= SPAN_P && row < SPAN_P + N_DIS)
        v = *reinterpret_cast<const float4*>(b + (size_t)(row - SPAN_P) * 128 + c4);
    ushort4 o = {f2bfu(v.x), f2bfu(v.y), f2bfu(v.z), f2bfu(v.w)};
    *reinterpret_cast<ushort4*>(out + (size_t)row * 128 + c4) = o;
}

// 3 weight transposes: W[K][N] f32 -> Wt[N][K] bf16
__global__ void k_wcast3(const float* __restrict__ W0, const float* __restrict__ W1,
                         const float* __restrict__ W2,
                         unsigned short* __restrict__ T0, unsigned short* __restrict__ T1,
                         unsigned short* __restrict__ T2, int Cin) {
    int i = blockIdx.x * 256 + threadIdx.x;
    int t0 = Cin * 256, t1 = 256 * 256, t2 = 256 * 128;
    if (i < t0) {
        int k = i / 256, c = i - k * 256;
        T0[(size_t)c * Cin + k] = f2bfu(W0[i]);
    } else if (i < t0 + t1) {
        int e = i - t0;
        int k = e / 256, c = e - k * 256;
        T1[(size_t)c * 256 + k] = f2bfu(W1[e]);
    } else if (i < t0 + t1 + t2) {
        int e = i - t0 - t1;
        int k = e / 128, c = e - k * 128;
        T2[(size_t)c * 256 + k] = f2bfu(W2[e]);
    }
}

// ---------------- merged-graph degree / CSR ----------------
__global__ void k_count3(const int* __restrict__ eA, const int* __restrict__ eB,
                         const int* __restrict__ eC, int* __restrict__ cnt) {
    int e = blockIdx.x * 256 + threadIdx.x;
    if (e >= ETOT) return;
    int d;
    if (e < E_G) d = eA[E_G + e];
    else if (e < 2 * E_G) d = eB[E_G + (e - E_G)] + SPAN_P;
    else d = eC[E_MOL + (e - 2 * E_G)] + NP;
    atomicAdd(&cnt[d], 1);
}

__global__ void k_scan1(const int* __restrict__ cnt, int* __restrict__ rowStart,
                        int* __restrict__ bsum, float* __restrict__ dinv, int n) {
    __shared__ int sh[256];
    int i = blockIdx.x * 256 + threadIdx.x;
    int v = (i < n) ? cnt[i] : 0;
    if (i < n) dinv[i] = rsqrtf(1.0f + (float)v);
    sh[threadIdx.x] = v;
    __syncthreads();
    for (int off = 1; off < 256; off <<= 1) {
        int t = (threadIdx.x >= off) ? sh[threadIdx.x - off] : 0;
        __syncthreads();
        sh[threadIdx.x] += t;
        __syncthreads();
    }
    if (i < n) rowStart[i] = sh[threadIdx.x] - v;
    if (threadIdx.x == 255) bsum[blockIdx.x] = sh[255];
}
// single-block multi-chunk exclusive scan of nb partials (nb can exceed 256)
__global__ void k_scan2b(int* __restrict__ bsum, int nb) {
    __shared__ int sh[256];
    __shared__ int carry;
    int t = threadIdx.x;
    if (t == 0) carry = 0;
    __syncthreads();
    for (int c0 = 0; c0 < nb; c0 += 256) {
        int v = (c0 + t < nb) ? bsum[c0 + t] : 0;
        sh[t] = v;
        __syncthreads();
        for (int off = 1; off < 256; off <<= 1) {
            int u = (t >= off) ? sh[t - off] : 0;
            __syncthreads();
            sh[t] += u;
            __syncthreads();
        }
        if (c0 + t < nb) bsum[c0 + t] = carry + sh[t] - v;   // exclusive
        __syncthreads();
        if (t == 0) carry += sh[255];
        __syncthreads();
    }
}
__global__ void k_scan3(int* __restrict__ rowStart, int* __restrict__ cursor,
                        const int* __restrict__ bsum, int n, int E) {
    int i = blockIdx.x * 256 + threadIdx.x;
    if (i < n) {
        int r = rowStart[i] + bsum[blockIdx.x];
        rowStart[i] = r;
        cursor[i] = r;
    }
    if (i == 0) rowStart[n] = E;
}
__global__ void k_fill3(const int* __restrict__ eA, const int* __restrict__ eB,
                        const int* __restrict__ eC, const float* __restrict__ dinv,
                        int* __restrict__ cursor, int2* __restrict__ csr2) {
    int e = blockIdx.x * 256 + threadIdx.x;
    if (e >= ETOT) return;
    int s, d;
    if (e < E_G) { s = eA[e]; d = eA[E_G + e]; }
    else if (e < 2 * E_G) { int i = e - E_G; s = eB[i] + SPAN_P; d = eB[E_G + i] + SPAN_P; }
    else { int i = e - 2 * E_G; s = eC[i] + NP; d = eC[E_MOL + i] + NP; }
    int p = atomicAdd(&cursor[d], 1);
    csr2[p] = make_int2(s, __float_as_int(dinv[s] * dinv[d]));
}

// ---------------- MFMA GEMM: up to 3 graphs batched by tile index ----------------
// g = y>=tb1 ? 2 : y>=tb0 ? 1 : 0; per-graph Bt/Mloc/row-offset; coef/bnbuf set = gbase+g.
// AFFINE: A' = relu(scale*A+shift) at fragment read. STATS: col sum/sumsq of acc.
template<int AFFINE, int STATS>
__global__ __launch_bounds__(256) void k_gemm_mfma(const unsigned short* __restrict__ A,
                                                   const unsigned short* __restrict__ Bt0,
                                                   const unsigned short* __restrict__ Bt1,
                                                   const unsigned short* __restrict__ Bt2,
                                                   const float* __restrict__ coef,
                                                   unsigned short* __restrict__ Cout,
                                                   float* __restrict__ bnbuf,
                                                   int tb0, int tb1, int off1, int off2,
                                                   int m0, int m1, int m2, int gbase,
                                                   int K, int N) {
    __shared__ unsigned short Al[2][4][128][8];
    __shared__ unsigned short Bl[2][4][128][8];
    __shared__ float csc[256], csh[256];
    const int tid = threadIdx.x;
    const int y = blockIdx.y;
    const int bm = y * 128;
    const int bn = blockIdx.x * 128;
    const int g = (y >= tb1) ? 2 : ((y >= tb0) ? 1 : 0);
    const int off = (g == 0) ? 0 : ((g == 1) ? off1 : off2);
    const int Mloc = (g == 0) ? m0 : ((g == 1) ? m1 : m2);
    const int lbm = bm - off;
    const unsigned short* Bt = (g == 0) ? Bt0 : ((g == 1) ? Bt1 : Bt2);
    const int gs = gbase + g;
    const int w = tid >> 6, l = tid & 63;
    const int wrow = (w >> 1) * 64, wcol = (w & 1) * 64;
    const int kg = l >> 4, lr = l & 15;

    if (AFFINE) {
        for (int i = tid; i < K; i += 256) {
            csc[i] = coef[gs * 512 + i];
            csh[i] = coef[gs * 512 + 256 + i];
        }
    }
    if (lbm + 128 > Mloc) {  // tail tile: pre-zero both A buffers (pad rows never restaged)
        for (int s = tid; s < 1024; s += 256) {
            u16x8 z = {0, 0, 0, 0, 0, 0, 0, 0};
            *reinterpret_cast<u16x8*>(&Al[0][0][0][0] + s * 8) = z;
        }
    }
    __syncthreads();

    auto stage = [&](int buf, int k0) {
#pragma unroll
        for (int i = 0; i < 4; ++i) {
            int id = w * 4 + i;
            int koff = (id >> 1) & 3;
            int half = id & 1;
            int row = half * 64 + l;
            if (id < 8) {
                if (lbm + row < Mloc) {
                    const unsigned short* gsrc = A + (size_t)(bm + row) * K + k0 + koff * 8;
                    __builtin_amdgcn_global_load_lds((gvoid_t*)gsrc,
                        (lvoid_t*)&Al[buf][koff][half * 64][0], 16, 0, 0);
                }
            } else {
                const unsigned short* gsrc = Bt + (size_t)(bn + row) * K + k0 + koff * 8;
                __builtin_amdgcn_global_load_lds((gvoid_t*)gsrc,
                    (lvoid_t*)&Bl[buf][koff][half * 64][0], 16, 0, 0);
            }
        }
    };

    f32x4 acc[4][4];
#pragma unroll
    for (int fm = 0; fm < 4; ++fm)
#pragma unroll
        for (int fn = 0; fn < 4; ++fn) acc[fm][fn] = f32x4{0.f, 0.f, 0.f, 0.f};

    stage(0, 0);
    __syncthreads();
    int nk = K >> 5;
    for (int t = 0; t < nk; ++t) {
        int cur = t & 1;
        if (t + 1 < nk) stage(cur ^ 1, (t + 1) * 32);
        s16x8 a[4], b[4];
#pragma unroll
        for (int fm = 0; fm < 4; ++fm)
            a[fm] = *reinterpret_cast<const s16x8*>(&Al[cur][kg][wrow + fm * 16 + lr][0]);
        if (AFFINE) {
            int k0 = t * 32;
            float sc[8], sh[8];
#pragma unroll
            for (int e = 0; e < 8; ++e) {
                sc[e] = csc[k0 + kg * 8 + e];
                sh[e] = csh[k0 + kg * 8 + e];
            }
#pragma unroll
            for (int fm = 0; fm < 4; ++fm)
#pragma unroll
                for (int e = 0; e < 8; ++e) {
                    float f = bfu2f((unsigned short)a[fm][e]);
                    a[fm][e] = (short)f2bfu(fmaxf(fmaf(sc[e], f, sh[e]), 0.f));
                }
        }
#pragma unroll
        for (int fn = 0; fn < 4; ++fn)
            b[fn] = *reinterpret_cast<const s16x8*>(&Bl[cur][kg][wcol + fn * 16 + lr][0]);
#pragma unroll
        for (int fm = 0; fm < 4; ++fm)
#pragma unroll
            for (int fn = 0; fn < 4; ++fn)
                acc[fm][fn] = __builtin_amdgcn_mfma_f32_16x16x32_bf16(a[fm], b[fn], acc[fm][fn], 0, 0, 0);
        __syncthreads();
    }
    // C/D layout: col = lane&15, row = (lane>>4)*4 + reg. Pad rows write 0 (needed downstream).
#pragma unroll
    for (int fm = 0; fm < 4; ++fm)
#pragma unroll
        for (int r = 0; r < 4; ++r) {
            int row = bm + wrow + fm * 16 + kg * 4 + r;
#pragma unroll
            for (int fn = 0; fn < 4; ++fn) {
                int col = bn + wcol + fn * 16 + lr;
                Cout[(size_t)row * N + col] = f2bfu(acc[fm][fn][r]);
            }
        }
    if constexpr (STATS) {
        __shared__ float colS[128], colQ[128];
        if (tid < 128) { colS[tid] = 0.f; colQ[tid] = 0.f; }
        __syncthreads();
#pragma unroll
        for (int fn = 0; fn < 4; ++fn) {
            float s = 0.f, q = 0.f;
#pragma unroll
            for (int fm = 0; fm < 4; ++fm)
#pragma unroll
                for (int r = 0; r < 4; ++r) {
                    float v = acc[fm][fn][r];
                    s += v; q += v * v;
                }
            int cl = (w & 1) * 64 + fn * 16 + lr;
            atomicAdd(&colS[cl], s);
            atomicAdd(&colQ[cl], q);
        }
        __syncthreads();
        if (tid < 128) {
            atomAddF(&bnbuf[gs * 512 + bn + tid], colS[tid]);
            atomAddF(&bnbuf[gs * 512 + 256 + bn + tid], colQ[tid]);
        }
    }
}

// ---------------- CSR gather: 32-lane row groups, 8 rows/block, 4-deep unroll ----------------
// addr(r) = h + r*C - hoff (elements); out(r) = outv + r*C - ooff. BIAS: 3-way select by row.
template<int C, int BIAS, int OUTBF>
__global__ __launch_bounds__(256) void k_gather(const unsigned short* __restrict__ h,
                                                long long hoff,
                                                const float* __restrict__ dinv,
                                                const float* __restrict__ b0,
                                                const float* __restrict__ b1,
                                                const float* __restrict__ b2,
                                                const int2* __restrict__ csr2,
                                                const int* __restrict__ rowStart,
                                                void* __restrict__ outv, long long ooff,
                                                int rowoff, int rowend) {
    constexpr int PL = C / 32;
    int row = rowoff + blockIdx.x * 8 + (threadIdx.x >> 5);
    if (row >= rowend) return;
    int lane = threadIdx.x & 31;
    int c0 = lane * PL;

    auto loadRow = [&](int r, float* d) {
        const unsigned short* base = h + ((size_t)r * C - hoff) + c0;
        if constexpr (PL == 8) {
            u16x8 v = *reinterpret_cast<const u16x8*>(base);
#pragma unroll
            for (int e = 0; e < 8; ++e) d[e] = bfu2f((unsigned short)v[e]);
        } else {
            ushort4 v = *reinterpret_cast<const ushort4*>(base);
            d[0] = bfu2f(v.x); d[1] = bfu2f(v.y); d[2] = bfu2f(v.z); d[3] = bfu2f(v.w);
        }
    };

    float dd = dinv[row], ws = dd * dd;
    int beg = rowStart[row], end = rowStart[row + 1];
    float a0[PL], a1[PL], a2[PL], a3[PL], t0[PL], t1[PL], t2[PL], t3[PL];
    loadRow(row, t0);
#pragma unroll
    for (int p = 0; p < PL; ++p) { a0[p] = t0[p] * ws; a1[p] = 0.f; a2[p] = 0.f; a3[p] = 0.f; }

    int j = beg;
    for (; j + 4 <= end; j += 4) {
        int2 e0 = csr2[j], e1 = csr2[j + 1], e2 = csr2[j + 2], e3 = csr2[j + 3];
        float w0 = __int_as_float(e0.y), w1 = __int_as_float(e1.y);
        float w2 = __int_as_float(e2.y), w3 = __int_as_float(e3.y);
        loadRow(e0.x, t0); loadRow(e1.x, t1); loadRow(e2.x, t2); loadRow(e3.x, t3);
#pragma unroll
        for (int p = 0; p < PL; ++p) {
            a0[p] += w0 * t0[p]; a1[p] += w1 * t1[p];
            a2[p] += w2 * t2[p]; a3[p] += w3 * t3[p];
        }
    }
    for (; j < end; ++j) {
        int2 e0 = csr2[j];
        float w = __int_as_float(e0.y);
        loadRow(e0.x, t0);
#pragma unroll
        for (int p = 0; p < PL; ++p) a0[p] += w * t0[p];
    }
    const float* bp = nullptr;
    if (BIAS) bp = (row < SPAN_P) ? b0 : ((row < NP) ? b1 : b2);
#pragma unroll
    for (int p = 0; p < PL; ++p) {
        a0[p] += (a1[p] + a2[p]) + a3[p];
        if (BIAS) a0[p] += bp[c0 + p];
    }
    if constexpr (OUTBF) {
        unsigned short* o = (unsigned short*)outv + ((size_t)row * C - ooff) + c0;
        if constexpr (PL == 8) {
            u16x8 ov;
#pragma unroll
            for (int e = 0; e < 8; ++e) ov[e] = f2bfu(a0[e]);
            *reinterpret_cast<u16x8*>(o) = ov;
        } else {
            ushort4 ov = {f2bfu(a0[0]), f2bfu(a0[1]), f2bfu(a0[2]), f2bfu(a0[3])};
            *reinterpret_cast<ushort4*>(o) = ov;
        }
    } else {
        float* o = (float*)outv + ((size_t)row * C - ooff) + c0;
#pragma unroll
        for (int q = 0; q < PL / 4; ++q) {
            float4 ov = {a0[q * 4 + 0], a0[q * 4 + 1], a0[q * 4 + 2], a0[q * 4 + 3]};
            *reinterpret_cast<float4*>(o + q * 4) = ov;
        }
    }
}

// ---------------- BN stats over merged [NTOT][256]: blockIdx.y = graph 0..2 ----------------
__global__ __launch_bounds__(256) void k_bn_stats3(const unsigned short* __restrict__ x,
                                                   float* __restrict__ bnbuf) {
    __shared__ float smS[8][256];
    __shared__ float smQ[8][256];
    int t = threadIdx.x;
    int y = blockIdx.y;
    int off = (y < 2) ? y * SPAN_P : NP;
    int span = (y < 2) ? SPAN_P : N_MOL;
    int g = t >> 5;
    int lane = t & 31;
    int c0 = lane * 8;
    float s[8], q[8];
#pragma unroll
    for (int e = 0; e < 8; ++e) { s[e] = 0.f; q[e] = 0.f; }
    int stride = gridDim.x * 8;
    for (int r = blockIdx.x * 8 + g; r < span; r += stride) {
        u16x8 v = *reinterpret_cast<const u16x8*>(x + ((size_t)(off + r)) * 256 + c0);
#pragma unroll
        for (int e = 0; e < 8; ++e) {
            float f = bfu2f((unsigned short)v[e]);
            s[e] += f; q[e] += f * f;
        }
    }
#pragma unroll
    for (int e = 0; e < 8; ++e) { smS[g][c0 + e] = s[e]; smQ[g][c0 + e] = q[e]; }
    __syncthreads();
    float S = 0.f, Q = 0.f;
#pragma unroll
    for (int g2 = 0; g2 < 8; ++g2) { S += smS[g2][t]; Q += smQ[g2][t]; }
    atomAddF(&bnbuf[y * 512 + t], S);
    atomAddF(&bnbuf[y * 512 + 256 + t], Q);
}

// 3-graph coef: coef[g][j]=gamma*rstd, coef[g][256+j]=beta-mean*scale; self-zeroes bnbuf
__global__ void k_bn_coef3(float* __restrict__ bnbuf,
                           const float* __restrict__ g0, const float* __restrict__ be0,
                           const float* __restrict__ g1, const float* __restrict__ be1,
                           const float* __restrict__ g2, const float* __restrict__ be2,
                           float* __restrict__ coef, float invN01, float invN2) {
    int gg = blockIdx.x;
    int j = threadIdx.x;
    const float* gp = (gg == 0) ? g0 : ((gg == 1) ? g1 : g2);
    const float* bp = (gg == 0) ? be0 : ((gg == 1) ? be1 : be2);
    float invN = (gg < 2) ? invN01 : invN2;
    float* s = bnbuf + gg * 512;
    float m = s[j] * invN;
    float v = s[256 + j] * invN - m * m;
    float r = rsqrtf(fmaxf(v, 0.f) + 1e-5f);
    float sc = gp[j] * r;
    coef[gg * 512 + j] = sc;
    coef[gg * 512 + 256 + j] = bp[j] - m * sc;
    s[j] = 0.f;
    s[256 + j] = 0.f;
}

// ---------------- atom encoder (writes local [N_MOL][256] bf16) ----------------
__global__ __launch_bounds__(256) void k_atom_enc(const int* __restrict__ mol_x,
                                                  const float* __restrict__ emb,
                                                  unsigned short* __restrict__ h) {
    __shared__ int sidx[4][NF];
    int t = threadIdx.x;
    if (t < 4 * NF) sidx[t / NF][t % NF] = mol_x[(blockIdx.x * 4 + t / NF) * NF + t % NF];
    __syncthreads();
    int r = t >> 6, lane = t & 63;
    int c0 = lane * 4;
    int row = blockIdx.x * 4 + r;
    float4 s = {0.f, 0.f, 0.f, 0.f};
#pragma unroll
    for (int f = 0; f < NF; ++f) {
        const float4 v = *reinterpret_cast<const float4*>(emb + ((size_t)f * NV + sidx[r][f]) * DH + c0);
        s.x += v.x; s.y += v.y; s.z += v.z; s.w += v.w;
    }
    ushort4 ov = {f2bfu(s.x), f2bfu(s.y), f2bfu(s.z), f2bfu(s.w)};
    *reinterpret_cast<ushort4*>(h + (size_t)row * DH + c0) = ov;
}

// ---------------- segment pool over f32 mol features [N_MOL][128] ----------------
__global__ __launch_bounds__(128) void k_pool_seg_f(const float* __restrict__ mfeat,
                                                    const int* __restrict__ batch,
                                                    float* __restrict__ mpool) {
    __shared__ int sr[2];
    __shared__ float smS[8][128];
    int b = blockIdx.x, t = threadIdx.x;
    if (t < 2) {
        int target = b + t;
        int lo = 0, hi = N_MOL;
        while (lo < hi) {
            int mid = (lo + hi) >> 1;
            if (batch[mid] < target) lo = mid + 1; else hi = mid;
        }
        sr[t] = lo;
    }
    __syncthreads();
    int g = t >> 4;
    int lane = t & 15;
    int c0 = lane * 8;
    float s[8];
#pragma unroll
    for (int e = 0; e < 8; ++e) s[e] = 0.f;
    int e1 = sr[1];
    for (int i = sr[0] + g; i < e1; i += 8) {
        const float4 v0 = *reinterpret_cast<const float4*>(mfeat + (size_t)i * 128 + c0);
        const float4 v1 = *reinterpret_cast<const float4*>(mfeat + (size_t)i * 128 + c0 + 4);
        s[0] += v0.x; s[1] += v0.y; s[2] += v0.z; s[3] += v0.w;
        s[4] += v1.x; s[5] += v1.y; s[6] += v1.z; s[7] += v1.w;
    }
#pragma unroll
    for (int e = 0; e < 8; ++e) smS[g][c0 + e] = s[e];
    __syncthreads();
    float S = 0.f;
#pragma unroll
    for (int g2 = 0; g2 < 8; ++g2) S += smS[g2][t];
    mpool[(size_t)b * 128 + t] = S;
}

// ---------------- head: conv1 ----------------
__global__ __launch_bounds__(64) void k_conv1(const float* __restrict__ dfeat,
                                              const float* __restrict__ mpool,
                                              const float* __restrict__ sfeat,
                                              const int* __restrict__ drug_idx,
                                              const int* __restrict__ dis_idx,
                                              const float* __restrict__ W,
                                              const float* __restrict__ bias,
                                              float* __restrict__ y1) {
    __shared__ float xs[3][128];
    __shared__ float w[54];
    __shared__ float bb[6];
    int b = blockIdx.x, t = threadIdx.x;
    int di = drug_idx[b], si = dis_idx[b];
    const float* r0 = dfeat + (size_t)di * 128;
    const float* r1 = mpool + (size_t)b * 128;
    const float* r2 = sfeat + (size_t)si * 128;
    xs[0][t] = r0[t]; xs[0][t + 64] = r0[t + 64];
    xs[1][t] = r1[t]; xs[1][t + 64] = r1[t + 64];
    xs[2][t] = r2[t]; xs[2][t + 64] = r2[t + 64];
    if (t < 54) w[t] = W[t];
    if (t < 6) bb[t] = bias[t];
    __syncthreads();
    int l0 = 2 * t, l1 = l0 + 1;
#pragma unroll
    for (int o = 0; o < 6; ++o) {
        float ya = bb[o], yb = bb[o];
#pragma unroll
        for (int i = 0; i < 3; ++i) {
            const float* wi = &w[(o * 3 + i) * 3];
            float xm1 = (l0 > 0) ? xs[i][l0 - 1] : 0.f;
            float x0 = xs[i][l0];
            float x1 = xs[i][l1];
            float x2 = (l1 < 127) ? xs[i][l1 + 1] : 0.f;
            ya += wi[0] * xm1 + wi[1] * x0 + wi[2] * x1;
            yb += wi[0] * x0 + wi[1] * x1 + wi[2] * x2;
        }
        y1[((size_t)b * 6 + o) * 64 + t] = fmaxf(ya, yb);
    }
}

// hb per 'which': [0..5]=sum [8..13]=sumsq [16..21]=mean [24..29]=rstd; grid (6,16)
__global__ __launch_bounds__(256) void k_head_stats(const float* __restrict__ y,
                                                    float* __restrict__ hb, int which, int L) {
    int o = blockIdx.x;
    int b0 = blockIdx.y * 256;
    int t = threadIdx.x;
    float s = 0.f, q = 0.f;
    int per = 256 * L;
    for (int idx = t; idx < per; idx += 256) {
        int b = b0 + idx / L;
        int l = idx - (idx / L) * L;
        float v = y[((size_t)b * 6 + o) * L + l];
        s += v; q += v * v;
    }
    __shared__ float sms[4], smq[4];
#pragma unroll
    for (int off = 32; off > 0; off >>= 1) {
        s += __shfl_down(s, off);
        q += __shfl_down(q, off);
    }
    if ((t & 63) == 0) { sms[t >> 6] = s; smq[t >> 6] = q; }
    __syncthreads();
    if (t == 0) {
        float S = 0.f, Q = 0.f;
        for (int i = 0; i < 4; ++i) { S += sms[i]; Q += smq[i]; }
        atomAddF(hb + which * 32 + o, S);
        atomAddF(hb + which * 32 + 8 + o, Q);
    }
}

__global__ void k_bn_fin(float* __restrict__ hb, int which, float invN) {
    int o = threadIdx.x;
    if (o >= 6) return;
    float* p = hb + which * 32;
    float m = p[o] * invN;
    float v = p[8 + o] * invN - m * m;
    p[16 + o] = m;
    p[24 + o] = rsqrtf(fmaxf(v, 0.f) + 1e-5f);
}

// ---------------- head: conv2 ----------------
__global__ __launch_bounds__(64) void k_conv2(const float* __restrict__ y1,
                                              const float* __restrict__ hb,
                                              const float* __restrict__ g1,
                                              const float* __restrict__ be1,
                                              const float* __restrict__ W,
                                              const float* __restrict__ bias,
                                              float* __restrict__ y2) {
    __shared__ float xs[6][64];
    __shared__ float w[108];
    __shared__ float bb[6];
    int b = blockIdx.x, t = threadIdx.x;
    const float* mean = hb + 16;
    const float* rstd = hb + 24;
    for (int idx = t; idx < 384; idx += 64) {
        int o = idx >> 6, l = idx & 63;
        float v = y1[((size_t)b * 6 + o) * 64 + l];
        v = g1[o] * (v - mean[o]) * rstd[o] + be1[o];
        xs[o][l] = fmaxf(v, 0.f);
    }
    for (int idx = t; idx < 108; idx += 64) w[idx] = W[idx];
    if (t < 6) bb[t] = bias[t];
    __syncthreads();
    if (t >= 32) return;
    int l0 = 2 * t, l1 = l0 + 1;
#pragma unroll
    for (int o = 0; o < 6; ++o) {
        float ya = bb[o], yb = bb[o];
#pragma unroll
        for (int i = 0; i < 6; ++i) {
            const float* wi = &w[(o * 6 + i) * 3];
            float xm1 = (l0 > 0) ? xs[i][l0 - 1] : 0.f;
            float x0 = xs[i][l0];
            float x1 = xs[i][l1];
            float x2 = (l1 < 63) ? xs[i][l1 + 1] : 0.f;
            ya += wi[0] * xm1 + wi[1] * x0 + wi[2] * x1;
            yb += wi[0] * x0 + wi[1] * x1 + wi[2] * x2;
        }
        y2[((size_t)b * 6 + o) * 32 + t] = fmaxf(ya, yb);
    }
}

// ---------------- head final ----------------
__global__ __launch_bounds__(128) void k_head(const float* __restrict__ y2,
                                              const float* __restrict__ hb,
                                              const float* __restrict__ g2,
                                              const float* __restrict__ be2,
                                              const float* __restrict__ l1W,
                                              const float* __restrict__ l1b,
                                              const float* __restrict__ l2W,
                                              const float* __restrict__ l2b,
                                              float* __restrict__ out) {
    __shared__ float fs[192];
    __shared__ float sm[2];
    int b = blockIdx.x, t = threadIdx.x;
    const float* mean = hb + 32 + 16;
    const float* rstd = hb + 32 + 24;
    for (int idx = t; idx < 192; idx += 128) {
        int o = idx >> 5, l = idx & 31;
        float v = y2[((size_t)b * 6 + o) * 32 + l];
        v = g2[o] * (v - mean[o]) * rstd[o] + be2[o];
        fs[idx] = fmaxf(v, 0.f);
    }
    __syncthreads();
    float h = l1b[t];
    for (int k = 0; k < 192; ++k)
        h += fs[k] * l1W[k * 128 + t];
    h = fmaxf(h, 0.f);
    float p = h * l2W[t];
#pragma unroll
    for (int off = 32; off > 0; off >>= 1) p += __shfl_down(p, off);
    if ((t & 63) == 0) sm[t >> 6] = p;
    __syncthreads();
    if (t == 0) out[b] = sm[0] + sm[1] + l2b[0];
}

extern "C" void kernel_launch(void* const* d_in, const int* in_sizes, int n_in,
                              void* d_out, int out_size, void* d_ws, size_t ws_size,
                              hipStream_t stream) {
    float* out = (float*)d_out;
    if (n_in != 52) { k_sentinel<<<16, 256, 0, stream>>>(out, out_size, -111.f); return; }
    if (in_sizes[0] != N_DRUG * 128 || in_sizes[29] != NF * NV * DH || in_sizes[48] != 192 * 128) {
        k_sentinel<<<16, 256, 0, stream>>>(out, out_size, -222.f); return;
    }

    char* w = (char*)d_ws;
    auto alloc = [&](size_t bytes) { char* p = w; w += (bytes + 255) & ~(size_t)255; return p; };
    unsigned short* B1 = (unsigned short*)alloc((size_t)NTOT * 256 * 2);   // 54.1 MB
    unsigned short* B2 = (unsigned short*)alloc((size_t)NTOT * 256 * 2);   // 54.1 MB
    float* fcat = (float*)B1;   // alias: B1 dead after L2 GEMM reads it; L2 gather writes fcat
    float* mpool = (float*)alloc((size_t)BATCH * 128 * 4);
    int*   cnt      = (int*)alloc((size_t)NTOT * 4);
    float* dinv     = (float*)alloc((size_t)NTOT * 4);
    int*   rowStart = (int*)alloc((size_t)(NTOT + 1) * 4);
    int*   cursor   = (int*)alloc((size_t)NTOT * 4);
    int2*  csr2     = (int2*)alloc((size_t)ETOT * 8);
    int*   bsum     = (int*)alloc(1024 * 4);
    float* bnbuf    = (float*)alloc(1536 * 4);
    float* coef     = (float*)alloc(1536 * 4);
    unsigned short* drT0 = (unsigned short*)alloc((size_t)128 * 256 * 2);
    unsigned short* drT1 = (unsigned short*)alloc((size_t)256 * 256 * 2);
    unsigned short* drT2 = (unsigned short*)alloc((size_t)256 * 128 * 2);
    unsigned short* diT0 = (unsigned short*)alloc((size_t)128 * 256 * 2);
    unsigned short* diT1 = (unsigned short*)alloc((size_t)256 * 256 * 2);
    unsigned short* diT2 = (unsigned short*)alloc((size_t)256 * 128 * 2);
    unsigned short* moT0 = (unsigned short*)alloc((size_t)256 * 256 * 2);
    unsigned short* moT1 = (unsigned short*)alloc((size_t)256 * 256 * 2);
    unsigned short* moT2 = (unsigned short*)alloc((size_t)256 * 128 * 2);
    float* hstat = (float*)alloc(64 * 4);
    float* y1    = (float*)alloc((size_t)BATCH * 6 * 64 * 4);
    float* y2    = (float*)alloc((size_t)BATCH * 6 * 32 * 4);
    if ((size_t)(w - (char*)d_ws) > ws_size) {
        k_sentinel<<<16, 256, 0, stream>>>(out, out_size, -333.f); return;
    }

    const float* drug_x  = (const float*)d_in[0];
    const int* drug_ei   = (const int*)d_in[1];
    const int* drug_idx  = (const int*)d_in[2];
    const float* dis_x   = (const float*)d_in[3];
    const int* dis_ei    = (const int*)d_in[4];
    const int* dis_idx   = (const int*)d_in[5];
    const int* mol_x     = (const int*)d_in[6];
    const int* mol_ei    = (const int*)d_in[7];
    const int* mol_b     = (const int*)d_in[8];
    const float *dr_W0 = (const float*)d_in[9], *dr_W1 = (const float*)d_in[10], *dr_W2 = (const float*)d_in[11];
    const float *dr_b2 = (const float*)d_in[14];
    const float *dr_g0 = (const float*)d_in[15], *dr_g1 = (const float*)d_in[16];
    const float *dr_be0 = (const float*)d_in[17], *dr_be1 = (const float*)d_in[18];
    const float *di_W0 = (const float*)d_in[19], *di_W1 = (const float*)d_in[20], *di_W2 = (const float*)d_in[21];
    const float *di_b2 = (const float*)d_in[24];
    const float *di_g0 = (const float*)d_in[25], *di_g1 = (const float*)d_in[26];
    const float *di_be0 = (const float*)d_in[27], *di_be1 = (const float*)d_in[28];
    const float* mol_emb = (const float*)d_in[29];
    const float *mo_W0 = (const float*)d_in[30], *mo_W1 = (const float*)d_in[31], *mo_W2 = (const float*)d_in[32];
    const float *mo_b2 = (const float*)d_in[35];
    const float *mo_g0 = (const float*)d_in[36], *mo_g1 = (const float*)d_in[37];
    const float *mo_be0 = (const float*)d_in[38], *mo_be1 = (const float*)d_in[39];
    const float *c1_W = (const float*)d_in[40], *c1_b = (const float*)d_in[41];
    const float *c1_g = (const float*)d_in[42], *c1_be = (const float*)d_in[43];
    const float *c2_W = (const float*)d_in[44], *c2_b = (const float*)d_in[45];
    const float *c2_g = (const float*)d_in[46], *c2_be = (const float*)d_in[47];
    const float *l1_W = (const float*)d_in[48], *l1_b = (const float*)d_in[49];
    const float *l2_W = (const float*)d_in[50], *l2_b = (const float*)d_in[51];

    const float invN01 = 1.0f / (float)N_DRUG;
    const float invNM  = 1.0f / (float)N_MOL;
    const long long MOFF = (long long)NP * 128;   // element offset of mol [N_MOL][256] region

    hipMemsetAsync(bnbuf, 0, 1536 * sizeof(float), stream);   // coef3 self-zeroes thereafter

    // ---- inputs into B1: drugdis [NP][128] @0, mol [N_MOL][256] @NP*128 ----
    k_cast_pair<<<(NP * 32 + 255) / 256, 256, 0, stream>>>(drug_x, dis_x, B1);
    k_atom_enc<<<N_MOL / 4, 256, 0, stream>>>(mol_x, mol_emb, B1 + MOFF);

    // ---- merged CSR over NTOT nodes / ETOT edges ----
    hipMemsetAsync(cnt, 0, (size_t)NTOT * sizeof(int), stream);
    k_count3<<<(ETOT + 255) / 256, 256, 0, stream>>>(drug_ei, dis_ei, mol_ei, cnt);
    int nb = (NTOT + 255) / 256;   // 413
    k_scan1<<<nb, 256, 0, stream>>>(cnt, rowStart, bsum, dinv, NTOT);
    k_scan2b<<<1, 256, 0, stream>>>(bsum, nb);
    k_scan3<<<nb, 256, 0, stream>>>(rowStart, cursor, bsum, NTOT, ETOT);
    k_fill3<<<(ETOT + 255) / 256, 256, 0, stream>>>(drug_ei, dis_ei, mol_ei, dinv, cursor, csr2);

    // ---- weights ----
    int wt1 = 128 * 256 + 256 * 256 + 256 * 128;
    int wt2 = 256 * 256 + 256 * 256 + 256 * 128;
    k_wcast3<<<(wt1 + 255) / 256, 256, 0, stream>>>(dr_W0, dr_W1, dr_W2, drT0, drT1, drT2, 128);
    k_wcast3<<<(wt1 + 255) / 256, 256, 0, stream>>>(di_W0, di_W1, di_W2, diT0, diT1, diT2, 128);
    k_wcast3<<<(wt2 + 255) / 256, 256, 0, stream>>>(mo_W0, mo_W1, mo_W2, moT0, moT1, moT2, 256);

    const int BIG = 1 << 28;
    // ---- L0: gather(agg-first) B1 -> B2, then GEMMs B2 -> B1[NTOT][256] (+stats) ----
    k_gather<128, 0, 1><<<NP / 8, 256, 0, stream>>>(B1, 0, dinv, nullptr, nullptr, nullptr,
                                                    csr2, rowStart, B2, 0, 0, NP);
    k_gather<256, 0, 1><<<N_MOL / 8, 256, 0, stream>>>(B1, MOFF, dinv, nullptr, nullptr, nullptr,
                                                       csr2, rowStart, B2, MOFF, NP, NTOT);
    k_gemm_mfma<0, 1><<<dim3(2, 314), 256, 0, stream>>>(B2, drT0, diT0, nullptr, nullptr,
        B1, bnbuf, 157, BIG, SPAN_P, 0, N_DRUG, N_DIS, 0, 0, 128, 256);
    k_gemm_mfma<0, 1><<<dim3(2, 512), 256, 0, stream>>>(B2 + MOFF, moT0, nullptr, nullptr, nullptr,
        B1 + (size_t)NP * 256, bnbuf, BIG, BIG, 0, 0, N_MOL, 0, 0, 2, 256, 256);
    k_bn_coef3<<<3, 256, 0, stream>>>(bnbuf, dr_g0, dr_be0, di_g0, di_be0, mo_g0, mo_be0,
                                      coef, invN01, invNM);
    // ---- L1 merged: GEMM(BN0 fused) B1 -> B2, gather B2 -> B1, stats, coef ----
    k_gemm_mfma<1, 0><<<dim3(2, 826), 256, 0, stream>>>(B1, drT1, diT1, moT1, coef,
        B2, nullptr, 157, 314, SPAN_P, NP, N_DRUG, N_DIS, N_MOL, 0, 256, 256);
    k_gather<256, 0, 1><<<NTOT / 8, 256, 0, stream>>>(B2, 0, dinv, nullptr, nullptr, nullptr,
                                                      csr2, rowStart, B1, 0, 0, NTOT);
    k_bn_stats3<<<dim3(256, 3), 256, 0, stream>>>(B1, bnbuf);
    k_bn_coef3<<<3, 256, 0, stream>>>(bnbuf, dr_g1, dr_be1, di_g1, di_be1, mo_g1, mo_be1,
                                      coef, invN01, invNM);
    // ---- L2 merged: GEMM(BN1 fused) B1 -> B2[NTOT][128], gather+bias3 -> fcat f32 ----
    k_gemm_mfma<1, 0><<<dim3(1, 826), 256, 0, stream>>>(B1, drT2, diT2, moT2, coef,
        B2, nullptr, 157, 314, SPAN_P, NP, N_DRUG, N_DIS, N_MOL, 0, 256, 128);
    k_gather<128, 1, 0><<<NTOT / 8, 256, 0, stream>>>(B2, 0, dinv, dr_b2, di_b2, mo_b2,
                                                      csr2, rowStart, fcat, 0, 0, NTOT);
    k_pool_seg_f<<<BATCH, 128, 0, stream>>>(fcat + (size_t)NP * 128, mol_b, mpool);

    // ---- head ----
    const float* dfeat = fcat;
    const float* sfeat = fcat + (size_t)SPAN_P * 128;
    hipMemsetAsync(hstat, 0, 64 * 4, stream);
    k_conv1<<<BATCH, 64, 0, stream>>>(dfeat, mpool, sfeat, drug_idx, dis_idx, c1_W, c1_b, y1);
    k_head_stats<<<dim3(6, BATCH / 256), 256, 0, stream>>>(y1, hstat, 0, 64);
    k_bn_fin<<<1, 8, 0, stream>>>(hstat, 0, 1.0f / (BATCH * 64.0f));
    k_conv2<<<BATCH, 64, 0, stream>>>(y1, hstat, c1_g, c1_be, c2_W, c2_b, y2);
    k_head_stats<<<dim3(6, BATCH / 256), 256, 0, stream>>>(y2, hstat, 1, 32);
    k_bn_fin<<<1, 8, 0, stream>>>(hstat, 1, 1.0f / (BATCH * 32.0f));
    k_head<<<BATCH, 128, 0, stream>>>(y2, hstat, c2_g, c2_be, l1_W, l1_b, l2_W, l2_b, out);
}

// Round 15
// 558.734 us; speedup vs baseline: 1.0671x; 1.0054x over previous
//
#include <hip/hip_runtime.h>
#include <hip/hip_bf16.h>

#define N_DRUG 20000
#define N_DIS  20000
#define E_G    320000
#define BATCH  4096
#define N_MOL  65536
#define E_MOL  262144
#define NF     9
#define NV     128
#define DH     256
#define SPAN_P 20096                 // 157*128 pad per drug/dis graph
#define NP     40192                 // 2*SPAN_P
#define NTOT   105728                // NP + N_MOL
#define ETOT   902144                // 2*E_G + E_MOL

typedef short s16x8 __attribute__((ext_vector_type(8)));
typedef unsigned short u16x8 __attribute__((ext_vector_type(8)));
typedef float f32x4 __attribute__((ext_vector_type(4)));

typedef __attribute__((address_space(1))) const void gvoid_t;
typedef __attribute__((address_space(3))) void lvoid_t;

__device__ __forceinline__ float bfu2f(unsigned short u) {
    return __uint_as_float(((unsigned int)u) << 16);
}
__device__ __forceinline__ unsigned short f2bfu(float f) {
    __hip_bfloat16 b = __float2bfloat16(f);
    return *reinterpret_cast<unsigned short*>(&b);
}
__device__ __forceinline__ void atomAddF(float* p, float v) { unsafeAtomicAdd(p, v); }

// ---------------- misc ----------------
__global__ void k_sentinel(float* out, int n, float v) {
    int i = blockIdx.x * 256 + threadIdx.x;
    if (i < n) out[i] = v;
}

// drug+dis cast into padded bf16 [NP][128] at buffer start; pad rows zero
__global__ void k_cast_pair(const float* __restrict__ a, const float* __restrict__ b,
                            unsigned short* __restrict__ out) {
    int i4 = blockIdx.x * 256 + threadIdx.x;
    if (i4 >= NP * 32) return;
    int row = i4 >> 5, c4 = (i4 & 31) * 4;
    float4 v = {0.f, 0.f, 0.f, 0.f};
    if (row < N_DRUG) v = *reinterpret_cast<const float4*>(a + (size_t)row * 128 + c4);
    else if (row >= SPAN_P && row < SPAN_P + N_DIS)
        v = *reinterpret_cast<const float4*>(b + (size_t)(row - SPAN_P) * 128 + c4);
    ushort4 o = {f2bfu(v.x), f2bfu(v.y), f2bfu(v.z), f2bfu(v.w)};
    *reinterpret_cast<ushort4*>(out + (size_t)row * 128 + c4) = o;
}

// 3 weight transposes: W[K][N] f32 -> Wt[N][K] bf16
__global__ void k_wcast3(const float* __restrict__ W0, const float* __restrict__ W1,
                         const float* __restrict__ W2,
                         unsigned short* __restrict__ T0, unsigned short* __restrict__ T1,
                         unsigned short* __restrict__ T2, int Cin) {
    int i = blockIdx.x * 256 + threadIdx.x;
    int t0 = Cin * 256, t1 = 256 * 256, t2 = 256 * 128;
    if (i < t0) {
        int k = i / 256, c = i - k * 256;
        T0[(size_t)c * Cin + k] = f2bfu(W0[i]);
    } else if (i < t0 + t1) {
        int e = i - t0;
        int k = e / 256, c = e - k * 256;
        T1[(size_t)c * 256 + k] = f2bfu(W1[e]);
    } else if (i < t0 + t1 + t2) {
        int e = i - t0 - t1;
        int k = e / 128, c = e - k * 128;
        T2[(size_t)c * 256 + k] = f2bfu(W2[e]);
    }
}

// ---------------- merged-graph degree / CSR ----------------
__global__ void k_count3(const int* __restrict__ eA, const int* __restrict__ eB,
                         const int* __restrict__ eC, int* __restrict__ cnt) {
    int e = blockIdx.x * 256 + threadIdx.x;
    if (e >= ETOT) return;
    int d;
    if (e < E_G) d = eA[E_G + e];
    else if (e < 2 * E_G) d = eB[E_G + (e - E_G)] + SPAN_P;
    else d = eC[E_MOL + (e - 2 * E_G)] + NP;
    atomicAdd(&cnt[d], 1);
}

__global__ void k_scan1(const int* __restrict__ cnt, int* __restrict__ rowStart,
                        int* __restrict__ bsum, float* __restrict__ dinv, int n) {
    __shared__ int sh[256];
    int i = blockIdx.x * 256 + threadIdx.x;
    int v = (i < n) ? cnt[i] : 0;
    if (i < n) dinv[i] = rsqrtf(1.0f + (float)v);
    sh[threadIdx.x] = v;
    __syncthreads();
    for (int off = 1; off < 256; off <<= 1) {
        int t = (threadIdx.x >= off) ? sh[threadIdx.x - off] : 0;
        __syncthreads();
        sh[threadIdx.x] += t;
        __syncthreads();
    }
    if (i < n) rowStart[i] = sh[threadIdx.x] - v;
    if (threadIdx.x == 255) bsum[blockIdx.x] = sh[255];
}
// single-block multi-chunk exclusive scan of nb partials
__global__ void k_scan2b(int* __restrict__ bsum, int nb) {
    __shared__ int sh[256];
    __shared__ int carry;
    int t = threadIdx.x;
    if (t == 0) carry = 0;
    __syncthreads();
    for (int c0 = 0; c0 < nb; c0 += 256) {
        int v = (c0 + t < nb) ? bsum[c0 + t] : 0;
        sh[t] = v;
        __syncthreads();
        for (int off = 1; off < 256; off <<= 1) {
            int u = (t >= off) ? sh[t - off] : 0;
            __syncthreads();
            sh[t] += u;
            __syncthreads();
        }
        if (c0 + t < nb) bsum[c0 + t] = carry + sh[t] - v;
        __syncthreads();
        if (t == 0) carry += sh[255];
        __syncthreads();
    }
}
__global__ void k_scan3(int* __restrict__ rowStart, int* __restrict__ cursor,
                        const int* __restrict__ bsum, int n, int E) {
    int i = blockIdx.x * 256 + threadIdx.x;
    if (i < n) {
        int r = rowStart[i] + bsum[blockIdx.x];
        rowStart[i] = r;
        cursor[i] = r;
    }
    if (i == 0) rowStart[n] = E;
}
__global__ void k_fill3(const int* __restrict__ eA, const int* __restrict__ eB,
                        const int* __restrict__ eC, const float* __restrict__ dinv,
                        int* __restrict__ cursor, int2* __restrict__ csr2) {
    int e = blockIdx.x * 256 + threadIdx.x;
    if (e >= ETOT) return;
    int s, d;
    if (e < E_G) { s = eA[e]; d = eA[E_G + e]; }
    else if (e < 2 * E_G) { int i = e - E_G; s = eB[i] + SPAN_P; d = eB[E_G + i] + SPAN_P; }
    else { int i = e - 2 * E_G; s = eC[i] + NP; d = eC[E_MOL + i] + NP; }
    int p = atomicAdd(&cursor[d], 1);
    csr2[p] = make_int2(s, __float_as_int(dinv[s] * dinv[d]));
}

// ---------------- MFMA GEMM: 3 graphs batched, per-graph K / A-base ----------------
// g = y>=tb1 ? 2 : y>=tb0 ? 1 : 0.  Kg = g==2 ? K2 : K01.
// mol (g==2) A addressing: base A+abase2, local row = bm-arow2+row.
// AFFINE: A' = relu(scale*A+shift) at fragment read. STATS: col sum/sumsq of acc.
template<int AFFINE, int STATS>
__global__ __launch_bounds__(256) void k_gemm_mfma(const unsigned short* __restrict__ A,
                                                   const unsigned short* __restrict__ Bt0,
                                                   const unsigned short* __restrict__ Bt1,
                                                   const unsigned short* __restrict__ Bt2,
                                                   const float* __restrict__ coef,
                                                   unsigned short* __restrict__ Cout,
                                                   float* __restrict__ bnbuf,
                                                   int tb0, int tb1, int boff1, int boff2,
                                                   int m0, int m1, int m2, int gbase,
                                                   int K01, int K2, long long abase2,
                                                   int arow2, int N) {
    __shared__ unsigned short Al[2][4][128][8];
    __shared__ unsigned short Bl[2][4][128][8];
    __shared__ float csc[256], csh[256];
    const int tid = threadIdx.x;
    const int y = blockIdx.y;
    const int bm = y * 128;
    const int bn = blockIdx.x * 128;
    const int g = (y >= tb1) ? 2 : ((y >= tb0) ? 1 : 0);
    const int Kg = (g == 2) ? K2 : K01;
    const int boff = (g == 0) ? 0 : ((g == 1) ? boff1 : boff2);
    const int Mloc = (g == 0) ? m0 : ((g == 1) ? m1 : m2);
    const int lbm = bm - boff;
    const unsigned short* Ag = (g == 2) ? (A + abase2) : A;
    const int arow = (g == 2) ? arow2 : 0;
    const unsigned short* Bt = (g == 0) ? Bt0 : ((g == 1) ? Bt1 : Bt2);
    const int gs = gbase + g;
    const int w = tid >> 6, l = tid & 63;
    const int wrow = (w >> 1) * 64, wcol = (w & 1) * 64;
    const int kg = l >> 4, lr = l & 15;

    if (AFFINE) {
        for (int i = tid; i < Kg; i += 256) {
            csc[i] = coef[gs * 512 + i];
            csh[i] = coef[gs * 512 + 256 + i];
        }
    }
    if (lbm + 128 > Mloc) {  // tail tile: pre-zero both A buffers (pad rows never restaged)
        for (int s = tid; s < 1024; s += 256) {
            u16x8 z = {0, 0, 0, 0, 0, 0, 0, 0};
            *reinterpret_cast<u16x8*>(&Al[0][0][0][0] + s * 8) = z;
        }
    }
    __syncthreads();

    auto stage = [&](int buf, int k0) {
#pragma unroll
        for (int i = 0; i < 4; ++i) {
            int id = w * 4 + i;
            int koff = (id >> 1) & 3;
            int half = id & 1;
            int row = half * 64 + l;
            if (id < 8) {
                if (lbm + row < Mloc) {
                    const unsigned short* gsrc = Ag + (size_t)(bm - arow + row) * Kg + k0 + koff * 8;
                    __builtin_amdgcn_global_load_lds((gvoid_t*)gsrc,
                        (lvoid_t*)&Al[buf][koff][half * 64][0], 16, 0, 0);
                }
            } else {
                const unsigned short* gsrc = Bt + (size_t)(bn + row) * Kg + k0 + koff * 8;
                __builtin_amdgcn_global_load_lds((gvoid_t*)gsrc,
                    (lvoid_t*)&Bl[buf][koff][half * 64][0], 16, 0, 0);
            }
        }
    };

    f32x4 acc[4][4];
#pragma unroll
    for (int fm = 0; fm < 4; ++fm)
#pragma unroll
        for (int fn = 0; fn < 4; ++fn) acc[fm][fn] = f32x4{0.f, 0.f, 0.f, 0.f};

    stage(0, 0);
    __syncthreads();
    int nk = Kg >> 5;
    for (int t = 0; t < nk; ++t) {
        int cur = t & 1;
        if (t + 1 < nk) stage(cur ^ 1, (t + 1) * 32);
        s16x8 a[4], b[4];
#pragma unroll
        for (int fm = 0; fm < 4; ++fm)
            a[fm] = *reinterpret_cast<const s16x8*>(&Al[cur][kg][wrow + fm * 16 + lr][0]);
        if (AFFINE) {
            int k0 = t * 32;
            float sc[8], sh[8];
#pragma unroll
            for (int e = 0; e < 8; ++e) {
                sc[e] = csc[k0 + kg * 8 + e];
                sh[e] = csh[k0 + kg * 8 + e];
            }
#pragma unroll
            for (int fm = 0; fm < 4; ++fm)
#pragma unroll
                for (int e = 0; e < 8; ++e) {
                    float f = bfu2f((unsigned short)a[fm][e]);
                    a[fm][e] = (short)f2bfu(fmaxf(fmaf(sc[e], f, sh[e]), 0.f));
                }
        }
#pragma unroll
        for (int fn = 0; fn < 4; ++fn)
            b[fn] = *reinterpret_cast<const s16x8*>(&Bl[cur][kg][wcol + fn * 16 + lr][0]);
#pragma unroll
        for (int fm = 0; fm < 4; ++fm)
#pragma unroll
            for (int fn = 0; fn < 4; ++fn)
                acc[fm][fn] = __builtin_amdgcn_mfma_f32_16x16x32_bf16(a[fm], b[fn], acc[fm][fn], 0, 0, 0);
        __syncthreads();
    }
    // C/D layout: col = lane&15, row = (lane>>4)*4 + reg. Pad rows write 0.
#pragma unroll
    for (int fm = 0; fm < 4; ++fm)
#pragma unroll
        for (int r = 0; r < 4; ++r) {
            int row = bm + wrow + fm * 16 + kg * 4 + r;
#pragma unroll
            for (int fn = 0; fn < 4; ++fn) {
                int col = bn + wcol + fn * 16 + lr;
                Cout[(size_t)row * N + col] = f2bfu(acc[fm][fn][r]);
            }
        }
    if constexpr (STATS) {
        __shared__ float colS[128], colQ[128];
        if (tid < 128) { colS[tid] = 0.f; colQ[tid] = 0.f; }
        __syncthreads();
#pragma unroll
        for (int fn = 0; fn < 4; ++fn) {
            float s = 0.f, q = 0.f;
#pragma unroll
            for (int fm = 0; fm < 4; ++fm)
#pragma unroll
                for (int r = 0; r < 4; ++r) {
                    float v = acc[fm][fn][r];
                    s += v; q += v * v;
                }
            int cl = (w & 1) * 64 + fn * 16 + lr;
            atomicAdd(&colS[cl], s);
            atomicAdd(&colQ[cl], q);
        }
        __syncthreads();
        if (tid < 128) {
            atomAddF(&bnbuf[gs * 512 + bn + tid], colS[tid]);
            atomAddF(&bnbuf[gs * 512 + 256 + bn + tid], colQ[tid]);
        }
    }
}

// ---------------- CSR gather: 32-lane row groups, 8 rows/block, 8/4/1 unroll ----------------
// addr(r) = h + r*C - hoff; out(r) = outv + r*C - ooff. BIAS: 3-way select by row.
template<int C, int BIAS, int OUTBF>
__global__ __launch_bounds__(256) void k_gather(const unsigned short* __restrict__ h,
                                                long long hoff,
                                                const float* __restrict__ dinv,
                                                const float* __restrict__ b0,
                                                const float* __restrict__ b1,
                                                const float* __restrict__ b2,
                                                const int2* __restrict__ csr2,
                                                const int* __restrict__ rowStart,
                                                void* __restrict__ outv, long long ooff,
                                                int rowoff, int rowend) {
    constexpr int PL = C / 32;
    int row = rowoff + blockIdx.x * 8 + (threadIdx.x >> 5);
    if (row >= rowend) return;
    int lane = threadIdx.x & 31;
    int c0 = lane * PL;

    auto loadRow = [&](int r, float* d) {
        const unsigned short* base = h + ((size_t)r * C - hoff) + c0;
        if constexpr (PL == 8) {
            u16x8 v = *reinterpret_cast<const u16x8*>(base);
#pragma unroll
            for (int e = 0; e < 8; ++e) d[e] = bfu2f((unsigned short)v[e]);
        } else {
            ushort4 v = *reinterpret_cast<const ushort4*>(base);
            d[0] = bfu2f(v.x); d[1] = bfu2f(v.y); d[2] = bfu2f(v.z); d[3] = bfu2f(v.w);
        }
    };

    float dd = dinv[row], ws = dd * dd;
    int beg = rowStart[row], end = rowStart[row + 1];
    float a0[PL], a1[PL], a2[PL], a3[PL];
    float t0[PL], t1[PL], t2[PL], t3[PL], t4[PL], t5[PL], t6[PL], t7[PL];
    loadRow(row, t0);
#pragma unroll
    for (int p = 0; p < PL; ++p) { a0[p] = t0[p] * ws; a1[p] = 0.f; a2[p] = 0.f; a3[p] = 0.f; }

    int j = beg;
    for (; j + 8 <= end; j += 8) {
        int2 e0 = csr2[j], e1 = csr2[j + 1], e2 = csr2[j + 2], e3 = csr2[j + 3];
        int2 e4 = csr2[j + 4], e5 = csr2[j + 5], e6 = csr2[j + 6], e7 = csr2[j + 7];
        float w0 = __int_as_float(e0.y), w1 = __int_as_float(e1.y);
        float w2 = __int_as_float(e2.y), w3 = __int_as_float(e3.y);
        float w4 = __int_as_float(e4.y), w5 = __int_as_float(e5.y);
        float w6 = __int_as_float(e6.y), w7 = __int_as_float(e7.y);
        loadRow(e0.x, t0); loadRow(e1.x, t1); loadRow(e2.x, t2); loadRow(e3.x, t3);
        loadRow(e4.x, t4); loadRow(e5.x, t5); loadRow(e6.x, t6); loadRow(e7.x, t7);
#pragma unroll
        for (int p = 0; p < PL; ++p) {
            a0[p] += w0 * t0[p]; a1[p] += w1 * t1[p];
            a2[p] += w2 * t2[p]; a3[p] += w3 * t3[p];
            a0[p] += w4 * t4[p]; a1[p] += w5 * t5[p];
            a2[p] += w6 * t6[p]; a3[p] += w7 * t7[p];
        }
    }
    for (; j + 4 <= end; j += 4) {
        int2 e0 = csr2[j], e1 = csr2[j + 1], e2 = csr2[j + 2], e3 = csr2[j + 3];
        float w0 = __int_as_float(e0.y), w1 = __int_as_float(e1.y);
        float w2 = __int_as_float(e2.y), w3 = __int_as_float(e3.y);
        loadRow(e0.x, t0); loadRow(e1.x, t1); loadRow(e2.x, t2); loadRow(e3.x, t3);
#pragma unroll
        for (int p = 0; p < PL; ++p) {
            a0[p] += w0 * t0[p]; a1[p] += w1 * t1[p];
            a2[p] += w2 * t2[p]; a3[p] += w3 * t3[p];
        }
    }
    for (; j < end; ++j) {
        int2 e0 = csr2[j];
        float w = __int_as_float(e0.y);
        loadRow(e0.x, t0);
#pragma unroll
        for (int p = 0; p < PL; ++p) a0[p] += w * t0[p];
    }
    const float* bp = nullptr;
    if (BIAS) bp = (row < SPAN_P) ? b0 : ((row < NP) ? b1 : b2);
#pragma unroll
    for (int p = 0; p < PL; ++p) {
        a0[p] += (a1[p] + a2[p]) + a3[p];
        if (BIAS) a0[p] += bp[c0 + p];
    }
    if constexpr (OUTBF) {
        unsigned short* o = (unsigned short*)outv + ((size_t)row * C - ooff) + c0;
        if constexpr (PL == 8) {
            u16x8 ov;
#pragma unroll
            for (int e = 0; e < 8; ++e) ov[e] = f2bfu(a0[e]);
            *reinterpret_cast<u16x8*>(o) = ov;
        } else {
            ushort4 ov = {f2bfu(a0[0]), f2bfu(a0[1]), f2bfu(a0[2]), f2bfu(a0[3])};
            *reinterpret_cast<ushort4*>(o) = ov;
        }
    } else {
        float* o = (float*)outv + ((size_t)row * C - ooff) + c0;
#pragma unroll
        for (int q = 0; q < PL / 4; ++q) {
            float4 ov = {a0[q * 4 + 0], a0[q * 4 + 1], a0[q * 4 + 2], a0[q * 4 + 3]};
            *reinterpret_cast<float4*>(o + q * 4) = ov;
        }
    }
}

// ---------------- BN stats over merged [NTOT][256]: blockIdx.y = graph 0..2 ----------------
__global__ __launch_bounds__(256) void k_bn_stats3(const unsigned short* __restrict__ x,
                                                   float* __restrict__ bnbuf) {
    __shared__ float smS[8][256];
    __shared__ float smQ[8][256];
    int t = threadIdx.x;
    int y = blockIdx.y;
    int off = (y < 2) ? y * SPAN_P : NP;
    int span = (y < 2) ? SPAN_P : N_MOL;
    int g = t >> 5;
    int lane = t & 31;
    int c0 = lane * 8;
    float s[8], q[8];
#pragma unroll
    for (int e = 0; e < 8; ++e) { s[e] = 0.f; q[e] = 0.f; }
    int stride = gridDim.x * 8;
    for (int r = blockIdx.x * 8 + g; r < span; r += stride) {
        u16x8 v = *reinterpret_cast<const u16x8*>(x + ((size_t)(off + r)) * 256 + c0);
#pragma unroll
        for (int e = 0; e < 8; ++e) {
            float f = bfu2f((unsigned short)v[e]);
            s[e] += f; q[e] += f * f;
        }
    }
#pragma unroll
    for (int e = 0; e < 8; ++e) { smS[g][c0 + e] = s[e]; smQ[g][c0 + e] = q[e]; }
    __syncthreads();
    float S = 0.f, Q = 0.f;
#pragma unroll
    for (int g2 = 0; g2 < 8; ++g2) { S += smS[g2][t]; Q += smQ[g2][t]; }
    atomAddF(&bnbuf[y * 512 + t], S);
    atomAddF(&bnbuf[y * 512 + 256 + t], Q);
}

// 3-graph coef: coef[g][j]=gamma*rstd, coef[g][256+j]=beta-mean*scale; self-zeroes bnbuf
__global__ void k_bn_coef3(float* __restrict__ bnbuf,
                           const float* __restrict__ g0, const float* __restrict__ be0,
                           const float* __restrict__ g1, const float* __restrict__ be1,
                           const float* __restrict__ g2, const float* __restrict__ be2,
                           float* __restrict__ coef, float invN01, float invN2) {
    int gg = blockIdx.x;
    int j = threadIdx.x;
    const float* gp = (gg == 0) ? g0 : ((gg == 1) ? g1 : g2);
    const float* bp = (gg == 0) ? be0 : ((gg == 1) ? be1 : be2);
    float invN = (gg < 2) ? invN01 : invN2;
    float* s = bnbuf + gg * 512;
    float m = s[j] * invN;
    float v = s[256 + j] * invN - m * m;
    float r = rsqrtf(fmaxf(v, 0.f) + 1e-5f);
    float sc = gp[j] * r;
    coef[gg * 512 + j] = sc;
    coef[gg * 512 + 256 + j] = bp[j] - m * sc;
    s[j] = 0.f;
    s[256 + j] = 0.f;
}

// ---------------- atom encoder (writes local [N_MOL][256] bf16) ----------------
__global__ __launch_bounds__(256) void k_atom_enc(const int* __restrict__ mol_x,
                                                  const float* __restrict__ emb,
                                                  unsigned short* __restrict__ h) {
    __shared__ int sidx[4][NF];
    int t = threadIdx.x;
    if (t < 4 * NF) sidx[t / NF][t % NF] = mol_x[(blockIdx.x * 4 + t / NF) * NF + t % NF];
    __syncthreads();
    int r = t >> 6, lane = t & 63;
    int c0 = lane * 4;
    int row = blockIdx.x * 4 + r;
    float4 s = {0.f, 0.f, 0.f, 0.f};
#pragma unroll
    for (int f = 0; f < NF; ++f) {
        const float4 v = *reinterpret_cast<const float4*>(emb + ((size_t)f * NV + sidx[r][f]) * DH + c0);
        s.x += v.x; s.y += v.y; s.z += v.z; s.w += v.w;
    }
    ushort4 ov = {f2bfu(s.x), f2bfu(s.y), f2bfu(s.z), f2bfu(s.w)};
    *reinterpret_cast<ushort4*>(h + (size_t)row * DH + c0) = ov;
}

// ---------------- segment pool over f32 mol features [N_MOL][128] ----------------
__global__ __launch_bounds__(128) void k_pool_seg_f(const float* __restrict__ mfeat,
                                                    const int* __restrict__ batch,
                                                    float* __restrict__ mpool) {
    __shared__ int sr[2];
    __shared__ float smS[8][128];
    int b = blockIdx.x, t = threadIdx.x;
    if (t < 2) {
        int target = b + t;
        int lo = 0, hi = N_MOL;
        while (lo < hi) {
            int mid = (lo + hi) >> 1;
            if (batch[mid] < target) lo = mid + 1; else hi = mid;
        }
        sr[t] = lo;
    }
    __syncthreads();
    int g = t >> 4;
    int lane = t & 15;
    int c0 = lane * 8;
    float s[8];
#pragma unroll
    for (int e = 0; e < 8; ++e) s[e] = 0.f;
    int e1 = sr[1];
    for (int i = sr[0] + g; i < e1; i += 8) {
        const float4 v0 = *reinterpret_cast<const float4*>(mfeat + (size_t)i * 128 + c0);
        const float4 v1 = *reinterpret_cast<const float4*>(mfeat + (size_t)i * 128 + c0 + 4);
        s[0] += v0.x; s[1] += v0.y; s[2] += v0.z; s[3] += v0.w;
        s[4] += v1.x; s[5] += v1.y; s[6] += v1.z; s[7] += v1.w;
    }
#pragma unroll
    for (int e = 0; e < 8; ++e) smS[g][c0 + e] = s[e];
    __syncthreads();
    float S = 0.f;
#pragma unroll
    for (int g2 = 0; g2 < 8; ++g2) S += smS[g2][t];
    mpool[(size_t)b * 128 + t] = S;
}

// ---------------- head: conv1 ----------------
__global__ __launch_bounds__(64) void k_conv1(const float* __restrict__ dfeat,
                                              const float* __restrict__ mpool,
                                              const float* __restrict__ sfeat,
                                              const int* __restrict__ drug_idx,
                                              const int* __restrict__ dis_idx,
                                              const float* __restrict__ W,
                                              const float* __restrict__ bias,
                                              float* __restrict__ y1) {
    __shared__ float xs[3][128];
    __shared__ float w[54];
    __shared__ float bb[6];
    int b = blockIdx.x, t = threadIdx.x;
    int di = drug_idx[b], si = dis_idx[b];
    const float* r0 = dfeat + (size_t)di * 128;
    const float* r1 = mpool + (size_t)b * 128;
    const float* r2 = sfeat + (size_t)si * 128;
    xs[0][t] = r0[t]; xs[0][t + 64] = r0[t + 64];
    xs[1][t] = r1[t]; xs[1][t + 64] = r1[t + 64];
    xs[2][t] = r2[t]; xs[2][t + 64] = r2[t + 64];
    if (t < 54) w[t] = W[t];
    if (t < 6) bb[t] = bias[t];
    __syncthreads();
    int l0 = 2 * t, l1 = l0 + 1;
#pragma unroll
    for (int o = 0; o < 6; ++o) {
        float ya = bb[o], yb = bb[o];
#pragma unroll
        for (int i = 0; i < 3; ++i) {
            const float* wi = &w[(o * 3 + i) * 3];
            float xm1 = (l0 > 0) ? xs[i][l0 - 1] : 0.f;
            float x0 = xs[i][l0];
            float x1 = xs[i][l1];
            float x2 = (l1 < 127) ? xs[i][l1 + 1] : 0.f;
            ya += wi[0] * xm1 + wi[1] * x0 + wi[2] * x1;
            yb += wi[0] * x0 + wi[1] * x1 + wi[2] * x2;
        }
        y1[((size_t)b * 6 + o) * 64 + t] = fmaxf(ya, yb);
    }
}

// hb per 'which': [0..5]=sum [8..13]=sumsq [16..21]=mean [24..29]=rstd; grid (6,16)
__global__ __launch_bounds__(256) void k_head_stats(const float* __restrict__ y,
                                                    float* __restrict__ hb, int which, int L) {
    int o = blockIdx.x;
    int b0 = blockIdx.y * 256;
    int t = threadIdx.x;
    float s = 0.f, q = 0.f;
    int per = 256 * L;
    for (int idx = t; idx < per; idx += 256) {
        int b = b0 + idx / L;
        int l = idx - (idx / L) * L;
        float v = y[((size_t)b * 6 + o) * L + l];
        s += v; q += v * v;
    }
    __shared__ float sms[4], smq[4];
#pragma unroll
    for (int off = 32; off > 0; off >>= 1) {
        s += __shfl_down(s, off);
        q += __shfl_down(q, off);
    }
    if ((t & 63) == 0) { sms[t >> 6] = s; smq[t >> 6] = q; }
    __syncthreads();
    if (t == 0) {
        float S = 0.f, Q = 0.f;
        for (int i = 0; i < 4; ++i) { S += sms[i]; Q += smq[i]; }
        atomAddF(hb + which * 32 + o, S);
        atomAddF(hb + which * 32 + 8 + o, Q);
    }
}

__global__ void k_bn_fin(float* __restrict__ hb, int which, float invN) {
    int o = threadIdx.x;
    if (o >= 6) return;
    float* p = hb + which * 32;
    float m = p[o] * invN;
    float v = p[8 + o] * invN - m * m;
    p[16 + o] = m;
    p[24 + o] = rsqrtf(fmaxf(v, 0.f) + 1e-5f);
}

// ---------------- head: conv2 ----------------
__global__ __launch_bounds__(64) void k_conv2(const float* __restrict__ y1,
                                              const float* __restrict__ hb,
                                              const float* __restrict__ g1,
                                              const float* __restrict__ be1,
                                              const float* __restrict__ W,
                                              const float* __restrict__ bias,
                                              float* __restrict__ y2) {
    __shared__ float xs[6][64];
    __shared__ float w[108];
    __shared__ float bb[6];
    int b = blockIdx.x, t = threadIdx.x;
    const float* mean = hb + 16;
    const float* rstd = hb + 24;
    for (int idx = t; idx < 384; idx += 64) {
        int o = idx >> 6, l = idx & 63;
        float v = y1[((size_t)b * 6 + o) * 64 + l];
        v = g1[o] * (v - mean[o]) * rstd[o] + be1[o];
        xs[o][l] = fmaxf(v, 0.f);
    }
    for (int idx = t; idx < 108; idx += 64) w[idx] = W[idx];
    if (t < 6) bb[t] = bias[t];
    __syncthreads();
    if (t >= 32) return;
    int l0 = 2 * t, l1 = l0 + 1;
#pragma unroll
    for (int o = 0; o < 6; ++o) {
        float ya = bb[o], yb = bb[o];
#pragma unroll
        for (int i = 0; i < 6; ++i) {
            const float* wi = &w[(o * 6 + i) * 3];
            float xm1 = (l0 > 0) ? xs[i][l0 - 1] : 0.f;
            float x0 = xs[i][l0];
            float x1 = xs[i][l1];
            float x2 = (l1 < 63) ? xs[i][l1 + 1] : 0.f;
            ya += wi[0] * xm1 + wi[1] * x0 + wi[2] * x1;
            yb += wi[0] * x0 + wi[1] * x1 + wi[2] * x2;
        }
        y2[((size_t)b * 6 + o) * 32 + t] = fmaxf(ya, yb);
    }
}

// ---------------- head final ----------------
__global__ __launch_bounds__(128) void k_head(const float* __restrict__ y2,
                                              const float* __restrict__ hb,
                                              const float* __restrict__ g2,
                                              const float* __restrict__ be2,
                                              const float* __restrict__ l1W,
                                              const float* __restrict__ l1b,
                                              const float* __restrict__ l2W,
                                              const float* __restrict__ l2b,
                                              float* __restrict__ out) {
    __shared__ float fs[192];
    __shared__ float sm[2];
    int b = blockIdx.x, t = threadIdx.x;
    const float* mean = hb + 32 + 16;
    const float* rstd = hb + 32 + 24;
    for (int idx = t; idx < 192; idx += 128) {
        int o = idx >> 5, l = idx & 31;
        float v = y2[((size_t)b * 6 + o) * 32 + l];
        v = g2[o] * (v - mean[o]) * rstd[o] + be2[o];
        fs[idx] = fmaxf(v, 0.f);
    }
    __syncthreads();
    float h = l1b[t];
    for (int k = 0; k < 192; ++k)
        h += fs[k] * l1W[k * 128 + t];
    h = fmaxf(h, 0.f);
    float p = h * l2W[t];
#pragma unroll
    for (int off = 32; off > 0; off >>= 1) p += __shfl_down(p, off);
    if ((t & 63) == 0) sm[t >> 6] = p;
    __syncthreads();
    if (t == 0) out[b] = sm[0] + sm[1] + l2b[0];
}

extern "C" void kernel_launch(void* const* d_in, const int* in_sizes, int n_in,
                              void* d_out, int out_size, void* d_ws, size_t ws_size,
                              hipStream_t stream) {
    float* out = (float*)d_out;
    if (n_in != 52) { k_sentinel<<<16, 256, 0, stream>>>(out, out_size, -111.f); return; }
    if (in_sizes[0] != N_DRUG * 128 || in_sizes[29] != NF * NV * DH || in_sizes[48] != 192 * 128) {
        k_sentinel<<<16, 256, 0, stream>>>(out, out_size, -222.f); return;
    }

    char* w = (char*)d_ws;
    auto alloc = [&](size_t bytes) { char* p = w; w += (bytes + 255) & ~(size_t)255; return p; };
    unsigned short* B1 = (unsigned short*)alloc((size_t)NTOT * 256 * 2);
    unsigned short* B2 = (unsigned short*)alloc((size_t)NTOT * 256 * 2);
    float* fcat = (float*)B1;   // alias: B1 dead after L2 GEMM; L2 gather writes fcat
    float* mpool = (float*)alloc((size_t)BATCH * 128 * 4);
    int*   cnt      = (int*)alloc((size_t)NTOT * 4);
    float* dinv     = (float*)alloc((size_t)NTOT * 4);
    int*   rowStart = (int*)alloc((size_t)(NTOT + 1) * 4);
    int*   cursor   = (int*)alloc((size_t)NTOT * 4);
    int2*  csr2     = (int2*)alloc((size_t)ETOT * 8);
    int*   bsum     = (int*)alloc(1024 * 4);
    float* bnbuf    = (float*)alloc(1536 * 4);
    float* coef     = (float*)alloc(1536 * 4);
    unsigned short* drT0 = (unsigned short*)alloc((size_t)128 * 256 * 2);
    unsigned short* drT1 = (unsigned short*)alloc((size_t)256 * 256 * 2);
    unsigned short* drT2 = (unsigned short*)alloc((size_t)256 * 128 * 2);
    unsigned short* diT0 = (unsigned short*)alloc((size_t)128 * 256 * 2);
    unsigned short* diT1 = (unsigned short*)alloc((size_t)256 * 256 * 2);
    unsigned short* diT2 = (unsigned short*)alloc((size_t)256 * 128 * 2);
    unsigned short* moT0 = (unsigned short*)alloc((size_t)256 * 256 * 2);
    unsigned short* moT1 = (unsigned short*)alloc((size_t)256 * 256 * 2);
    unsigned short* moT2 = (unsigned short*)alloc((size_t)256 * 128 * 2);
    float* hstat = (float*)alloc(64 * 4);
    float* y1    = (float*)alloc((size_t)BATCH * 6 * 64 * 4);
    float* y2    = (float*)alloc((size_t)BATCH * 6 * 32 * 4);
    if ((size_t)(w - (char*)d_ws) > ws_size) {
        k_sentinel<<<16, 256, 0, stream>>>(out, out_size, -333.f); return;
    }

    const float* drug_x  = (const float*)d_in[0];
    const int* drug_ei   = (const int*)d_in[1];
    const int* drug_idx  = (const int*)d_in[2];
    const float* dis_x   = (const float*)d_in[3];
    const int* dis_ei    = (const int*)d_in[4];
    const int* dis_idx   = (const int*)d_in[5];
    const int* mol_x     = (const int*)d_in[6];
    const int* mol_ei    = (const int*)d_in[7];
    const int* mol_b     = (const int*)d_in[8];
    const float *dr_W0 = (const float*)d_in[9], *dr_W1 = (const float*)d_in[10], *dr_W2 = (const float*)d_in[11];
    const float *dr_b2 = (const float*)d_in[14];
    const float *dr_g0 = (const float*)d_in[15], *dr_g1 = (const float*)d_in[16];
    const float *dr_be0 = (const float*)d_in[17], *dr_be1 = (const float*)d_in[18];
    const float *di_W0 = (const float*)d_in[19], *di_W1 = (const float*)d_in[20], *di_W2 = (const float*)d_in[21];
    const float *di_b2 = (const float*)d_in[24];
    const float *di_g0 = (const float*)d_in[25], *di_g1 = (const float*)d_in[26];
    const float *di_be0 = (const float*)d_in[27], *di_be1 = (const float*)d_in[28];
    const float* mol_emb = (const float*)d_in[29];
    const float *mo_W0 = (const float*)d_in[30], *mo_W1 = (const float*)d_in[31], *mo_W2 = (const float*)d_in[32];
    const float *mo_b2 = (const float*)d_in[35];
    const float *mo_g0 = (const float*)d_in[36], *mo_g1 = (const float*)d_in[37];
    const float *mo_be0 = (const float*)d_in[38], *mo_be1 = (const float*)d_in[39];
    const float *c1_W = (const float*)d_in[40], *c1_b = (const float*)d_in[41];
    const float *c1_g = (const float*)d_in[42], *c1_be = (const float*)d_in[43];
    const float *c2_W = (const float*)d_in[44], *c2_b = (const float*)d_in[45];
    const float *c2_g = (const float*)d_in[46], *c2_be = (const float*)d_in[47];
    const float *l1_W = (const float*)d_in[48], *l1_b = (const float*)d_in[49];
    const float *l2_W = (const float*)d_in[50], *l2_b = (const float*)d_in[51];

    const float invN01 = 1.0f / (float)N_DRUG;
    const float invNM  = 1.0f / (float)N_MOL;
    const long long MOFF = (long long)NP * 128;

    hipMemsetAsync(bnbuf, 0, 1536 * sizeof(float), stream);

    // ---- inputs into B1: drugdis [NP][128] @0, mol [N_MOL][256] @MOFF ----
    k_cast_pair<<<(NP * 32 + 255) / 256, 256, 0, stream>>>(drug_x, dis_x, B1);
    k_atom_enc<<<N_MOL / 4, 256, 0, stream>>>(mol_x, mol_emb, B1 + MOFF);

    // ---- merged CSR ----
    hipMemsetAsync(cnt, 0, (size_t)NTOT * sizeof(int), stream);
    k_count3<<<(ETOT + 255) / 256, 256, 0, stream>>>(drug_ei, dis_ei, mol_ei, cnt);
    int nb = (NTOT + 255) / 256;
    k_scan1<<<nb, 256, 0, stream>>>(cnt, rowStart, bsum, dinv, NTOT);
    k_scan2b<<<1, 256, 0, stream>>>(bsum, nb);
    k_scan3<<<nb, 256, 0, stream>>>(rowStart, cursor, bsum, NTOT, ETOT);
    k_fill3<<<(ETOT + 255) / 256, 256, 0, stream>>>(drug_ei, dis_ei, mol_ei, dinv, cursor, csr2);

    // ---- weights ----
    int wt1 = 128 * 256 + 256 * 256 + 256 * 128;
    int wt2 = 256 * 256 + 256 * 256 + 256 * 128;
    k_wcast3<<<(wt1 + 255) / 256, 256, 0, stream>>>(dr_W0, dr_W1, dr_W2, drT0, drT1, drT2, 128);
    k_wcast3<<<(wt1 + 255) / 256, 256, 0, stream>>>(di_W0, di_W1, di_W2, diT0, diT1, diT2, 128);
    k_wcast3<<<(wt2 + 255) / 256, 256, 0, stream>>>(mo_W0, mo_W1, mo_W2, moT0, moT1, moT2, 256);

    // ---- L0: gathers (agg-first) B1 -> B2, one merged GEMM B2 -> B1[NTOT][256] (+stats) ----
    k_gather<128, 0, 1><<<NP / 8, 256, 0, stream>>>(B1, 0, dinv, nullptr, nullptr, nullptr,
                                                    csr2, rowStart, B2, 0, 0, NP);
    k_gather<256, 0, 1><<<N_MOL / 8, 256, 0, stream>>>(B1, MOFF, dinv, nullptr, nullptr, nullptr,
                                                       csr2, rowStart, B2, MOFF, NP, NTOT);
    k_gemm_mfma<0, 1><<<dim3(2, 826), 256, 0, stream>>>(B2, drT0, diT0, moT0, nullptr,
        B1, bnbuf, 157, 314, SPAN_P, NP, N_DRUG, N_DIS, N_MOL, 0, 128, 256, MOFF, NP, 256);
    k_bn_coef3<<<3, 256, 0, stream>>>(bnbuf, dr_g0, dr_be0, di_g0, di_be0, mo_g0, mo_be0,
                                      coef, invN01, invNM);
    // ---- L1 merged ----
    k_gemm_mfma<1, 0><<<dim3(2, 826), 256, 0, stream>>>(B1, drT1, diT1, moT1, coef,
        B2, nullptr, 157, 314, SPAN_P, NP, N_DRUG, N_DIS, N_MOL, 0, 256, 256, 0, 0, 256);
    k_gather<256, 0, 1><<<NTOT / 8, 256, 0, stream>>>(B2, 0, dinv, nullptr, nullptr, nullptr,
                                                      csr2, rowStart, B1, 0, 0, NTOT);
    k_bn_stats3<<<dim3(256, 3), 256, 0, stream>>>(B1, bnbuf);
    k_bn_coef3<<<3, 256, 0, stream>>>(bnbuf, dr_g1, dr_be1, di_g1, di_be1, mo_g1, mo_be1,
                                      coef, invN01, invNM);
    // ---- L2 merged ----
    k_gemm_mfma<1, 0><<<dim3(1, 826), 256, 0, stream>>>(B1, drT2, diT2, moT2, coef,
        B2, nullptr, 157, 314, SPAN_P, NP, N_DRUG, N_DIS, N_MOL, 0, 256, 256, 0, 0, 128);
    k_gather<128, 1, 0><<<NTOT / 8, 256, 0, stream>>>(B2, 0, dinv, dr_b2, di_b2, mo_b2,
                                                      csr2, rowStart, fcat, 0, 0, NTOT);
    k_pool_seg_f<<<BATCH, 128, 0, stream>>>(fcat + (size_t)NP * 128, mol_b, mpool);

    // ---- head ----
    const float* dfeat = fcat;
    const float* sfeat = fcat + (size_t)SPAN_P * 128;
    hipMemsetAsync(hstat, 0, 64 * 4, stream);
    k_conv1<<<BATCH, 64, 0, stream>>>(dfeat, mpool, sfeat, drug_idx, dis_idx, c1_W, c1_b, y1);
    k_head_stats<<<dim3(6, BATCH / 256), 256, 0, stream>>>(y1, hstat, 0, 64);
    k_bn_fin<<<1, 8, 0, stream>>>(hstat, 0, 1.0f / (BATCH * 64.0f));
    k_conv2<<<BATCH, 64, 0, stream>>>(y1, hstat, c1_g, c1_be, c2_W, c2_b, y2);
    k_head_stats<<<dim3(6, BATCH / 256), 256, 0, stream>>>(y2, hstat, 1, 32);
    k_bn_fin<<<1, 8, 0, stream>>>(hstat, 1, 1.0f / (BATCH * 32.0f));
    k_head<<<BATCH, 128, 0, stream>>>(y2, hstat, c2_g, c2_be, l1_W, l1_b, l2_W, l2_b, out);
}

// Round 16
// 546.645 us; speedup vs baseline: 1.0907x; 1.0221x over previous
//
#include <hip/hip_runtime.h>
#include <hip/hip_bf16.h>

#define N_DRUG 20000
#define N_DIS  20000
#define E_G    320000
#define BATCH  4096
#define N_MOL  65536
#define E_MOL  262144
#define NF     9
#define NV     128
#define DH     256
#define SPAN_P 20096                 // 157*128 pad per drug/dis graph
#define NP     40192                 // 2*SPAN_P
#define NTOT   105728                // NP + N_MOL
#define ETOT   902144                // 2*E_G + E_MOL

typedef short s16x8 __attribute__((ext_vector_type(8)));
typedef unsigned short u16x8 __attribute__((ext_vector_type(8)));
typedef float f32x4 __attribute__((ext_vector_type(4)));

typedef __attribute__((address_space(1))) const void gvoid_t;
typedef __attribute__((address_space(3))) void lvoid_t;

__device__ __forceinline__ float bfu2f(unsigned short u) {
    return __uint_as_float(((unsigned int)u) << 16);
}
__device__ __forceinline__ unsigned short f2bfu(float f) {
    __hip_bfloat16 b = __float2bfloat16(f);
    return *reinterpret_cast<unsigned short*>(&b);
}
__device__ __forceinline__ void atomAddF(float* p, float v) { unsafeAtomicAdd(p, v); }

// ---------------- misc ----------------
__global__ void k_sentinel(float* out, int n, float v) {
    int i = blockIdx.x * 256 + threadIdx.x;
    if (i < n) out[i] = v;
}

// drug+dis cast into padded bf16 [NP][128]; pad rows zero
__global__ void k_cast_pair(const float* __restrict__ a, const float* __restrict__ b,
                            unsigned short* __restrict__ out) {
    int i4 = blockIdx.x * 256 + threadIdx.x;
    if (i4 >= NP * 32) return;
    int row = i4 >> 5, c4 = (i4 & 31) * 4;
    float4 v = {0.f, 0.f, 0.f, 0.f};
    if (row < N_DRUG) v = *reinterpret_cast<const float4*>(a + (size_t)row * 128 + c4);
    else if (row >= SPAN_P && row < SPAN_P + N_DIS)
        v = *reinterpret_cast<const float4*>(b + (size_t)(row - SPAN_P) * 128 + c4);
    ushort4 o = {f2bfu(v.x), f2bfu(v.y), f2bfu(v.z), f2bfu(v.w)};
    *reinterpret_cast<ushort4*>(out + (size_t)row * 128 + c4) = o;
}

// 3 weight transposes: W[K][N] f32 -> Wt[N][K] bf16
__global__ void k_wcast3(const float* __restrict__ W0, const float* __restrict__ W1,
                         const float* __restrict__ W2,
                         unsigned short* __restrict__ T0, unsigned short* __restrict__ T1,
                         unsigned short* __restrict__ T2, int Cin) {
    int i = blockIdx.x * 256 + threadIdx.x;
    int t0 = Cin * 256, t1 = 256 * 256, t2 = 256 * 128;
    if (i < t0) {
        int k = i / 256, c = i - k * 256;
        T0[(size_t)c * Cin + k] = f2bfu(W0[i]);
    } else if (i < t0 + t1) {
        int e = i - t0;
        int k = e / 256, c = e - k * 256;
        T1[(size_t)c * 256 + k] = f2bfu(W1[e]);
    } else if (i < t0 + t1 + t2) {
        int e = i - t0 - t1;
        int k = e / 128, c = e - k * 128;
        T2[(size_t)c * 256 + k] = f2bfu(W2[e]);
    }
}

// ---------------- merged-graph degree / CSR ----------------
__global__ void k_count3(const int* __restrict__ eA, const int* __restrict__ eB,
                         const int* __restrict__ eC, int* __restrict__ cnt) {
    int e = blockIdx.x * 256 + threadIdx.x;
    if (e >= ETOT) return;
    int d;
    if (e < E_G) d = eA[E_G + e];
    else if (e < 2 * E_G) d = eB[E_G + (e - E_G)] + SPAN_P;
    else d = eC[E_MOL + (e - 2 * E_G)] + NP;
    atomicAdd(&cnt[d], 1);
}

__global__ void k_scan1(const int* __restrict__ cnt, int* __restrict__ rowStart,
                        int* __restrict__ bsum, float* __restrict__ dinv, int n) {
    __shared__ int sh[256];
    int i = blockIdx.x * 256 + threadIdx.x;
    int v = (i < n) ? cnt[i] : 0;
    if (i < n) dinv[i] = rsqrtf(1.0f + (float)v);
    sh[threadIdx.x] = v;
    __syncthreads();
    for (int off = 1; off < 256; off <<= 1) {
        int t = (threadIdx.x >= off) ? sh[threadIdx.x - off] : 0;
        __syncthreads();
        sh[threadIdx.x] += t;
        __syncthreads();
    }
    if (i < n) rowStart[i] = sh[threadIdx.x] - v;
    if (threadIdx.x == 255) bsum[blockIdx.x] = sh[255];
}
// single-block multi-chunk exclusive scan of nb partials
__global__ void k_scan2b(int* __restrict__ bsum, int nb) {
    __shared__ int sh[256];
    __shared__ int carry;
    int t = threadIdx.x;
    if (t == 0) carry = 0;
    __syncthreads();
    for (int c0 = 0; c0 < nb; c0 += 256) {
        int v = (c0 + t < nb) ? bsum[c0 + t] : 0;
        sh[t] = v;
        __syncthreads();
        for (int off = 1; off < 256; off <<= 1) {
            int u = (t >= off) ? sh[t - off] : 0;
            __syncthreads();
            sh[t] += u;
            __syncthreads();
        }
        if (c0 + t < nb) bsum[c0 + t] = carry + sh[t] - v;
        __syncthreads();
        if (t == 0) carry += sh[255];
        __syncthreads();
    }
}
__global__ void k_scan3(int* __restrict__ rowStart, int* __restrict__ cursor,
                        const int* __restrict__ bsum, int n, int E) {
    int i = blockIdx.x * 256 + threadIdx.x;
    if (i < n) {
        int r = rowStart[i] + bsum[blockIdx.x];
        rowStart[i] = r;
        cursor[i] = r;
    }
    if (i == 0) rowStart[n] = E;
}
__global__ void k_fill3(const int* __restrict__ eA, const int* __restrict__ eB,
                        const int* __restrict__ eC, const float* __restrict__ dinv,
                        int* __restrict__ cursor, int2* __restrict__ csr2) {
    int e = blockIdx.x * 256 + threadIdx.x;
    if (e >= ETOT) return;
    int s, d;
    if (e < E_G) { s = eA[e]; d = eA[E_G + e]; }
    else if (e < 2 * E_G) { int i = e - E_G; s = eB[i] + SPAN_P; d = eB[E_G + i] + SPAN_P; }
    else { int i = e - 2 * E_G; s = eC[i] + NP; d = eC[E_MOL + i] + NP; }
    int p = atomicAdd(&cursor[d], 1);
    csr2[p] = make_int2(s, __float_as_int(dinv[s] * dinv[d]));
}

// ---------------- MFMA GEMM: 3 graphs batched, per-graph K / A-base ----------------
template<int AFFINE, int STATS>
__global__ __launch_bounds__(256) void k_gemm_mfma(const unsigned short* __restrict__ A,
                                                   const unsigned short* __restrict__ Bt0,
                                                   const unsigned short* __restrict__ Bt1,
                                                   const unsigned short* __restrict__ Bt2,
                                                   const float* __restrict__ coef,
                                                   unsigned short* __restrict__ Cout,
                                                   float* __restrict__ bnbuf,
                                                   int tb0, int tb1, int boff1, int boff2,
                                                   int m0, int m1, int m2, int gbase,
                                                   int K01, int K2, long long abase2,
                                                   int arow2, int N) {
    __shared__ unsigned short Al[2][4][128][8];
    __shared__ unsigned short Bl[2][4][128][8];
    __shared__ float csc[256], csh[256];
    const int tid = threadIdx.x;
    const int y = blockIdx.y;
    const int bm = y * 128;
    const int bn = blockIdx.x * 128;
    const int g = (y >= tb1) ? 2 : ((y >= tb0) ? 1 : 0);
    const int Kg = (g == 2) ? K2 : K01;
    const int boff = (g == 0) ? 0 : ((g == 1) ? boff1 : boff2);
    const int Mloc = (g == 0) ? m0 : ((g == 1) ? m1 : m2);
    const int lbm = bm - boff;
    const unsigned short* Ag = (g == 2) ? (A + abase2) : A;
    const int arow = (g == 2) ? arow2 : 0;
    const unsigned short* Bt = (g == 0) ? Bt0 : ((g == 1) ? Bt1 : Bt2);
    const int gs = gbase + g;
    const int w = tid >> 6, l = tid & 63;
    const int wrow = (w >> 1) * 64, wcol = (w & 1) * 64;
    const int kg = l >> 4, lr = l & 15;

    if (AFFINE) {
        for (int i = tid; i < Kg; i += 256) {
            csc[i] = coef[gs * 512 + i];
            csh[i] = coef[gs * 512 + 256 + i];
        }
    }
    if (lbm + 128 > Mloc) {
        for (int s = tid; s < 1024; s += 256) {
            u16x8 z = {0, 0, 0, 0, 0, 0, 0, 0};
            *reinterpret_cast<u16x8*>(&Al[0][0][0][0] + s * 8) = z;
        }
    }
    __syncthreads();

    auto stage = [&](int buf, int k0) {
#pragma unroll
        for (int i = 0; i < 4; ++i) {
            int id = w * 4 + i;
            int koff = (id >> 1) & 3;
            int half = id & 1;
            int row = half * 64 + l;
            if (id < 8) {
                if (lbm + row < Mloc) {
                    const unsigned short* gsrc = Ag + (size_t)(bm - arow + row) * Kg + k0 + koff * 8;
                    __builtin_amdgcn_global_load_lds((gvoid_t*)gsrc,
                        (lvoid_t*)&Al[buf][koff][half * 64][0], 16, 0, 0);
                }
            } else {
                const unsigned short* gsrc = Bt + (size_t)(bn + row) * Kg + k0 + koff * 8;
                __builtin_amdgcn_global_load_lds((gvoid_t*)gsrc,
                    (lvoid_t*)&Bl[buf][koff][half * 64][0], 16, 0, 0);
            }
        }
    };

    f32x4 acc[4][4];
#pragma unroll
    for (int fm = 0; fm < 4; ++fm)
#pragma unroll
        for (int fn = 0; fn < 4; ++fn) acc[fm][fn] = f32x4{0.f, 0.f, 0.f, 0.f};

    stage(0, 0);
    __syncthreads();
    int nk = Kg >> 5;
    for (int t = 0; t < nk; ++t) {
        int cur = t & 1;
        if (t + 1 < nk) stage(cur ^ 1, (t + 1) * 32);
        s16x8 a[4], b[4];
#pragma unroll
        for (int fm = 0; fm < 4; ++fm)
            a[fm] = *reinterpret_cast<const s16x8*>(&Al[cur][kg][wrow + fm * 16 + lr][0]);
        if (AFFINE) {
            int k0 = t * 32;
            float sc[8], sh[8];
#pragma unroll
            for (int e = 0; e < 8; ++e) {
                sc[e] = csc[k0 + kg * 8 + e];
                sh[e] = csh[k0 + kg * 8 + e];
            }
#pragma unroll
            for (int fm = 0; fm < 4; ++fm)
#pragma unroll
                for (int e = 0; e < 8; ++e) {
                    float f = bfu2f((unsigned short)a[fm][e]);
                    a[fm][e] = (short)f2bfu(fmaxf(fmaf(sc[e], f, sh[e]), 0.f));
                }
        }
#pragma unroll
        for (int fn = 0; fn < 4; ++fn)
            b[fn] = *reinterpret_cast<const s16x8*>(&Bl[cur][kg][wcol + fn * 16 + lr][0]);
#pragma unroll
        for (int fm = 0; fm < 4; ++fm)
#pragma unroll
            for (int fn = 0; fn < 4; ++fn)
                acc[fm][fn] = __builtin_amdgcn_mfma_f32_16x16x32_bf16(a[fm], b[fn], acc[fm][fn], 0, 0, 0);
        __syncthreads();
    }
    // C/D layout: col = lane&15, row = (lane>>4)*4 + reg. Pad rows write 0.
#pragma unroll
    for (int fm = 0; fm < 4; ++fm)
#pragma unroll
        for (int r = 0; r < 4; ++r) {
            int row = bm + wrow + fm * 16 + kg * 4 + r;
#pragma unroll
            for (int fn = 0; fn < 4; ++fn) {
                int col = bn + wcol + fn * 16 + lr;
                Cout[(size_t)row * N + col] = f2bfu(acc[fm][fn][r]);
            }
        }
    if constexpr (STATS) {
        __shared__ float colS[128], colQ[128];
        if (tid < 128) { colS[tid] = 0.f; colQ[tid] = 0.f; }
        __syncthreads();
#pragma unroll
        for (int fn = 0; fn < 4; ++fn) {
            float s = 0.f, q = 0.f;
#pragma unroll
            for (int fm = 0; fm < 4; ++fm)
#pragma unroll
                for (int r = 0; r < 4; ++r) {
                    float v = acc[fm][fn][r];
                    s += v; q += v * v;
                }
            int cl = (w & 1) * 64 + fn * 16 + lr;
            atomicAdd(&colS[cl], s);
            atomicAdd(&colQ[cl], q);
        }
        __syncthreads();
        if (tid < 128) {
            atomAddF(&bnbuf[gs * 512 + bn + tid], colS[tid]);
            atomAddF(&bnbuf[gs * 512 + 256 + bn + tid], colQ[tid]);
        }
    }
}

// ---------------- CSR gather: 32-lane row groups, 8 rows/block, 8/4/1 unroll ----------------
template<int C, int BIAS, int OUTBF>
__global__ __launch_bounds__(256) void k_gather(const unsigned short* __restrict__ h,
                                                long long hoff,
                                                const float* __restrict__ dinv,
                                                const float* __restrict__ b0,
                                                const float* __restrict__ b1,
                                                const float* __restrict__ b2,
                                                const int2* __restrict__ csr2,
                                                const int* __restrict__ rowStart,
                                                void* __restrict__ outv, long long ooff,
                                                int rowoff, int rowend) {
    constexpr int PL = C / 32;
    int row = rowoff + blockIdx.x * 8 + (threadIdx.x >> 5);
    if (row >= rowend) return;
    int lane = threadIdx.x & 31;
    int c0 = lane * PL;

    auto loadRow = [&](int r, float* d) {
        const unsigned short* base = h + ((size_t)r * C - hoff) + c0;
        if constexpr (PL == 8) {
            u16x8 v = *reinterpret_cast<const u16x8*>(base);
#pragma unroll
            for (int e = 0; e < 8; ++e) d[e] = bfu2f((unsigned short)v[e]);
        } else {
            ushort4 v = *reinterpret_cast<const ushort4*>(base);
            d[0] = bfu2f(v.x); d[1] = bfu2f(v.y); d[2] = bfu2f(v.z); d[3] = bfu2f(v.w);
        }
    };

    float dd = dinv[row], ws = dd * dd;
    int beg = rowStart[row], end = rowStart[row + 1];
    float a0[PL], a1[PL], a2[PL], a3[PL];
    float t0[PL], t1[PL], t2[PL], t3[PL], t4[PL], t5[PL], t6[PL], t7[PL];
    loadRow(row, t0);
#pragma unroll
    for (int p = 0; p < PL; ++p) { a0[p] = t0[p] * ws; a1[p] = 0.f; a2[p] = 0.f; a3[p] = 0.f; }

    int j = beg;
    for (; j + 8 <= end; j += 8) {
        int2 e0 = csr2[j], e1 = csr2[j + 1], e2 = csr2[j + 2], e3 = csr2[j + 3];
        int2 e4 = csr2[j + 4], e5 = csr2[j + 5], e6 = csr2[j + 6], e7 = csr2[j + 7];
        float w0 = __int_as_float(e0.y), w1 = __int_as_float(e1.y);
        float w2 = __int_as_float(e2.y), w3 = __int_as_float(e3.y);
        float w4 = __int_as_float(e4.y), w5 = __int_as_float(e5.y);
        float w6 = __int_as_float(e6.y), w7 = __int_as_float(e7.y);
        loadRow(e0.x, t0); loadRow(e1.x, t1); loadRow(e2.x, t2); loadRow(e3.x, t3);
        loadRow(e4.x, t4); loadRow(e5.x, t5); loadRow(e6.x, t6); loadRow(e7.x, t7);
#pragma unroll
        for (int p = 0; p < PL; ++p) {
            a0[p] += w0 * t0[p]; a1[p] += w1 * t1[p];
            a2[p] += w2 * t2[p]; a3[p] += w3 * t3[p];
            a0[p] += w4 * t4[p]; a1[p] += w5 * t5[p];
            a2[p] += w6 * t6[p]; a3[p] += w7 * t7[p];
        }
    }
    for (; j + 4 <= end; j += 4) {
        int2 e0 = csr2[j], e1 = csr2[j + 1], e2 = csr2[j + 2], e3 = csr2[j + 3];
        float w0 = __int_as_float(e0.y), w1 = __int_as_float(e1.y);
        float w2 = __int_as_float(e2.y), w3 = __int_as_float(e3.y);
        loadRow(e0.x, t0); loadRow(e1.x, t1); loadRow(e2.x, t2); loadRow(e3.x, t3);
#pragma unroll
        for (int p = 0; p < PL; ++p) {
            a0[p] += w0 * t0[p]; a1[p] += w1 * t1[p];
            a2[p] += w2 * t2[p]; a3[p] += w3 * t3[p];
        }
    }
    for (; j < end; ++j) {
        int2 e0 = csr2[j];
        float w = __int_as_float(e0.y);
        loadRow(e0.x, t0);
#pragma unroll
        for (int p = 0; p < PL; ++p) a0[p] += w * t0[p];
    }
    const float* bp = nullptr;
    if (BIAS) bp = (row < SPAN_P) ? b0 : ((row < NP) ? b1 : b2);
#pragma unroll
    for (int p = 0; p < PL; ++p) {
        a0[p] += (a1[p] + a2[p]) + a3[p];
        if (BIAS) a0[p] += bp[c0 + p];
    }
    if constexpr (OUTBF) {
        unsigned short* o = (unsigned short*)outv + ((size_t)row * C - ooff) + c0;
        if constexpr (PL == 8) {
            u16x8 ov;
#pragma unroll
            for (int e = 0; e < 8; ++e) ov[e] = f2bfu(a0[e]);
            *reinterpret_cast<u16x8*>(o) = ov;
        } else {
            ushort4 ov = {f2bfu(a0[0]), f2bfu(a0[1]), f2bfu(a0[2]), f2bfu(a0[3])};
            *reinterpret_cast<ushort4*>(o) = ov;
        }
    } else {
        float* o = (float*)outv + ((size_t)row * C - ooff) + c0;
#pragma unroll
        for (int q = 0; q < PL / 4; ++q) {
            float4 ov = {a0[q * 4 + 0], a0[q * 4 + 1], a0[q * 4 + 2], a0[q * 4 + 3]};
            *reinterpret_cast<float4*>(o + q * 4) = ov;
        }
    }
}

// ---------------- indexed gather (C=128): only rows the head consumes ----------------
// slot b<4096 -> drug_idx[b]; else dis_idx[b-4096]+SPAN_P. Output compact [8192][128] f32.
__global__ __launch_bounds__(256) void k_gather_idx(const unsigned short* __restrict__ h,
                                                    const float* __restrict__ dinv,
                                                    const float* __restrict__ dr_b,
                                                    const float* __restrict__ di_b,
                                                    const int* __restrict__ drug_idx,
                                                    const int* __restrict__ dis_idx,
                                                    const int2* __restrict__ csr2,
                                                    const int* __restrict__ rowStart,
                                                    float* __restrict__ outc) {
    constexpr int PL = 4;
    int slot = blockIdx.x * 8 + (threadIdx.x >> 5);
    if (slot >= 2 * BATCH) return;
    int row = (slot < BATCH) ? drug_idx[slot] : (dis_idx[slot - BATCH] + SPAN_P);
    int lane = threadIdx.x & 31;
    int c0 = lane * PL;

    auto loadRow = [&](int r, float* d) {
        ushort4 v = *reinterpret_cast<const ushort4*>(h + (size_t)r * 128 + c0);
        d[0] = bfu2f(v.x); d[1] = bfu2f(v.y); d[2] = bfu2f(v.z); d[3] = bfu2f(v.w);
    };

    float dd = dinv[row], ws = dd * dd;
    int beg = rowStart[row], end = rowStart[row + 1];
    float a0[PL], a1[PL], a2[PL], a3[PL];
    float t0[PL], t1[PL], t2[PL], t3[PL], t4[PL], t5[PL], t6[PL], t7[PL];
    loadRow(row, t0);
#pragma unroll
    for (int p = 0; p < PL; ++p) { a0[p] = t0[p] * ws; a1[p] = 0.f; a2[p] = 0.f; a3[p] = 0.f; }

    int j = beg;
    for (; j + 8 <= end; j += 8) {
        int2 e0 = csr2[j], e1 = csr2[j + 1], e2 = csr2[j + 2], e3 = csr2[j + 3];
        int2 e4 = csr2[j + 4], e5 = csr2[j + 5], e6 = csr2[j + 6], e7 = csr2[j + 7];
        float w0 = __int_as_float(e0.y), w1 = __int_as_float(e1.y);
        float w2 = __int_as_float(e2.y), w3 = __int_as_float(e3.y);
        float w4 = __int_as_float(e4.y), w5 = __int_as_float(e5.y);
        float w6 = __int_as_float(e6.y), w7 = __int_as_float(e7.y);
        loadRow(e0.x, t0); loadRow(e1.x, t1); loadRow(e2.x, t2); loadRow(e3.x, t3);
        loadRow(e4.x, t4); loadRow(e5.x, t5); loadRow(e6.x, t6); loadRow(e7.x, t7);
#pragma unroll
        for (int p = 0; p < PL; ++p) {
            a0[p] += w0 * t0[p]; a1[p] += w1 * t1[p];
            a2[p] += w2 * t2[p]; a3[p] += w3 * t3[p];
            a0[p] += w4 * t4[p]; a1[p] += w5 * t5[p];
            a2[p] += w6 * t6[p]; a3[p] += w7 * t7[p];
        }
    }
    for (; j + 4 <= end; j += 4) {
        int2 e0 = csr2[j], e1 = csr2[j + 1], e2 = csr2[j + 2], e3 = csr2[j + 3];
        float w0 = __int_as_float(e0.y), w1 = __int_as_float(e1.y);
        float w2 = __int_as_float(e2.y), w3 = __int_as_float(e3.y);
        loadRow(e0.x, t0); loadRow(e1.x, t1); loadRow(e2.x, t2); loadRow(e3.x, t3);
#pragma unroll
        for (int p = 0; p < PL; ++p) {
            a0[p] += w0 * t0[p]; a1[p] += w1 * t1[p];
            a2[p] += w2 * t2[p]; a3[p] += w3 * t3[p];
        }
    }
    for (; j < end; ++j) {
        int2 e0 = csr2[j];
        float w = __int_as_float(e0.y);
        loadRow(e0.x, t0);
#pragma unroll
        for (int p = 0; p < PL; ++p) a0[p] += w * t0[p];
    }
    const float* bp = (row < SPAN_P) ? dr_b : di_b;
    float* o = outc + (size_t)slot * 128 + c0;
    float4 ov = {a0[0] + (a1[0] + a2[0]) + a3[0] + bp[c0 + 0],
                 a0[1] + (a1[1] + a2[1]) + a3[1] + bp[c0 + 1],
                 a0[2] + (a1[2] + a2[2]) + a3[2] + bp[c0 + 2],
                 a0[3] + (a1[3] + a2[3]) + a3[3] + bp[c0 + 3]};
    *reinterpret_cast<float4*>(o) = ov;
}

// ---------------- BN stats over merged [NTOT][256]: blockIdx.y = graph 0..2 ----------------
__global__ __launch_bounds__(256) void k_bn_stats3(const unsigned short* __restrict__ x,
                                                   float* __restrict__ bnbuf) {
    __shared__ float smS[8][256];
    __shared__ float smQ[8][256];
    int t = threadIdx.x;
    int y = blockIdx.y;
    int off = (y < 2) ? y * SPAN_P : NP;
    int span = (y < 2) ? SPAN_P : N_MOL;
    int g = t >> 5;
    int lane = t & 31;
    int c0 = lane * 8;
    float s[8], q[8];
#pragma unroll
    for (int e = 0; e < 8; ++e) { s[e] = 0.f; q[e] = 0.f; }
    int stride = gridDim.x * 8;
    for (int r = blockIdx.x * 8 + g; r < span; r += stride) {
        u16x8 v = *reinterpret_cast<const u16x8*>(x + ((size_t)(off + r)) * 256 + c0);
#pragma unroll
        for (int e = 0; e < 8; ++e) {
            float f = bfu2f((unsigned short)v[e]);
            s[e] += f; q[e] += f * f;
        }
    }
#pragma unroll
    for (int e = 0; e < 8; ++e) { smS[g][c0 + e] = s[e]; smQ[g][c0 + e] = q[e]; }
    __syncthreads();
    float S = 0.f, Q = 0.f;
#pragma unroll
    for (int g2 = 0; g2 < 8; ++g2) { S += smS[g2][t]; Q += smQ[g2][t]; }
    atomAddF(&bnbuf[y * 512 + t], S);
    atomAddF(&bnbuf[y * 512 + 256 + t], Q);
}

// 3-graph coef; self-zeroes bnbuf
__global__ void k_bn_coef3(float* __restrict__ bnbuf,
                           const float* __restrict__ g0, const float* __restrict__ be0,
                           const float* __restrict__ g1, const float* __restrict__ be1,
                           const float* __restrict__ g2, const float* __restrict__ be2,
                           float* __restrict__ coef, float invN01, float invN2) {
    int gg = blockIdx.x;
    int j = threadIdx.x;
    const float* gp = (gg == 0) ? g0 : ((gg == 1) ? g1 : g2);
    const float* bp = (gg == 0) ? be0 : ((gg == 1) ? be1 : be2);
    float invN = (gg < 2) ? invN01 : invN2;
    float* s = bnbuf + gg * 512;
    float m = s[j] * invN;
    float v = s[256 + j] * invN - m * m;
    float r = rsqrtf(fmaxf(v, 0.f) + 1e-5f);
    float sc = gp[j] * r;
    coef[gg * 512 + j] = sc;
    coef[gg * 512 + 256 + j] = bp[j] - m * sc;
    s[j] = 0.f;
    s[256 + j] = 0.f;
}

// ---------------- atom encoder ----------------
__global__ __launch_bounds__(256) void k_atom_enc(const int* __restrict__ mol_x,
                                                  const float* __restrict__ emb,
                                                  unsigned short* __restrict__ h) {
    __shared__ int sidx[4][NF];
    int t = threadIdx.x;
    if (t < 4 * NF) sidx[t / NF][t % NF] = mol_x[(blockIdx.x * 4 + t / NF) * NF + t % NF];
    __syncthreads();
    int r = t >> 6, lane = t & 63;
    int c0 = lane * 4;
    int row = blockIdx.x * 4 + r;
    float4 s = {0.f, 0.f, 0.f, 0.f};
#pragma unroll
    for (int f = 0; f < NF; ++f) {
        const float4 v = *reinterpret_cast<const float4*>(emb + ((size_t)f * NV + sidx[r][f]) * DH + c0);
        s.x += v.x; s.y += v.y; s.z += v.z; s.w += v.w;
    }
    ushort4 ov = {f2bfu(s.x), f2bfu(s.y), f2bfu(s.z), f2bfu(s.w)};
    *reinterpret_cast<ushort4*>(h + (size_t)row * DH + c0) = ov;
}

// ---------------- segment pool over f32 mol features [N_MOL][128] ----------------
__global__ __launch_bounds__(128) void k_pool_seg_f(const float* __restrict__ mfeat,
                                                    const int* __restrict__ batch,
                                                    float* __restrict__ mpool) {
    __shared__ int sr[2];
    __shared__ float smS[8][128];
    int b = blockIdx.x, t = threadIdx.x;
    if (t < 2) {
        int target = b + t;
        int lo = 0, hi = N_MOL;
        while (lo < hi) {
            int mid = (lo + hi) >> 1;
            if (batch[mid] < target) lo = mid + 1; else hi = mid;
        }
        sr[t] = lo;
    }
    __syncthreads();
    int g = t >> 4;
    int lane = t & 15;
    int c0 = lane * 8;
    float s[8];
#pragma unroll
    for (int e = 0; e < 8; ++e) s[e] = 0.f;
    int e1 = sr[1];
    for (int i = sr[0] + g; i < e1; i += 8) {
        const float4 v0 = *reinterpret_cast<const float4*>(mfeat + (size_t)i * 128 + c0);
        const float4 v1 = *reinterpret_cast<const float4*>(mfeat + (size_t)i * 128 + c0 + 4);
        s[0] += v0.x; s[1] += v0.y; s[2] += v0.z; s[3] += v0.w;
        s[4] += v1.x; s[5] += v1.y; s[6] += v1.z; s[7] += v1.w;
    }
#pragma unroll
    for (int e = 0; e < 8; ++e) smS[g][c0 + e] = s[e];
    __syncthreads();
    float S = 0.f;
#pragma unroll
    for (int g2 = 0; g2 < 8; ++g2) S += smS[g2][t];
    mpool[(size_t)b * 128 + t] = S;
}

// ---------------- head: conv1 (compact dgs[8192][128]: drug @b, dis @4096+b) ----------------
__global__ __launch_bounds__(64) void k_conv1(const float* __restrict__ dgs,
                                              const float* __restrict__ mpool,
                                              const float* __restrict__ W,
                                              const float* __restrict__ bias,
                                              float* __restrict__ y1) {
    __shared__ float xs[3][128];
    __shared__ float w[54];
    __shared__ float bb[6];
    int b = blockIdx.x, t = threadIdx.x;
    const float* r0 = dgs + (size_t)b * 128;
    const float* r1 = mpool + (size_t)b * 128;
    const float* r2 = dgs + (size_t)(BATCH + b) * 128;
    xs[0][t] = r0[t]; xs[0][t + 64] = r0[t + 64];
    xs[1][t] = r1[t]; xs[1][t + 64] = r1[t + 64];
    xs[2][t] = r2[t]; xs[2][t + 64] = r2[t + 64];
    if (t < 54) w[t] = W[t];
    if (t < 6) bb[t] = bias[t];
    __syncthreads();
    int l0 = 2 * t, l1 = l0 + 1;
#pragma unroll
    for (int o = 0; o < 6; ++o) {
        float ya = bb[o], yb = bb[o];
#pragma unroll
        for (int i = 0; i < 3; ++i) {
            const float* wi = &w[(o * 3 + i) * 3];
            float xm1 = (l0 > 0) ? xs[i][l0 - 1] : 0.f;
            float x0 = xs[i][l0];
            float x1 = xs[i][l1];
            float x2 = (l1 < 127) ? xs[i][l1 + 1] : 0.f;
            ya += wi[0] * xm1 + wi[1] * x0 + wi[2] * x1;
            yb += wi[0] * x0 + wi[1] * x1 + wi[2] * x2;
        }
        y1[((size_t)b * 6 + o) * 64 + t] = fmaxf(ya, yb);
    }
}

// hb per 'which': [0..5]=sum [8..13]=sumsq [16..21]=mean [24..29]=rstd; grid (6,16)
__global__ __launch_bounds__(256) void k_head_stats(const float* __restrict__ y,
                                                    float* __restrict__ hb, int which, int L) {
    int o = blockIdx.x;
    int b0 = blockIdx.y * 256;
    int t = threadIdx.x;
    float s = 0.f, q = 0.f;
    int per = 256 * L;
    for (int idx = t; idx < per; idx += 256) {
        int b = b0 + idx / L;
        int l = idx - (idx / L) * L;
        float v = y[((size_t)b * 6 + o) * L + l];
        s += v; q += v * v;
    }
    __shared__ float sms[4], smq[4];
#pragma unroll
    for (int off = 32; off > 0; off >>= 1) {
        s += __shfl_down(s, off);
        q += __shfl_down(q, off);
    }
    if ((t & 63) == 0) { sms[t >> 6] = s; smq[t >> 6] = q; }
    __syncthreads();
    if (t == 0) {
        float S = 0.f, Q = 0.f;
        for (int i = 0; i < 4; ++i) { S += sms[i]; Q += smq[i]; }
        atomAddF(hb + which * 32 + o, S);
        atomAddF(hb + which * 32 + 8 + o, Q);
    }
}

__global__ void k_bn_fin(float* __restrict__ hb, int which, float invN) {
    int o = threadIdx.x;
    if (o >= 6) return;
    float* p = hb + which * 32;
    float m = p[o] * invN;
    float v = p[8 + o] * invN - m * m;
    p[16 + o] = m;
    p[24 + o] = rsqrtf(fmaxf(v, 0.f) + 1e-5f);
}

// ---------------- head: conv2 ----------------
__global__ __launch_bounds__(64) void k_conv2(const float* __restrict__ y1,
                                              const float* __restrict__ hb,
                                              const float* __restrict__ g1,
                                              const float* __restrict__ be1,
                                              const float* __restrict__ W,
                                              const float* __restrict__ bias,
                                              float* __restrict__ y2) {
    __shared__ float xs[6][64];
    __shared__ float w[108];
    __shared__ float bb[6];
    int b = blockIdx.x, t = threadIdx.x;
    const float* mean = hb + 16;
    const float* rstd = hb + 24;
    for (int idx = t; idx < 384; idx += 64) {
        int o = idx >> 6, l = idx & 63;
        float v = y1[((size_t)b * 6 + o) * 64 + l];
        v = g1[o] * (v - mean[o]) * rstd[o] + be1[o];
        xs[o][l] = fmaxf(v, 0.f);
    }
    for (int idx = t; idx < 108; idx += 64) w[idx] = W[idx];
    if (t < 6) bb[t] = bias[t];
    __syncthreads();
    if (t >= 32) return;
    int l0 = 2 * t, l1 = l0 + 1;
#pragma unroll
    for (int o = 0; o < 6; ++o) {
        float ya = bb[o], yb = bb[o];
#pragma unroll
        for (int i = 0; i < 6; ++i) {
            const float* wi = &w[(o * 6 + i) * 3];
            float xm1 = (l0 > 0) ? xs[i][l0 - 1] : 0.f;
            float x0 = xs[i][l0];
            float x1 = xs[i][l1];
            float x2 = (l1 < 63) ? xs[i][l1 + 1] : 0.f;
            ya += wi[0] * xm1 + wi[1] * x0 + wi[2] * x1;
            yb += wi[0] * x0 + wi[1] * x1 + wi[2] * x2;
        }
        y2[((size_t)b * 6 + o) * 32 + t] = fmaxf(ya, yb);
    }
}

// ---------------- head final ----------------
__global__ __launch_bounds__(128) void k_head(const float* __restrict__ y2,
                                              const float* __restrict__ hb,
                                              const float* __restrict__ g2,
                                              const float* __restrict__ be2,
                                              const float* __restrict__ l1W,
                                              const float* __restrict__ l1b,
                                              const float* __restrict__ l2W,
                                              const float* __restrict__ l2b,
                                              float* __restrict__ out) {
    __shared__ float fs[192];
    __shared__ float sm[2];
    int b = blockIdx.x, t = threadIdx.x;
    const float* mean = hb + 32 + 16;
    const float* rstd = hb + 32 + 24;
    for (int idx = t; idx < 192; idx += 128) {
        int o = idx >> 5, l = idx & 31;
        float v = y2[((size_t)b * 6 + o) * 32 + l];
        v = g2[o] * (v - mean[o]) * rstd[o] + be2[o];
        fs[idx] = fmaxf(v, 0.f);
    }
    __syncthreads();
    float h = l1b[t];
    for (int k = 0; k < 192; ++k)
        h += fs[k] * l1W[k * 128 + t];
    h = fmaxf(h, 0.f);
    float p = h * l2W[t];
#pragma unroll
    for (int off = 32; off > 0; off >>= 1) p += __shfl_down(p, off);
    if ((t & 63) == 0) sm[t >> 6] = p;
    __syncthreads();
    if (t == 0) out[b] = sm[0] + sm[1] + l2b[0];
}

extern "C" void kernel_launch(void* const* d_in, const int* in_sizes, int n_in,
                              void* d_out, int out_size, void* d_ws, size_t ws_size,
                              hipStream_t stream) {
    float* out = (float*)d_out;
    if (n_in != 52) { k_sentinel<<<16, 256, 0, stream>>>(out, out_size, -111.f); return; }
    if (in_sizes[0] != N_DRUG * 128 || in_sizes[29] != NF * NV * DH || in_sizes[48] != 192 * 128) {
        k_sentinel<<<16, 256, 0, stream>>>(out, out_size, -222.f); return;
    }

    char* w = (char*)d_ws;
    auto alloc = [&](size_t bytes) { char* p = w; w += (bytes + 255) & ~(size_t)255; return p; };
    unsigned short* B1 = (unsigned short*)alloc((size_t)NTOT * 256 * 2);
    unsigned short* B2 = (unsigned short*)alloc((size_t)NTOT * 256 * 2);
    // aliases into B1 (dead after L2 GEMM): molf [N_MOL][128] f32 then dgs [8192][128] f32
    float* molf = (float*)B1;
    float* dgs  = molf + (size_t)N_MOL * 128;
    float* mpool = (float*)alloc((size_t)BATCH * 128 * 4);
    int*   cnt      = (int*)alloc((size_t)NTOT * 4);
    float* dinv     = (float*)alloc((size_t)NTOT * 4);
    int*   rowStart = (int*)alloc((size_t)(NTOT + 1) * 4);
    int*   cursor   = (int*)alloc((size_t)NTOT * 4);
    int2*  csr2     = (int2*)alloc((size_t)ETOT * 8);
    int*   bsum     = (int*)alloc(1024 * 4);
    float* bnbuf    = (float*)alloc(1536 * 4);
    float* coef     = (float*)alloc(1536 * 4);
    unsigned short* drT0 = (unsigned short*)alloc((size_t)128 * 256 * 2);
    unsigned short* drT1 = (unsigned short*)alloc((size_t)256 * 256 * 2);
    unsigned short* drT2 = (unsigned short*)alloc((size_t)256 * 128 * 2);
    unsigned short* diT0 = (unsigned short*)alloc((size_t)128 * 256 * 2);
    unsigned short* diT1 = (unsigned short*)alloc((size_t)256 * 256 * 2);
    unsigned short* diT2 = (unsigned short*)alloc((size_t)256 * 128 * 2);
    unsigned short* moT0 = (unsigned short*)alloc((size_t)256 * 256 * 2);
    unsigned short* moT1 = (unsigned short*)alloc((size_t)256 * 256 * 2);
    unsigned short* moT2 = (unsigned short*)alloc((size_t)256 * 128 * 2);
    float* hstat = (float*)alloc(64 * 4);
    float* y1    = (float*)alloc((size_t)BATCH * 6 * 64 * 4);
    float* y2    = (float*)alloc((size_t)BATCH * 6 * 32 * 4);
    if ((size_t)(w - (char*)d_ws) > ws_size) {
        k_sentinel<<<16, 256, 0, stream>>>(out, out_size, -333.f); return;
    }

    const float* drug_x  = (const float*)d_in[0];
    const int* drug_ei   = (const int*)d_in[1];
    const int* drug_idx  = (const int*)d_in[2];
    const float* dis_x   = (const float*)d_in[3];
    const int* dis_ei    = (const int*)d_in[4];
    const int* dis_idx   = (const int*)d_in[5];
    const int* mol_x     = (const int*)d_in[6];
    const int* mol_ei    = (const int*)d_in[7];
    const int* mol_b     = (const int*)d_in[8];
    const float *dr_W0 = (const float*)d_in[9], *dr_W1 = (const float*)d_in[10], *dr_W2 = (const float*)d_in[11];
    const float *dr_b2 = (const float*)d_in[14];
    const float *dr_g0 = (const float*)d_in[15], *dr_g1 = (const float*)d_in[16];
    const float *dr_be0 = (const float*)d_in[17], *dr_be1 = (const float*)d_in[18];
    const float *di_W0 = (const float*)d_in[19], *di_W1 = (const float*)d_in[20], *di_W2 = (const float*)d_in[21];
    const float *di_b2 = (const float*)d_in[24];
    const float *di_g0 = (const float*)d_in[25], *di_g1 = (const float*)d_in[26];
    const float *di_be0 = (const float*)d_in[27], *di_be1 = (const float*)d_in[28];
    const float* mol_emb = (const float*)d_in[29];
    const float *mo_W0 = (const float*)d_in[30], *mo_W1 = (const float*)d_in[31], *mo_W2 = (const float*)d_in[32];
    const float *mo_b2 = (const float*)d_in[35];
    const float *mo_g0 = (const float*)d_in[36], *mo_g1 = (const float*)d_in[37];
    const float *mo_be0 = (const float*)d_in[38], *mo_be1 = (const float*)d_in[39];
    const float *c1_W = (const float*)d_in[40], *c1_b = (const float*)d_in[41];
    const float *c1_g = (const float*)d_in[42], *c1_be = (const float*)d_in[43];
    const float *c2_W = (const float*)d_in[44], *c2_b = (const float*)d_in[45];
    const float *c2_g = (const float*)d_in[46], *c2_be = (const float*)d_in[47];
    const float *l1_W = (const float*)d_in[48], *l1_b = (const float*)d_in[49];
    const float *l2_W = (const float*)d_in[50], *l2_b = (const float*)d_in[51];

    const float invN01 = 1.0f / (float)N_DRUG;
    const float invNM  = 1.0f / (float)N_MOL;
    const long long MOFF = (long long)NP * 128;

    hipMemsetAsync(bnbuf, 0, 1536 * sizeof(float), stream);

    // ---- inputs into B1: drugdis [NP][128] @0, mol [N_MOL][256] @MOFF ----
    k_cast_pair<<<(NP * 32 + 255) / 256, 256, 0, stream>>>(drug_x, dis_x, B1);
    k_atom_enc<<<N_MOL / 4, 256, 0, stream>>>(mol_x, mol_emb, B1 + MOFF);

    // ---- merged CSR ----
    hipMemsetAsync(cnt, 0, (size_t)NTOT * sizeof(int), stream);
    k_count3<<<(ETOT + 255) / 256, 256, 0, stream>>>(drug_ei, dis_ei, mol_ei, cnt);
    int nb = (NTOT + 255) / 256;
    k_scan1<<<nb, 256, 0, stream>>>(cnt, rowStart, bsum, dinv, NTOT);
    k_scan2b<<<1, 256, 0, stream>>>(bsum, nb);
    k_scan3<<<nb, 256, 0, stream>>>(rowStart, cursor, bsum, NTOT, ETOT);
    k_fill3<<<(ETOT + 255) / 256, 256, 0, stream>>>(drug_ei, dis_ei, mol_ei, dinv, cursor, csr2);

    // ---- weights ----
    int wt1 = 128 * 256 + 256 * 256 + 256 * 128;
    int wt2 = 256 * 256 + 256 * 256 + 256 * 128;
    k_wcast3<<<(wt1 + 255) / 256, 256, 0, stream>>>(dr_W0, dr_W1, dr_W2, drT0, drT1, drT2, 128);
    k_wcast3<<<(wt1 + 255) / 256, 256, 0, stream>>>(di_W0, di_W1, di_W2, diT0, diT1, diT2, 128);
    k_wcast3<<<(wt2 + 255) / 256, 256, 0, stream>>>(mo_W0, mo_W1, mo_W2, moT0, moT1, moT2, 256);

    // ---- L0: gathers (agg-first) B1 -> B2, merged GEMM B2 -> B1[NTOT][256] (+stats) ----
    k_gather<128, 0, 1><<<NP / 8, 256, 0, stream>>>(B1, 0, dinv, nullptr, nullptr, nullptr,
                                                    csr2, rowStart, B2, 0, 0, NP);
    k_gather<256, 0, 1><<<N_MOL / 8, 256, 0, stream>>>(B1, MOFF, dinv, nullptr, nullptr, nullptr,
                                                       csr2, rowStart, B2, MOFF, NP, NTOT);
    k_gemm_mfma<0, 1><<<dim3(2, 826), 256, 0, stream>>>(B2, drT0, diT0, moT0, nullptr,
        B1, bnbuf, 157, 314, SPAN_P, NP, N_DRUG, N_DIS, N_MOL, 0, 128, 256, MOFF, NP, 256);
    k_bn_coef3<<<3, 256, 0, stream>>>(bnbuf, dr_g0, dr_be0, di_g0, di_be0, mo_g0, mo_be0,
                                      coef, invN01, invNM);
    // ---- L1 merged ----
    k_gemm_mfma<1, 0><<<dim3(2, 826), 256, 0, stream>>>(B1, drT1, diT1, moT1, coef,
        B2, nullptr, 157, 314, SPAN_P, NP, N_DRUG, N_DIS, N_MOL, 0, 256, 256, 0, 0, 256);
    k_gather<256, 0, 1><<<NTOT / 8, 256, 0, stream>>>(B2, 0, dinv, nullptr, nullptr, nullptr,
                                                      csr2, rowStart, B1, 0, 0, NTOT);
    k_bn_stats3<<<dim3(256, 3), 256, 0, stream>>>(B1, bnbuf);
    k_bn_coef3<<<3, 256, 0, stream>>>(bnbuf, dr_g1, dr_be1, di_g1, di_be1, mo_g1, mo_be1,
                                      coef, invN01, invNM);
    // ---- L2: GEMM(BN1 fused) B1 -> B2[NTOT][128]; sparse gathers (only consumed rows) ----
    k_gemm_mfma<1, 0><<<dim3(1, 826), 256, 0, stream>>>(B1, drT2, diT2, moT2, coef,
        B2, nullptr, 157, 314, SPAN_P, NP, N_DRUG, N_DIS, N_MOL, 0, 256, 256, 0, 0, 128);
    k_gather_idx<<<2 * BATCH / 8, 256, 0, stream>>>(B2, dinv, dr_b2, di_b2, drug_idx, dis_idx,
                                                    csr2, rowStart, dgs);
    k_gather<128, 1, 0><<<N_MOL / 8, 256, 0, stream>>>(B2, 0, dinv, nullptr, nullptr, mo_b2,
                                                       csr2, rowStart, molf, MOFF, NP, NTOT);
    k_pool_seg_f<<<BATCH, 128, 0, stream>>>(molf, mol_b, mpool);

    // ---- head ----
    hipMemsetAsync(hstat, 0, 64 * 4, stream);
    k_conv1<<<BATCH, 64, 0, stream>>>(dgs, mpool, c1_W, c1_b, y1);
    k_head_stats<<<dim3(6, BATCH / 256), 256, 0, stream>>>(y1, hstat, 0, 64);
    k_bn_fin<<<1, 8, 0, stream>>>(hstat, 0, 1.0f / (BATCH * 64.0f));
    k_conv2<<<BATCH, 64, 0, stream>>>(y1, hstat, c1_g, c1_be, c2_W, c2_b, y2);
    k_head_stats<<<dim3(6, BATCH / 256), 256, 0, stream>>>(y2, hstat, 1, 32);
    k_bn_fin<<<1, 8, 0, stream>>>(hstat, 1, 1.0f / (BATCH * 32.0f));
    k_head<<<BATCH, 128, 0, stream>>>(y2, hstat, c2_g, c2_be, l1_W, l1_b, l2_W, l2_b, out);
}

// Round 17
// 540.319 us; speedup vs baseline: 1.1035x; 1.0117x over previous
//
#include <hip/hip_runtime.h>
#include <hip/hip_bf16.h>

#define N_DRUG 20000
#define N_DIS  20000
#define E_G    320000
#define BATCH  4096
#define N_MOL  65536
#define E_MOL  262144
#define NF     9
#define NV     128
#define DH     256
#define SPAN_P 20096                 // 157*128 pad per drug/dis graph (8-row aligned)
#define NP     40192                 // 2*SPAN_P (8-row aligned)
#define NTOT   105728                // NP + N_MOL (8-row aligned)
#define ETOT   902144                // 2*E_G + E_MOL
#define NBUCK  16

typedef short s16x8 __attribute__((ext_vector_type(8)));
typedef unsigned short u16x8 __attribute__((ext_vector_type(8)));
typedef float f32x4 __attribute__((ext_vector_type(4)));

typedef __attribute__((address_space(1))) const void gvoid_t;
typedef __attribute__((address_space(3))) void lvoid_t;

__device__ __forceinline__ float bfu2f(unsigned short u) {
    return __uint_as_float(((unsigned int)u) << 16);
}
__device__ __forceinline__ unsigned short f2bfu(float f) {
    __hip_bfloat16 b = __float2bfloat16(f);
    return *reinterpret_cast<unsigned short*>(&b);
}
__device__ __forceinline__ void atomAddF(float* p, float v) { unsafeAtomicAdd(p, v); }

// ---------------- misc ----------------
__global__ void k_sentinel(float* out, int n, float v) {
    int i = blockIdx.x * 256 + threadIdx.x;
    if (i < n) out[i] = v;
}

// merged input prep: blocks [0,5024) cast drug+dis -> B1[NP][128]; rest atom-enc -> B1+MOFF
__global__ __launch_bounds__(256) void k_in_prep(const float* __restrict__ a,
                                                 const float* __restrict__ b,
                                                 const int* __restrict__ mol_x,
                                                 const float* __restrict__ emb,
                                                 unsigned short* __restrict__ B1,
                                                 unsigned short* __restrict__ molh) {
    __shared__ int sidx[4][NF];
    int bx = blockIdx.x, t = threadIdx.x;
    if (bx < NP * 32 / 256) {
        int i4 = bx * 256 + t;
        int row = i4 >> 5, c4 = (i4 & 31) * 4;
        float4 v = {0.f, 0.f, 0.f, 0.f};
        if (row < N_DRUG) v = *reinterpret_cast<const float4*>(a + (size_t)row * 128 + c4);
        else if (row >= SPAN_P && row < SPAN_P + N_DIS)
            v = *reinterpret_cast<const float4*>(b + (size_t)(row - SPAN_P) * 128 + c4);
        ushort4 o = {f2bfu(v.x), f2bfu(v.y), f2bfu(v.z), f2bfu(v.w)};
        *reinterpret_cast<ushort4*>(B1 + (size_t)row * 128 + c4) = o;
    } else {
        int blk = bx - NP * 32 / 256;
        if (t < 4 * NF) sidx[t / NF][t % NF] = mol_x[(blk * 4 + t / NF) * NF + t % NF];
        __syncthreads();
        int r = t >> 6, lane = t & 63;
        int c0 = lane * 4;
        int row = blk * 4 + r;
        float4 s = {0.f, 0.f, 0.f, 0.f};
#pragma unroll
        for (int f = 0; f < NF; ++f) {
            const float4 v = *reinterpret_cast<const float4*>(emb + ((size_t)f * NV + sidx[r][f]) * DH + c0);
            s.x += v.x; s.y += v.y; s.z += v.z; s.w += v.w;
        }
        ushort4 ov = {f2bfu(s.x), f2bfu(s.y), f2bfu(s.z), f2bfu(s.w)};
        *reinterpret_cast<ushort4*>(molh + (size_t)row * DH + c0) = ov;
    }
}

// all 9 weight transposes in one kernel: W[K][N] f32 -> Wt[N][K] bf16
__global__ void k_wcast9(const float* __restrict__ a0, const float* __restrict__ a1,
                         const float* __restrict__ a2, const float* __restrict__ b0,
                         const float* __restrict__ b1, const float* __restrict__ b2,
                         const float* __restrict__ m0, const float* __restrict__ m1,
                         const float* __restrict__ m2,
                         unsigned short* __restrict__ A0, unsigned short* __restrict__ A1,
                         unsigned short* __restrict__ A2, unsigned short* __restrict__ B0,
                         unsigned short* __restrict__ B1, unsigned short* __restrict__ B2,
                         unsigned short* __restrict__ M0, unsigned short* __restrict__ M1,
                         unsigned short* __restrict__ M2) {
    int i = blockIdx.x * 256 + threadIdx.x;
    const float* W; unsigned short* T; int K, N, e;
    if (i < 32768)       { W = a0; T = A0; K = 128; N = 256; e = i; }
    else if (i < 98304)  { W = a1; T = A1; K = 256; N = 256; e = i - 32768; }
    else if (i < 131072) { W = a2; T = A2; K = 256; N = 128; e = i - 98304; }
    else if (i < 163840) { W = b0; T = B0; K = 128; N = 256; e = i - 131072; }
    else if (i < 229376) { W = b1; T = B1; K = 256; N = 256; e = i - 163840; }
    else if (i < 262144) { W = b2; T = B2; K = 256; N = 128; e = i - 229376; }
    else if (i < 327680) { W = m0; T = M0; K = 256; N = 256; e = i - 262144; }
    else if (i < 393216) { W = m1; T = M1; K = 256; N = 256; e = i - 327680; }
    else if (i < 425984) { W = m2; T = M2; K = 256; N = 128; e = i - 393216; }
    else return;
    int k = e / N, c = e - k * N;
    T[(size_t)c * K + k] = f2bfu(W[e]);
}

// ---------------- merged-graph degree / CSR ----------------
__global__ void k_count3(const int* __restrict__ eA, const int* __restrict__ eB,
                         const int* __restrict__ eC, int* __restrict__ cnt) {
    int e = blockIdx.x * 256 + threadIdx.x;
    if (e >= ETOT) return;
    int d;
    if (e < E_G) d = eA[E_G + e];
    else if (e < 2 * E_G) d = eB[E_G + (e - E_G)] + SPAN_P;
    else d = eC[E_MOL + (e - 2 * E_G)] + NP;
    atomicAdd(&cnt[d], 1);
}

__global__ void k_scan1(const int* __restrict__ cnt, int* __restrict__ rowStart,
                        int* __restrict__ bsum, float* __restrict__ dinv, int n) {
    __shared__ int sh[256];
    int i = blockIdx.x * 256 + threadIdx.x;
    int v = (i < n) ? cnt[i] : 0;
    if (i < n) dinv[i] = rsqrtf(1.0f + (float)v);
    sh[threadIdx.x] = v;
    __syncthreads();
    for (int off = 1; off < 256; off <<= 1) {
        int t = (threadIdx.x >= off) ? sh[threadIdx.x - off] : 0;
        __syncthreads();
        sh[threadIdx.x] += t;
        __syncthreads();
    }
    if (i < n) rowStart[i] = sh[threadIdx.x] - v;
    if (threadIdx.x == 255) bsum[blockIdx.x] = sh[255];
}
__global__ void k_scan2b(int* __restrict__ bsum, int nb) {
    __shared__ int sh[256];
    __shared__ int carry;
    int t = threadIdx.x;
    if (t == 0) carry = 0;
    __syncthreads();
    for (int c0 = 0; c0 < nb; c0 += 256) {
        int v = (c0 + t < nb) ? bsum[c0 + t] : 0;
        sh[t] = v;
        __syncthreads();
        for (int off = 1; off < 256; off <<= 1) {
            int u = (t >= off) ? sh[t - off] : 0;
            __syncthreads();
            sh[t] += u;
            __syncthreads();
        }
        if (c0 + t < nb) bsum[c0 + t] = carry + sh[t] - v;
        __syncthreads();
        if (t == 0) carry += sh[255];
        __syncthreads();
    }
}
__global__ void k_scan3(int* __restrict__ rowStart, int* __restrict__ cursor,
                        const int* __restrict__ bsum, int n, int E) {
    int i = blockIdx.x * 256 + threadIdx.x;
    if (i < n) {
        int r = rowStart[i] + bsum[blockIdx.x];
        rowStart[i] = r;
        cursor[i] = r;
    }
    if (i == 0) rowStart[n] = E;
}
__global__ void k_fill3(const int* __restrict__ eA, const int* __restrict__ eB,
                        const int* __restrict__ eC, const float* __restrict__ dinv,
                        int* __restrict__ cursor, int2* __restrict__ csr2) {
    int e = blockIdx.x * 256 + threadIdx.x;
    if (e >= ETOT) return;
    int s, d;
    if (e < E_G) { s = eA[e]; d = eA[E_G + e]; }
    else if (e < 2 * E_G) { int i = e - E_G; s = eB[i] + SPAN_P; d = eB[E_G + i] + SPAN_P; }
    else { int i = e - 2 * E_G; s = eC[i] + NP; d = eC[E_MOL + i] + NP; }
    int p = atomicAdd(&cursor[d], 1);
    csr2[p] = make_int2(s, __float_as_int(dinv[s] * dinv[d]));
}

// ---------------- MFMA GEMM: 3 graphs batched, per-graph K / A-base ----------------
template<int AFFINE, int STATS>
__global__ __launch_bounds__(256) void k_gemm_mfma(const unsigned short* __restrict__ A,
                                                   const unsigned short* __restrict__ Bt0,
                                                   const unsigned short* __restrict__ Bt1,
                                                   const unsigned short* __restrict__ Bt2,
                                                   const float* __restrict__ coef,
                                                   unsigned short* __restrict__ Cout,
                                                   float* __restrict__ bnbuf,
                                                   int tb0, int tb1, int boff1, int boff2,
                                                   int m0, int m1, int m2, int gbase,
                                                   int K01, int K2, long long abase2,
                                                   int arow2, int N) {
    __shared__ unsigned short Al[2][4][128][8];
    __shared__ unsigned short Bl[2][4][128][8];
    __shared__ float csc[256], csh[256];
    const int tid = threadIdx.x;
    const int y = blockIdx.y;
    const int bm = y * 128;
    const int bn = blockIdx.x * 128;
    const int g = (y >= tb1) ? 2 : ((y >= tb0) ? 1 : 0);
    const int Kg = (g == 2) ? K2 : K01;
    const int boff = (g == 0) ? 0 : ((g == 1) ? boff1 : boff2);
    const int Mloc = (g == 0) ? m0 : ((g == 1) ? m1 : m2);
    const int lbm = bm - boff;
    const unsigned short* Ag = (g == 2) ? (A + abase2) : A;
    const int arow = (g == 2) ? arow2 : 0;
    const unsigned short* Bt = (g == 0) ? Bt0 : ((g == 1) ? Bt1 : Bt2);
    const int gs = gbase + g;
    const int w = tid >> 6, l = tid & 63;
    const int wrow = (w >> 1) * 64, wcol = (w & 1) * 64;
    const int kg = l >> 4, lr = l & 15;

    if (AFFINE) {
        for (int i = tid; i < Kg; i += 256) {
            csc[i] = coef[gs * 512 + i];
            csh[i] = coef[gs * 512 + 256 + i];
        }
    }
    if (lbm + 128 > Mloc) {
        for (int s = tid; s < 1024; s += 256) {
            u16x8 z = {0, 0, 0, 0, 0, 0, 0, 0};
            *reinterpret_cast<u16x8*>(&Al[0][0][0][0] + s * 8) = z;
        }
    }
    __syncthreads();

    auto stage = [&](int buf, int k0) {
#pragma unroll
        for (int i = 0; i < 4; ++i) {
            int id = w * 4 + i;
            int koff = (id >> 1) & 3;
            int half = id & 1;
            int row = half * 64 + l;
            if (id < 8) {
                if (lbm + row < Mloc) {
                    const unsigned short* gsrc = Ag + (size_t)(bm - arow + row) * Kg + k0 + koff * 8;
                    __builtin_amdgcn_global_load_lds((gvoid_t*)gsrc,
                        (lvoid_t*)&Al[buf][koff][half * 64][0], 16, 0, 0);
                }
            } else {
                const unsigned short* gsrc = Bt + (size_t)(bn + row) * Kg + k0 + koff * 8;
                __builtin_amdgcn_global_load_lds((gvoid_t*)gsrc,
                    (lvoid_t*)&Bl[buf][koff][half * 64][0], 16, 0, 0);
            }
        }
    };

    f32x4 acc[4][4];
#pragma unroll
    for (int fm = 0; fm < 4; ++fm)
#pragma unroll
        for (int fn = 0; fn < 4; ++fn) acc[fm][fn] = f32x4{0.f, 0.f, 0.f, 0.f};

    stage(0, 0);
    __syncthreads();
    int nk = Kg >> 5;
    for (int t = 0; t < nk; ++t) {
        int cur = t & 1;
        if (t + 1 < nk) stage(cur ^ 1, (t + 1) * 32);
        s16x8 a[4], b[4];
#pragma unroll
        for (int fm = 0; fm < 4; ++fm)
            a[fm] = *reinterpret_cast<const s16x8*>(&Al[cur][kg][wrow + fm * 16 + lr][0]);
        if (AFFINE) {
            int k0 = t * 32;
            float sc[8], sh[8];
#pragma unroll
            for (int e = 0; e < 8; ++e) {
                sc[e] = csc[k0 + kg * 8 + e];
                sh[e] = csh[k0 + kg * 8 + e];
            }
#pragma unroll
            for (int fm = 0; fm < 4; ++fm)
#pragma unroll
                for (int e = 0; e < 8; ++e) {
                    float f = bfu2f((unsigned short)a[fm][e]);
                    a[fm][e] = (short)f2bfu(fmaxf(fmaf(sc[e], f, sh[e]), 0.f));
                }
        }
#pragma unroll
        for (int fn = 0; fn < 4; ++fn)
            b[fn] = *reinterpret_cast<const s16x8*>(&Bl[cur][kg][wcol + fn * 16 + lr][0]);
#pragma unroll
        for (int fm = 0; fm < 4; ++fm)
#pragma unroll
            for (int fn = 0; fn < 4; ++fn)
                acc[fm][fn] = __builtin_amdgcn_mfma_f32_16x16x32_bf16(a[fm], b[fn], acc[fm][fn], 0, 0, 0);
        __syncthreads();
    }
    // C/D layout: col = lane&15, row = (lane>>4)*4 + reg. Pad rows write 0.
#pragma unroll
    for (int fm = 0; fm < 4; ++fm)
#pragma unroll
        for (int r = 0; r < 4; ++r) {
            int row = bm + wrow + fm * 16 + kg * 4 + r;
#pragma unroll
            for (int fn = 0; fn < 4; ++fn) {
                int col = bn + wcol + fn * 16 + lr;
                Cout[(size_t)row * N + col] = f2bfu(acc[fm][fn][r]);
            }
        }
    if constexpr (STATS) {
        __shared__ float colS[128], colQ[128];
        if (tid < 128) { colS[tid] = 0.f; colQ[tid] = 0.f; }
        __syncthreads();
#pragma unroll
        for (int fn = 0; fn < 4; ++fn) {
            float s = 0.f, q = 0.f;
#pragma unroll
            for (int fm = 0; fm < 4; ++fm)
#pragma unroll
                for (int r = 0; r < 4; ++r) {
                    float v = acc[fm][fn][r];
                    s += v; q += v * v;
                }
            int cl = (w & 1) * 64 + fn * 16 + lr;
            atomicAdd(&colS[cl], s);
            atomicAdd(&colQ[cl], q);
        }
        __syncthreads();
        if (tid < 128) {
            atomAddF(&bnbuf[gs * 512 + bn + tid], colS[tid]);
            atomAddF(&bnbuf[gs * 512 + 256 + bn + tid], colQ[tid]);
        }
    }
}

// ---------------- gather core: one row, 32 lanes, PL channels/lane, 8/4/1 unroll ----------------
template<int C, int BIAS>
__device__ __forceinline__ void gather_core(const unsigned short* __restrict__ h,
                                            long long hoff,
                                            const float* __restrict__ dinv,
                                            const float* __restrict__ b0,
                                            const float* __restrict__ b1,
                                            const float* __restrict__ b2,
                                            const int2* __restrict__ csr2,
                                            const int* __restrict__ rowStart,
                                            int row, int c0, float* a0) {
    constexpr int PL = C / 32;
    auto loadRow = [&](int r, float* d) {
        const unsigned short* base = h + ((size_t)r * C - hoff) + c0;
        if constexpr (PL == 8) {
            u16x8 v = *reinterpret_cast<const u16x8*>(base);
#pragma unroll
            for (int e = 0; e < 8; ++e) d[e] = bfu2f((unsigned short)v[e]);
        } else {
            ushort4 v = *reinterpret_cast<const ushort4*>(base);
            d[0] = bfu2f(v.x); d[1] = bfu2f(v.y); d[2] = bfu2f(v.z); d[3] = bfu2f(v.w);
        }
    };
    float dd = dinv[row], ws = dd * dd;
    int beg = rowStart[row], end = rowStart[row + 1];
    float a1[PL], a2[PL], a3[PL];
    float t0[PL], t1[PL], t2[PL], t3[PL], t4[PL], t5[PL], t6[PL], t7[PL];
    loadRow(row, t0);
#pragma unroll
    for (int p = 0; p < PL; ++p) { a0[p] = t0[p] * ws; a1[p] = 0.f; a2[p] = 0.f; a3[p] = 0.f; }
    int j = beg;
    for (; j + 8 <= end; j += 8) {
        int2 e0 = csr2[j], e1 = csr2[j + 1], e2 = csr2[j + 2], e3 = csr2[j + 3];
        int2 e4 = csr2[j + 4], e5 = csr2[j + 5], e6 = csr2[j + 6], e7 = csr2[j + 7];
        float w0 = __int_as_float(e0.y), w1 = __int_as_float(e1.y);
        float w2 = __int_as_float(e2.y), w3 = __int_as_float(e3.y);
        float w4 = __int_as_float(e4.y), w5 = __int_as_float(e5.y);
        float w6 = __int_as_float(e6.y), w7 = __int_as_float(e7.y);
        loadRow(e0.x, t0); loadRow(e1.x, t1); loadRow(e2.x, t2); loadRow(e3.x, t3);
        loadRow(e4.x, t4); loadRow(e5.x, t5); loadRow(e6.x, t6); loadRow(e7.x, t7);
#pragma unroll
        for (int p = 0; p < PL; ++p) {
            a0[p] += w0 * t0[p]; a1[p] += w1 * t1[p];
            a2[p] += w2 * t2[p]; a3[p] += w3 * t3[p];
            a0[p] += w4 * t4[p]; a1[p] += w5 * t5[p];
            a2[p] += w6 * t6[p]; a3[p] += w7 * t7[p];
        }
    }
    for (; j + 4 <= end; j += 4) {
        int2 e0 = csr2[j], e1 = csr2[j + 1], e2 = csr2[j + 2], e3 = csr2[j + 3];
        float w0 = __int_as_float(e0.y), w1 = __int_as_float(e1.y);
        float w2 = __int_as_float(e2.y), w3 = __int_as_float(e3.y);
        loadRow(e0.x, t0); loadRow(e1.x, t1); loadRow(e2.x, t2); loadRow(e3.x, t3);
#pragma unroll
        for (int p = 0; p < PL; ++p) {
            a0[p] += w0 * t0[p]; a1[p] += w1 * t1[p];
            a2[p] += w2 * t2[p]; a3[p] += w3 * t3[p];
        }
    }
    for (; j < end; ++j) {
        int2 e0 = csr2[j];
        float ww = __int_as_float(e0.y);
        loadRow(e0.x, t0);
#pragma unroll
        for (int p = 0; p < PL; ++p) a0[p] += ww * t0[p];
    }
    const float* bp = nullptr;
    if (BIAS) bp = (row < SPAN_P) ? b0 : ((row < NP) ? b1 : b2);
#pragma unroll
    for (int p = 0; p < PL; ++p) {
        a0[p] += (a1[p] + a2[p]) + a3[p];
        if (BIAS) a0[p] += bp[c0 + p];
    }
}

// ---------------- L0 merged gather: [0,NP) C=128, [NP,NTOT) C=256; bf16 out ----------------
__global__ __launch_bounds__(256) void k_gather_l0(const unsigned short* __restrict__ B1,
                                                   const float* __restrict__ dinv,
                                                   const int2* __restrict__ csr2,
                                                   const int* __restrict__ rowStart,
                                                   unsigned short* __restrict__ B2,
                                                   long long moff) {
    int bx = blockIdx.x;
    int grp = threadIdx.x >> 5;
    int lane = threadIdx.x & 31;
    if (bx < NP / 8) {
        int row = bx * 8 + grp;
        int c0 = lane * 4;
        float a0[4];
        gather_core<128, 0>(B1, 0, dinv, nullptr, nullptr, nullptr, csr2, rowStart, row, c0, a0);
        ushort4 ov = {f2bfu(a0[0]), f2bfu(a0[1]), f2bfu(a0[2]), f2bfu(a0[3])};
        *reinterpret_cast<ushort4*>(B2 + (size_t)row * 128 + c0) = ov;
    } else {
        int row = NP + (bx - NP / 8) * 8 + grp;
        int c0 = lane * 8;
        float a0[8];
        gather_core<256, 0>(B1, moff, dinv, nullptr, nullptr, nullptr, csr2, rowStart, row, c0, a0);
        u16x8 ov;
#pragma unroll
        for (int e = 0; e < 8; ++e) ov[e] = f2bfu(a0[e]);
        *reinterpret_cast<u16x8*>(B2 + ((size_t)row * 256 - moff) + c0) = ov;
    }
}

// ---------------- L1 gather + fused BN stats (bucketed partials) ----------------
// rows [0,NTOT) exact (NTOT/8 blocks); block never straddles a graph boundary.
__global__ __launch_bounds__(256) void k_gather_l1s(const unsigned short* __restrict__ B2,
                                                    const float* __restrict__ dinv,
                                                    const int2* __restrict__ csr2,
                                                    const int* __restrict__ rowStart,
                                                    unsigned short* __restrict__ B1,
                                                    float* __restrict__ bnpart) {
    __shared__ float smS[8][256];
    __shared__ float smQ[8][256];
    int grp = threadIdx.x >> 5;
    int lane = threadIdx.x & 31;
    int row = blockIdx.x * 8 + grp;
    int c0 = lane * 8;
    float a0[8];
    gather_core<256, 0>(B2, 0, dinv, nullptr, nullptr, nullptr, csr2, rowStart, row, c0, a0);
    u16x8 ov;
    float s8[8];
#pragma unroll
    for (int e = 0; e < 8; ++e) {
        ov[e] = f2bfu(a0[e]);
        s8[e] = bfu2f((unsigned short)ov[e]);   // stats on the stored bf16 value
    }
    *reinterpret_cast<u16x8*>(B1 + (size_t)row * 256 + c0) = ov;
#pragma unroll
    for (int e = 0; e < 8; ++e) { smS[grp][c0 + e] = s8[e]; smQ[grp][c0 + e] = s8[e] * s8[e]; }
    __syncthreads();
    int t = threadIdx.x;
    float S = 0.f, Q = 0.f;
#pragma unroll
    for (int g2 = 0; g2 < 8; ++g2) { S += smS[g2][t]; Q += smQ[g2][t]; }
    int r0 = blockIdx.x * 8;
    int g3 = (r0 < SPAN_P) ? 0 : ((r0 < NP) ? 1 : 2);
    int bucket = blockIdx.x & (NBUCK - 1);
    float* p = bnpart + ((size_t)g3 * NBUCK + bucket) * 512;
    atomAddF(&p[t], S);
    atomAddF(&p[256 + t], Q);
}

// ---------------- indexed L2 gather: only head-consumed drug/dis rows ----------------
__global__ __launch_bounds__(256) void k_gather_idx(const unsigned short* __restrict__ h,
                                                    const float* __restrict__ dinv,
                                                    const float* __restrict__ dr_b,
                                                    const float* __restrict__ di_b,
                                                    const int* __restrict__ drug_idx,
                                                    const int* __restrict__ dis_idx,
                                                    const int2* __restrict__ csr2,
                                                    const int* __restrict__ rowStart,
                                                    float* __restrict__ outc) {
    int slot = blockIdx.x * 8 + (threadIdx.x >> 5);
    if (slot >= 2 * BATCH) return;
    int row = (slot < BATCH) ? drug_idx[slot] : (dis_idx[slot - BATCH] + SPAN_P);
    int lane = threadIdx.x & 31;
    int c0 = lane * 4;
    float a0[4];
    gather_core<128, 1>(h, 0, dinv, dr_b, di_b, nullptr, csr2, rowStart, row, c0, a0);
    float4 ov = {a0[0], a0[1], a0[2], a0[3]};
    *reinterpret_cast<float4*>(outc + (size_t)slot * 128 + c0) = ov;
}

// ---------------- L2 mol gather -> f32 ----------------
__global__ __launch_bounds__(256) void k_gather_mol(const unsigned short* __restrict__ h,
                                                    const float* __restrict__ dinv,
                                                    const float* __restrict__ mo_b,
                                                    const int2* __restrict__ csr2,
                                                    const int* __restrict__ rowStart,
                                                    float* __restrict__ molf, long long moff) {
    int row = NP + blockIdx.x * 8 + (threadIdx.x >> 5);
    int lane = threadIdx.x & 31;
    int c0 = lane * 4;
    float a0[4];
    gather_core<128, 1>(h, 0, dinv, nullptr, nullptr, mo_b, csr2, rowStart, row, c0, a0);
    float4 ov = {a0[0], a0[1], a0[2], a0[3]};
    *reinterpret_cast<float4*>(molf + ((size_t)row * 128 - moff) + c0) = ov;
}

// 3-graph coef from nbuck partial sets: part[(g*nbuck+b)*512 + {j | 256+j}]
__global__ void k_bn_coef3(const float* __restrict__ part, int nbuck,
                           const float* __restrict__ g0, const float* __restrict__ be0,
                           const float* __restrict__ g1, const float* __restrict__ be1,
                           const float* __restrict__ g2, const float* __restrict__ be2,
                           float* __restrict__ coef, float invN01, float invN2) {
    int gg = blockIdx.x;
    int j = threadIdx.x;
    const float* gp = (gg == 0) ? g0 : ((gg == 1) ? g1 : g2);
    const float* bp = (gg == 0) ? be0 : ((gg == 1) ? be1 : be2);
    float invN = (gg < 2) ? invN01 : invN2;
    float S = 0.f, Q = 0.f;
    for (int b = 0; b < nbuck; ++b) {
        const float* p = part + ((size_t)gg * nbuck + b) * 512;
        S += p[j];
        Q += p[256 + j];
    }
    float m = S * invN;
    float v = Q * invN - m * m;
    float r = rsqrtf(fmaxf(v, 0.f) + 1e-5f);
    float sc = gp[j] * r;
    coef[gg * 512 + j] = sc;
    coef[gg * 512 + 256 + j] = bp[j] - m * sc;
}

// ---------------- segment pool over f32 mol features [N_MOL][128] ----------------
__global__ __launch_bounds__(128) void k_pool_seg_f(const float* __restrict__ mfeat,
                                                    const int* __restrict__ batch,
                                                    float* __restrict__ mpool) {
    __shared__ int sr[2];
    __shared__ float smS[8][128];
    int b = blockIdx.x, t = threadIdx.x;
    if (t < 2) {
        int target = b + t;
        int lo = 0, hi = N_MOL;
        while (lo < hi) {
            int mid = (lo + hi) >> 1;
            if (batch[mid] < target) lo = mid + 1; else hi = mid;
        }
        sr[t] = lo;
    }
    __syncthreads();
    int g = t >> 4;
    int lane = t & 15;
    int c0 = lane * 8;
    float s[8];
#pragma unroll
    for (int e = 0; e < 8; ++e) s[e] = 0.f;
    int e1 = sr[1];
    for (int i = sr[0] + g; i < e1; i += 8) {
        const float4 v0 = *reinterpret_cast<const float4*>(mfeat + (size_t)i * 128 + c0);
        const float4 v1 = *reinterpret_cast<const float4*>(mfeat + (size_t)i * 128 + c0 + 4);
        s[0] += v0.x; s[1] += v0.y; s[2] += v0.z; s[3] += v0.w;
        s[4] += v1.x; s[5] += v1.y; s[6] += v1.z; s[7] += v1.w;
    }
#pragma unroll
    for (int e = 0; e < 8; ++e) smS[g][c0 + e] = s[e];
    __syncthreads();
    float S = 0.f;
#pragma unroll
    for (int g2 = 0; g2 < 8; ++g2) S += smS[g2][t];
    mpool[(size_t)b * 128 + t] = S;
}

// ---------------- head: conv1 (compact dgs[8192][128]: drug @b, dis @4096+b) ----------------
__global__ __launch_bounds__(64) void k_conv1(const float* __restrict__ dgs,
                                              const float* __restrict__ mpool,
                                              const float* __restrict__ W,
                                              const float* __restrict__ bias,
                                              float* __restrict__ y1) {
    __shared__ float xs[3][128];
    __shared__ float w[54];
    __shared__ float bb[6];
    int b = blockIdx.x, t = threadIdx.x;
    const float* r0 = dgs + (size_t)b * 128;
    const float* r1 = mpool + (size_t)b * 128;
    const float* r2 = dgs + (size_t)(BATCH + b) * 128;
    xs[0][t] = r0[t]; xs[0][t + 64] = r0[t + 64];
    xs[1][t] = r1[t]; xs[1][t + 64] = r1[t + 64];
    xs[2][t] = r2[t]; xs[2][t + 64] = r2[t + 64];
    if (t < 54) w[t] = W[t];
    if (t < 6) bb[t] = bias[t];
    __syncthreads();
    int l0 = 2 * t, l1 = l0 + 1;
#pragma unroll
    for (int o = 0; o < 6; ++o) {
        float ya = bb[o], yb = bb[o];
#pragma unroll
        for (int i = 0; i < 3; ++i) {
            const float* wi = &w[(o * 3 + i) * 3];
            float xm1 = (l0 > 0) ? xs[i][l0 - 1] : 0.f;
            float x0 = xs[i][l0];
            float x1 = xs[i][l1];
            float x2 = (l1 < 127) ? xs[i][l1 + 1] : 0.f;
            ya += wi[0] * xm1 + wi[1] * x0 + wi[2] * x1;
            yb += wi[0] * x0 + wi[1] * x1 + wi[2] * x2;
        }
        y1[((size_t)b * 6 + o) * 64 + t] = fmaxf(ya, yb);
    }
}

// hb per 'which': [0..5]=sum [8..13]=sumsq [16..21]=mean [24..29]=rstd; grid (6,16)
__global__ __launch_bounds__(256) void k_head_stats(const float* __restrict__ y,
                                                    float* __restrict__ hb, int which, int L) {
    int o = blockIdx.x;
    int b0 = blockIdx.y * 256;
    int t = threadIdx.x;
    float s = 0.f, q = 0.f;
    int per = 256 * L;
    for (int idx = t; idx < per; idx += 256) {
        int b = b0 + idx / L;
        int l = idx - (idx / L) * L;
        float v = y[((size_t)b * 6 + o) * L + l];
        s += v; q += v * v;
    }
    __shared__ float sms[4], smq[4];
#pragma unroll
    for (int off = 32; off > 0; off >>= 1) {
        s += __shfl_down(s, off);
        q += __shfl_down(q, off);
    }
    if ((t & 63) == 0) { sms[t >> 6] = s; smq[t >> 6] = q; }
    __syncthreads();
    if (t == 0) {
        float S = 0.f, Q = 0.f;
        for (int i = 0; i < 4; ++i) { S += sms[i]; Q += smq[i]; }
        atomAddF(hb + which * 32 + o, S);
        atomAddF(hb + which * 32 + 8 + o, Q);
    }
}

__global__ void k_bn_fin(float* __restrict__ hb, int which, float invN) {
    int o = threadIdx.x;
    if (o >= 6) return;
    float* p = hb + which * 32;
    float m = p[o] * invN;
    float v = p[8 + o] * invN - m * m;
    p[16 + o] = m;
    p[24 + o] = rsqrtf(fmaxf(v, 0.f) + 1e-5f);
}

// ---------------- head: conv2 ----------------
__global__ __launch_bounds__(64) void k_conv2(const float* __restrict__ y1,
                                              const float* __restrict__ hb,
                                              const float* __restrict__ g1,
                                              const float* __restrict__ be1,
                                              const float* __restrict__ W,
                                              const float* __restrict__ bias,
                                              float* __restrict__ y2) {
    __shared__ float xs[6][64];
    __shared__ float w[108];
    __shared__ float bb[6];
    int b = blockIdx.x, t = threadIdx.x;
    const float* mean = hb + 16;
    const float* rstd = hb + 24;
    for (int idx = t; idx < 384; idx += 64) {
        int o = idx >> 6, l = idx & 63;
        float v = y1[((size_t)b * 6 + o) * 64 + l];
        v = g1[o] * (v - mean[o]) * rstd[o] + be1[o];
        xs[o][l] = fmaxf(v, 0.f);
    }
    for (int idx = t; idx < 108; idx += 64) w[idx] = W[idx];
    if (t < 6) bb[t] = bias[t];
    __syncthreads();
    if (t >= 32) return;
    int l0 = 2 * t, l1 = l0 + 1;
#pragma unroll
    for (int o = 0; o < 6; ++o) {
        float ya = bb[o], yb = bb[o];
#pragma unroll
        for (int i = 0; i < 6; ++i) {
            const float* wi = &w[(o * 6 + i) * 3];
            float xm1 = (l0 > 0) ? xs[i][l0 - 1] : 0.f;
            float x0 = xs[i][l0];
            float x1 = xs[i][l1];
            float x2 = (l1 < 63) ? xs[i][l1 + 1] : 0.f;
            ya += wi[0] * xm1 + wi[1] * x0 + wi[2] * x1;
            yb += wi[0] * x0 + wi[1] * x1 + wi[2] * x2;
        }
        y2[((size_t)b * 6 + o) * 32 + t] = fmaxf(ya, yb);
    }
}

// ---------------- head final ----------------
__global__ __launch_bounds__(128) void k_head(const float* __restrict__ y2,
                                              const float* __restrict__ hb,
                                              const float* __restrict__ g2,
                                              const float* __restrict__ be2,
                                              const float* __restrict__ l1W,
                                              const float* __restrict__ l1b,
                                              const float* __restrict__ l2W,
                                              const float* __restrict__ l2b,
                                              float* __restrict__ out) {
    __shared__ float fs[192];
    __shared__ float sm[2];
    int b = blockIdx.x, t = threadIdx.x;
    const float* mean = hb + 32 + 16;
    const float* rstd = hb + 32 + 24;
    for (int idx = t; idx < 192; idx += 128) {
        int o = idx >> 5, l = idx & 31;
        float v = y2[((size_t)b * 6 + o) * 32 + l];
        v = g2[o] * (v - mean[o]) * rstd[o] + be2[o];
        fs[idx] = fmaxf(v, 0.f);
    }
    __syncthreads();
    float h = l1b[t];
    for (int k = 0; k < 192; ++k)
        h += fs[k] * l1W[k * 128 + t];
    h = fmaxf(h, 0.f);
    float p = h * l2W[t];
#pragma unroll
    for (int off = 32; off > 0; off >>= 1) p += __shfl_down(p, off);
    if ((t & 63) == 0) sm[t >> 6] = p;
    __syncthreads();
    if (t == 0) out[b] = sm[0] + sm[1] + l2b[0];
}

extern "C" void kernel_launch(void* const* d_in, const int* in_sizes, int n_in,
                              void* d_out, int out_size, void* d_ws, size_t ws_size,
                              hipStream_t stream) {
    float* out = (float*)d_out;
    if (n_in != 52) { k_sentinel<<<16, 256, 0, stream>>>(out, out_size, -111.f); return; }
    if (in_sizes[0] != N_DRUG * 128 || in_sizes[29] != NF * NV * DH || in_sizes[48] != 192 * 128) {
        k_sentinel<<<16, 256, 0, stream>>>(out, out_size, -222.f); return;
    }

    char* w = (char*)d_ws;
    auto alloc = [&](size_t bytes) { char* p = w; w += (bytes + 255) & ~(size_t)255; return p; };
    unsigned short* B1 = (unsigned short*)alloc((size_t)NTOT * 256 * 2);
    unsigned short* B2 = (unsigned short*)alloc((size_t)NTOT * 256 * 2);
    float* molf = (float*)B1;                         // alias: B1 dead after L2 GEMM
    float* dgs  = molf + (size_t)N_MOL * 128;
    float* mpool = (float*)alloc((size_t)BATCH * 128 * 4);
    int*   cnt      = (int*)alloc((size_t)NTOT * 4);
    float* dinv     = (float*)alloc((size_t)NTOT * 4);
    int*   rowStart = (int*)alloc((size_t)(NTOT + 1) * 4);
    int*   cursor   = (int*)alloc((size_t)NTOT * 4);
    int2*  csr2     = (int2*)alloc((size_t)ETOT * 8);
    int*   bsum     = (int*)alloc(1024 * 4);
    float* bnbuf    = (float*)alloc(1536 * 4);        // [3][1][512] for L0 GEMM stats
    float* bnpart   = (float*)alloc((size_t)3 * NBUCK * 512 * 4);  // contiguous after bnbuf
    float* coef     = (float*)alloc(1536 * 4);
    unsigned short* drT0 = (unsigned short*)alloc((size_t)128 * 256 * 2);
    unsigned short* drT1 = (unsigned short*)alloc((size_t)256 * 256 * 2);
    unsigned short* drT2 = (unsigned short*)alloc((size_t)256 * 128 * 2);
    unsigned short* diT0 = (unsigned short*)alloc((size_t)128 * 256 * 2);
    unsigned short* diT1 = (unsigned short*)alloc((size_t)256 * 256 * 2);
    unsigned short* diT2 = (unsigned short*)alloc((size_t)256 * 128 * 2);
    unsigned short* moT0 = (unsigned short*)alloc((size_t)256 * 256 * 2);
    unsigned short* moT1 = (unsigned short*)alloc((size_t)256 * 256 * 2);
    unsigned short* moT2 = (unsigned short*)alloc((size_t)256 * 128 * 2);
    float* hstat = (float*)alloc(64 * 4);
    float* y1    = (float*)alloc((size_t)BATCH * 6 * 64 * 4);
    float* y2    = (float*)alloc((size_t)BATCH * 6 * 32 * 4);
    if ((size_t)(w - (char*)d_ws) > ws_size) {
        k_sentinel<<<16, 256, 0, stream>>>(out, out_size, -333.f); return;
    }

    const float* drug_x  = (const float*)d_in[0];
    const int* drug_ei   = (const int*)d_in[1];
    const int* drug_idx  = (const int*)d_in[2];
    const float* dis_x   = (const float*)d_in[3];
    const int* dis_ei    = (const int*)d_in[4];
    const int* dis_idx   = (const int*)d_in[5];
    const int* mol_x     = (const int*)d_in[6];
    const int* mol_ei    = (const int*)d_in[7];
    const int* mol_b     = (const int*)d_in[8];
    const float *dr_W0 = (const float*)d_in[9], *dr_W1 = (const float*)d_in[10], *dr_W2 = (const float*)d_in[11];
    const float *dr_b2 = (const float*)d_in[14];
    const float *dr_g0 = (const float*)d_in[15], *dr_g1 = (const float*)d_in[16];
    const float *dr_be0 = (const float*)d_in[17], *dr_be1 = (const float*)d_in[18];
    const float *di_W0 = (const float*)d_in[19], *di_W1 = (const float*)d_in[20], *di_W2 = (const float*)d_in[21];
    const float *di_b2 = (const float*)d_in[24];
    const float *di_g0 = (const float*)d_in[25], *di_g1 = (const float*)d_in[26];
    const float *di_be0 = (const float*)d_in[27], *di_be1 = (const float*)d_in[28];
    const float* mol_emb = (const float*)d_in[29];
    const float *mo_W0 = (const float*)d_in[30], *mo_W1 = (const float*)d_in[31], *mo_W2 = (const float*)d_in[32];
    const float *mo_b2 = (const float*)d_in[35];
    const float *mo_g0 = (const float*)d_in[36], *mo_g1 = (const float*)d_in[37];
    const float *mo_be0 = (const float*)d_in[38], *mo_be1 = (const float*)d_in[39];
    const float *c1_W = (const float*)d_in[40], *c1_b = (const float*)d_in[41];
    const float *c1_g = (const float*)d_in[42], *c1_be = (const float*)d_in[43];
    const float *c2_W = (const float*)d_in[44], *c2_b = (const float*)d_in[45];
    const float *c2_g = (const float*)d_in[46], *c2_be = (const float*)d_in[47];
    const float *l1_W = (const float*)d_in[48], *l1_b = (const float*)d_in[49];
    const float *l2_W = (const float*)d_in[50], *l2_b = (const float*)d_in[51];

    const float invN01 = 1.0f / (float)N_DRUG;
    const float invNM  = 1.0f / (float)N_MOL;
    const long long MOFF = (long long)NP * 128;

    // zero bnbuf + bnpart (contiguous, both 256B-aligned sizes)
    hipMemsetAsync(bnbuf, 0, (1536 + (size_t)3 * NBUCK * 512) * sizeof(float), stream);

    // ---- inputs (merged cast+atom_enc) ----
    k_in_prep<<<NP * 32 / 256 + N_MOL / 4, 256, 0, stream>>>(drug_x, dis_x, mol_x, mol_emb,
                                                             B1, B1 + MOFF);

    // ---- merged CSR ----
    hipMemsetAsync(cnt, 0, (size_t)NTOT * sizeof(int), stream);
    k_count3<<<(ETOT + 255) / 256, 256, 0, stream>>>(drug_ei, dis_ei, mol_ei, cnt);
    int nb = (NTOT + 255) / 256;
    k_scan1<<<nb, 256, 0, stream>>>(cnt, rowStart, bsum, dinv, NTOT);
    k_scan2b<<<1, 256, 0, stream>>>(bsum, nb);
    k_scan3<<<nb, 256, 0, stream>>>(rowStart, cursor, bsum, NTOT, ETOT);
    k_fill3<<<(ETOT + 255) / 256, 256, 0, stream>>>(drug_ei, dis_ei, mol_ei, dinv, cursor, csr2);

    // ---- all weights in one dispatch ----
    k_wcast9<<<(425984 + 255) / 256, 256, 0, stream>>>(dr_W0, dr_W1, dr_W2, di_W0, di_W1, di_W2,
                                                       mo_W0, mo_W1, mo_W2,
                                                       drT0, drT1, drT2, diT0, diT1, diT2,
                                                       moT0, moT1, moT2);

    // ---- L0: merged gather (agg-first) B1 -> B2, merged GEMM B2 -> B1[NTOT][256] (+stats) ----
    k_gather_l0<<<NTOT / 8, 256, 0, stream>>>(B1, dinv, csr2, rowStart, B2, MOFF);
    k_gemm_mfma<0, 1><<<dim3(2, 826), 256, 0, stream>>>(B2, drT0, diT0, moT0, nullptr,
        B1, bnbuf, 157, 314, SPAN_P, NP, N_DRUG, N_DIS, N_MOL, 0, 128, 256, MOFF, NP, 256);
    k_bn_coef3<<<3, 256, 0, stream>>>(bnbuf, 1, dr_g0, dr_be0, di_g0, di_be0, mo_g0, mo_be0,
                                      coef, invN01, invNM);
    // ---- L1: merged GEMM, gather with fused BN stats, coef ----
    k_gemm_mfma<1, 0><<<dim3(2, 826), 256, 0, stream>>>(B1, drT1, diT1, moT1, coef,
        B2, nullptr, 157, 314, SPAN_P, NP, N_DRUG, N_DIS, N_MOL, 0, 256, 256, 0, 0, 256);
    k_gather_l1s<<<NTOT / 8, 256, 0, stream>>>(B2, dinv, csr2, rowStart, B1, bnpart);
    k_bn_coef3<<<3, 256, 0, stream>>>(bnpart, NBUCK, dr_g1, dr_be1, di_g1, di_be1, mo_g1, mo_be1,
                                      coef, invN01, invNM);
    // ---- L2: GEMM; sparse gathers (only consumed rows) ----
    k_gemm_mfma<1, 0><<<dim3(1, 826), 256, 0, stream>>>(B1, drT2, diT2, moT2, coef,
        B2, nullptr, 157, 314, SPAN_P, NP, N_DRUG, N_DIS, N_MOL, 0, 256, 256, 0, 0, 128);
    k_gather_idx<<<2 * BATCH / 8, 256, 0, stream>>>(B2, dinv, dr_b2, di_b2, drug_idx, dis_idx,
                                                    csr2, rowStart, dgs);
    k_gather_mol<<<N_MOL / 8, 256, 0, stream>>>(B2, dinv, mo_b2, csr2, rowStart, molf, MOFF);
    k_pool_seg_f<<<BATCH, 128, 0, stream>>>(molf, mol_b, mpool);

    // ---- head ----
    hipMemsetAsync(hstat, 0, 64 * 4, stream);
    k_conv1<<<BATCH, 64, 0, stream>>>(dgs, mpool, c1_W, c1_b, y1);
    k_head_stats<<<dim3(6, BATCH / 256), 256, 0, stream>>>(y1, hstat, 0, 64);
    k_bn_fin<<<1, 8, 0, stream>>>(hstat, 0, 1.0f / (BATCH * 64.0f));
    k_conv2<<<BATCH, 64, 0, stream>>>(y1, hstat, c1_g, c1_be, c2_W, c2_b, y2);
    k_head_stats<<<dim3(6, BATCH / 256), 256, 0, stream>>>(y2, hstat, 1, 32);
    k_bn_fin<<<1, 8, 0, stream>>>(hstat, 1, 1.0f / (BATCH * 32.0f));
    k_head<<<BATCH, 128, 0, stream>>>(y2, hstat, c2_g, c2_be, l1_W, l1_b, l2_W, l2_b, out);
}

// Round 18
// 537.095 us; speedup vs baseline: 1.1101x; 1.0060x over previous
//
#include <hip/hip_runtime.h>
#include <hip/hip_bf16.h>

#define N_DRUG 20000
#define N_DIS  20000
#define E_G    320000
#define BATCH  4096
#define N_MOL  65536
#define E_MOL  262144
#define NF     9
#define NV     128
#define DH     256
#define SPAN_P 20096                 // 157*128 pad per drug/dis graph (32-row aligned)
#define NP     40192                 // 2*SPAN_P (32-row aligned)
#define NTOT   105728                // NP + N_MOL (32-row aligned)
#define ETOT   902144                // 2*E_G + E_MOL
#define NBUCK  16

typedef short s16x8 __attribute__((ext_vector_type(8)));
typedef unsigned short u16x8 __attribute__((ext_vector_type(8)));
typedef float f32x4 __attribute__((ext_vector_type(4)));

typedef __attribute__((address_space(1))) const void gvoid_t;
typedef __attribute__((address_space(3))) void lvoid_t;

__device__ __forceinline__ float bfu2f(unsigned short u) {
    return __uint_as_float(((unsigned int)u) << 16);
}
__device__ __forceinline__ unsigned short f2bfu(float f) {
    __hip_bfloat16 b = __float2bfloat16(f);
    return *reinterpret_cast<unsigned short*>(&b);
}
__device__ __forceinline__ void atomAddF(float* p, float v) { unsafeAtomicAdd(p, v); }

// ---------------- misc ----------------
__global__ void k_sentinel(float* out, int n, float v) {
    int i = blockIdx.x * 256 + threadIdx.x;
    if (i < n) out[i] = v;
}

// merged input prep: blocks [0,5024) cast drug+dis -> B1[NP][128]; rest atom-enc -> B1+MOFF
__global__ __launch_bounds__(256) void k_in_prep(const float* __restrict__ a,
                                                 const float* __restrict__ b,
                                                 const int* __restrict__ mol_x,
                                                 const float* __restrict__ emb,
                                                 unsigned short* __restrict__ B1,
                                                 unsigned short* __restrict__ molh) {
    __shared__ int sidx[4][NF];
    int bx = blockIdx.x, t = threadIdx.x;
    if (bx < NP * 32 / 256) {
        int i4 = bx * 256 + t;
        int row = i4 >> 5, c4 = (i4 & 31) * 4;
        float4 v = {0.f, 0.f, 0.f, 0.f};
        if (row < N_DRUG) v = *reinterpret_cast<const float4*>(a + (size_t)row * 128 + c4);
        else if (row >= SPAN_P && row < SPAN_P + N_DIS)
            v = *reinterpret_cast<const float4*>(b + (size_t)(row - SPAN_P) * 128 + c4);
        ushort4 o = {f2bfu(v.x), f2bfu(v.y), f2bfu(v.z), f2bfu(v.w)};
        *reinterpret_cast<ushort4*>(B1 + (size_t)row * 128 + c4) = o;
    } else {
        int blk = bx - NP * 32 / 256;
        if (t < 4 * NF) sidx[t / NF][t % NF] = mol_x[(blk * 4 + t / NF) * NF + t % NF];
        __syncthreads();
        int r = t >> 6, lane = t & 63;
        int c0 = lane * 4;
        int row = blk * 4 + r;
        float4 s = {0.f, 0.f, 0.f, 0.f};
#pragma unroll
        for (int f = 0; f < NF; ++f) {
            const float4 v = *reinterpret_cast<const float4*>(emb + ((size_t)f * NV + sidx[r][f]) * DH + c0);
            s.x += v.x; s.y += v.y; s.z += v.z; s.w += v.w;
        }
        ushort4 ov = {f2bfu(s.x), f2bfu(s.y), f2bfu(s.z), f2bfu(s.w)};
        *reinterpret_cast<ushort4*>(molh + (size_t)row * DH + c0) = ov;
    }
}

// all 9 weight transposes in one kernel: W[K][N] f32 -> Wt[N][K] bf16
__global__ void k_wcast9(const float* __restrict__ a0, const float* __restrict__ a1,
                         const float* __restrict__ a2, const float* __restrict__ b0,
                         const float* __restrict__ b1, const float* __restrict__ b2,
                         const float* __restrict__ m0, const float* __restrict__ m1,
                         const float* __restrict__ m2,
                         unsigned short* __restrict__ A0, unsigned short* __restrict__ A1,
                         unsigned short* __restrict__ A2, unsigned short* __restrict__ B0,
                         unsigned short* __restrict__ B1, unsigned short* __restrict__ B2,
                         unsigned short* __restrict__ M0, unsigned short* __restrict__ M1,
                         unsigned short* __restrict__ M2) {
    int i = blockIdx.x * 256 + threadIdx.x;
    const float* W; unsigned short* T; int K, N, e;
    if (i < 32768)       { W = a0; T = A0; K = 128; N = 256; e = i; }
    else if (i < 98304)  { W = a1; T = A1; K = 256; N = 256; e = i - 32768; }
    else if (i < 131072) { W = a2; T = A2; K = 256; N = 128; e = i - 98304; }
    else if (i < 163840) { W = b0; T = B0; K = 128; N = 256; e = i - 131072; }
    else if (i < 229376) { W = b1; T = B1; K = 256; N = 256; e = i - 163840; }
    else if (i < 262144) { W = b2; T = B2; K = 256; N = 128; e = i - 229376; }
    else if (i < 327680) { W = m0; T = M0; K = 256; N = 256; e = i - 262144; }
    else if (i < 393216) { W = m1; T = M1; K = 256; N = 256; e = i - 327680; }
    else if (i < 425984) { W = m2; T = M2; K = 256; N = 128; e = i - 393216; }
    else return;
    int k = e / N, c = e - k * N;
    T[(size_t)c * K + k] = f2bfu(W[e]);
}

// ---------------- merged-graph degree / CSR ----------------
__global__ void k_count3(const int* __restrict__ eA, const int* __restrict__ eB,
                         const int* __restrict__ eC, int* __restrict__ cnt) {
    int e = blockIdx.x * 256 + threadIdx.x;
    if (e >= ETOT) return;
    int d;
    if (e < E_G) d = eA[E_G + e];
    else if (e < 2 * E_G) d = eB[E_G + (e - E_G)] + SPAN_P;
    else d = eC[E_MOL + (e - 2 * E_G)] + NP;
    atomicAdd(&cnt[d], 1);
}

__global__ void k_scan1(const int* __restrict__ cnt, int* __restrict__ rowStart,
                        int* __restrict__ bsum, float* __restrict__ dinv, int n) {
    __shared__ int sh[256];
    int i = blockIdx.x * 256 + threadIdx.x;
    int v = (i < n) ? cnt[i] : 0;
    if (i < n) dinv[i] = rsqrtf(1.0f + (float)v);
    sh[threadIdx.x] = v;
    __syncthreads();
    for (int off = 1; off < 256; off <<= 1) {
        int t = (threadIdx.x >= off) ? sh[threadIdx.x - off] : 0;
        __syncthreads();
        sh[threadIdx.x] += t;
        __syncthreads();
    }
    if (i < n) rowStart[i] = sh[threadIdx.x] - v;
    if (threadIdx.x == 255) bsum[blockIdx.x] = sh[255];
}
__global__ void k_scan2b(int* __restrict__ bsum, int nb) {
    __shared__ int sh[256];
    __shared__ int carry;
    int t = threadIdx.x;
    if (t == 0) carry = 0;
    __syncthreads();
    for (int c0 = 0; c0 < nb; c0 += 256) {
        int v = (c0 + t < nb) ? bsum[c0 + t] : 0;
        sh[t] = v;
        __syncthreads();
        for (int off = 1; off < 256; off <<= 1) {
            int u = (t >= off) ? sh[t - off] : 0;
            __syncthreads();
            sh[t] += u;
            __syncthreads();
        }
        if (c0 + t < nb) bsum[c0 + t] = carry + sh[t] - v;
        __syncthreads();
        if (t == 0) carry += sh[255];
        __syncthreads();
    }
}
__global__ void k_scan3(int* __restrict__ rowStart, int* __restrict__ cursor,
                        const int* __restrict__ bsum, int n, int E) {
    int i = blockIdx.x * 256 + threadIdx.x;
    if (i < n) {
        int r = rowStart[i] + bsum[blockIdx.x];
        rowStart[i] = r;
        cursor[i] = r;
    }
    if (i == 0) rowStart[n] = E;
}
__global__ void k_fill3(const int* __restrict__ eA, const int* __restrict__ eB,
                        const int* __restrict__ eC, const float* __restrict__ dinv,
                        int* __restrict__ cursor, int2* __restrict__ csr2) {
    int e = blockIdx.x * 256 + threadIdx.x;
    if (e >= ETOT) return;
    int s, d;
    if (e < E_G) { s = eA[e]; d = eA[E_G + e]; }
    else if (e < 2 * E_G) { int i = e - E_G; s = eB[i] + SPAN_P; d = eB[E_G + i] + SPAN_P; }
    else { int i = e - 2 * E_G; s = eC[i] + NP; d = eC[E_MOL + i] + NP; }
    int p = atomicAdd(&cursor[d], 1);
    csr2[p] = make_int2(s, __float_as_int(dinv[s] * dinv[d]));
}

// ---------------- MFMA GEMM: 3 graphs batched, per-graph K / A-base ----------------
template<int AFFINE, int STATS>
__global__ __launch_bounds__(256) void k_gemm_mfma(const unsigned short* __restrict__ A,
                                                   const unsigned short* __restrict__ Bt0,
                                                   const unsigned short* __restrict__ Bt1,
                                                   const unsigned short* __restrict__ Bt2,
                                                   const float* __restrict__ coef,
                                                   unsigned short* __restrict__ Cout,
                                                   float* __restrict__ bnbuf,
                                                   int tb0, int tb1, int boff1, int boff2,
                                                   int m0, int m1, int m2, int gbase,
                                                   int K01, int K2, long long abase2,
                                                   int arow2, int N) {
    __shared__ unsigned short Al[2][4][128][8];
    __shared__ unsigned short Bl[2][4][128][8];
    __shared__ float csc[256], csh[256];
    const int tid = threadIdx.x;
    const int y = blockIdx.y;
    const int bm = y * 128;
    const int bn = blockIdx.x * 128;
    const int g = (y >= tb1) ? 2 : ((y >= tb0) ? 1 : 0);
    const int Kg = (g == 2) ? K2 : K01;
    const int boff = (g == 0) ? 0 : ((g == 1) ? boff1 : boff2);
    const int Mloc = (g == 0) ? m0 : ((g == 1) ? m1 : m2);
    const int lbm = bm - boff;
    const unsigned short* Ag = (g == 2) ? (A + abase2) : A;
    const int arow = (g == 2) ? arow2 : 0;
    const unsigned short* Bt = (g == 0) ? Bt0 : ((g == 1) ? Bt1 : Bt2);
    const int gs = gbase + g;
    const int w = tid >> 6, l = tid & 63;
    const int wrow = (w >> 1) * 64, wcol = (w & 1) * 64;
    const int kg = l >> 4, lr = l & 15;

    if (AFFINE) {
        for (int i = tid; i < Kg; i += 256) {
            csc[i] = coef[gs * 512 + i];
            csh[i] = coef[gs * 512 + 256 + i];
        }
    }
    if (lbm + 128 > Mloc) {
        for (int s = tid; s < 1024; s += 256) {
            u16x8 z = {0, 0, 0, 0, 0, 0, 0, 0};
            *reinterpret_cast<u16x8*>(&Al[0][0][0][0] + s * 8) = z;
        }
    }
    __syncthreads();

    auto stage = [&](int buf, int k0) {
#pragma unroll
        for (int i = 0; i < 4; ++i) {
            int id = w * 4 + i;
            int koff = (id >> 1) & 3;
            int half = id & 1;
            int row = half * 64 + l;
            if (id < 8) {
                if (lbm + row < Mloc) {
                    const unsigned short* gsrc = Ag + (size_t)(bm - arow + row) * Kg + k0 + koff * 8;
                    __builtin_amdgcn_global_load_lds((gvoid_t*)gsrc,
                        (lvoid_t*)&Al[buf][koff][half * 64][0], 16, 0, 0);
                }
            } else {
                const unsigned short* gsrc = Bt + (size_t)(bn + row) * Kg + k0 + koff * 8;
                __builtin_amdgcn_global_load_lds((gvoid_t*)gsrc,
                    (lvoid_t*)&Bl[buf][koff][half * 64][0], 16, 0, 0);
            }
        }
    };

    f32x4 acc[4][4];
#pragma unroll
    for (int fm = 0; fm < 4; ++fm)
#pragma unroll
        for (int fn = 0; fn < 4; ++fn) acc[fm][fn] = f32x4{0.f, 0.f, 0.f, 0.f};

    stage(0, 0);
    __syncthreads();
    int nk = Kg >> 5;
    for (int t = 0; t < nk; ++t) {
        int cur = t & 1;
        if (t + 1 < nk) stage(cur ^ 1, (t + 1) * 32);
        s16x8 a[4], b[4];
#pragma unroll
        for (int fm = 0; fm < 4; ++fm)
            a[fm] = *reinterpret_cast<const s16x8*>(&Al[cur][kg][wrow + fm * 16 + lr][0]);
        if (AFFINE) {
            int k0 = t * 32;
            float sc[8], sh[8];
#pragma unroll
            for (int e = 0; e < 8; ++e) {
                sc[e] = csc[k0 + kg * 8 + e];
                sh[e] = csh[k0 + kg * 8 + e];
            }
#pragma unroll
            for (int fm = 0; fm < 4; ++fm)
#pragma unroll
                for (int e = 0; e < 8; ++e) {
                    float f = bfu2f((unsigned short)a[fm][e]);
                    a[fm][e] = (short)f2bfu(fmaxf(fmaf(sc[e], f, sh[e]), 0.f));
                }
        }
#pragma unroll
        for (int fn = 0; fn < 4; ++fn)
            b[fn] = *reinterpret_cast<const s16x8*>(&Bl[cur][kg][wcol + fn * 16 + lr][0]);
#pragma unroll
        for (int fm = 0; fm < 4; ++fm)
#pragma unroll
            for (int fn = 0; fn < 4; ++fn)
                acc[fm][fn] = __builtin_amdgcn_mfma_f32_16x16x32_bf16(a[fm], b[fn], acc[fm][fn], 0, 0, 0);
        __syncthreads();
    }
    // C/D layout: col = lane&15, row = (lane>>4)*4 + reg. Pad rows write 0.
#pragma unroll
    for (int fm = 0; fm < 4; ++fm)
#pragma unroll
        for (int r = 0; r < 4; ++r) {
            int row = bm + wrow + fm * 16 + kg * 4 + r;
#pragma unroll
            for (int fn = 0; fn < 4; ++fn) {
                int col = bn + wcol + fn * 16 + lr;
                Cout[(size_t)row * N + col] = f2bfu(acc[fm][fn][r]);
            }
        }
    if constexpr (STATS) {
        __shared__ float colS[128], colQ[128];
        if (tid < 128) { colS[tid] = 0.f; colQ[tid] = 0.f; }
        __syncthreads();
#pragma unroll
        for (int fn = 0; fn < 4; ++fn) {
            float s = 0.f, q = 0.f;
#pragma unroll
            for (int fm = 0; fm < 4; ++fm)
#pragma unroll
                for (int r = 0; r < 4; ++r) {
                    float v = acc[fm][fn][r];
                    s += v; q += v * v;
                }
            int cl = (w & 1) * 64 + fn * 16 + lr;
            atomicAdd(&colS[cl], s);
            atomicAdd(&colQ[cl], q);
        }
        __syncthreads();
        if (tid < 128) {
            atomAddF(&bnbuf[gs * 512 + bn + tid], colS[tid]);
            atomAddF(&bnbuf[gs * 512 + 256 + bn + tid], colQ[tid]);
        }
    }
}

// ---------------- gather core: one row, 32 lanes, PL channels/lane, 8/4/1 unroll ----------------
template<int C, int BIAS>
__device__ __forceinline__ void gather_core(const unsigned short* __restrict__ h,
                                            long long hoff,
                                            const float* __restrict__ dinv,
                                            const float* __restrict__ b0,
                                            const float* __restrict__ b1,
                                            const float* __restrict__ b2,
                                            const int2* __restrict__ csr2,
                                            const int* __restrict__ rowStart,
                                            int row, int c0, float* a0) {
    constexpr int PL = C / 32;
    auto loadRow = [&](int r, float* d) {
        const unsigned short* base = h + ((size_t)r * C - hoff) + c0;
        if constexpr (PL == 8) {
            u16x8 v = *reinterpret_cast<const u16x8*>(base);
#pragma unroll
            for (int e = 0; e < 8; ++e) d[e] = bfu2f((unsigned short)v[e]);
        } else {
            ushort4 v = *reinterpret_cast<const ushort4*>(base);
            d[0] = bfu2f(v.x); d[1] = bfu2f(v.y); d[2] = bfu2f(v.z); d[3] = bfu2f(v.w);
        }
    };
    float dd = dinv[row], ws = dd * dd;
    int beg = rowStart[row], end = rowStart[row + 1];
    float a1[PL], a2[PL], a3[PL];
    float t0[PL], t1[PL], t2[PL], t3[PL], t4[PL], t5[PL], t6[PL], t7[PL];
    loadRow(row, t0);
#pragma unroll
    for (int p = 0; p < PL; ++p) { a0[p] = t0[p] * ws; a1[p] = 0.f; a2[p] = 0.f; a3[p] = 0.f; }
    int j = beg;
    for (; j + 8 <= end; j += 8) {
        int2 e0 = csr2[j], e1 = csr2[j + 1], e2 = csr2[j + 2], e3 = csr2[j + 3];
        int2 e4 = csr2[j + 4], e5 = csr2[j + 5], e6 = csr2[j + 6], e7 = csr2[j + 7];
        float w0 = __int_as_float(e0.y), w1 = __int_as_float(e1.y);
        float w2 = __int_as_float(e2.y), w3 = __int_as_float(e3.y);
        float w4 = __int_as_float(e4.y), w5 = __int_as_float(e5.y);
        float w6 = __int_as_float(e6.y), w7 = __int_as_float(e7.y);
        loadRow(e0.x, t0); loadRow(e1.x, t1); loadRow(e2.x, t2); loadRow(e3.x, t3);
        loadRow(e4.x, t4); loadRow(e5.x, t5); loadRow(e6.x, t6); loadRow(e7.x, t7);
#pragma unroll
        for (int p = 0; p < PL; ++p) {
            a0[p] += w0 * t0[p]; a1[p] += w1 * t1[p];
            a2[p] += w2 * t2[p]; a3[p] += w3 * t3[p];
            a0[p] += w4 * t4[p]; a1[p] += w5 * t5[p];
            a2[p] += w6 * t6[p]; a3[p] += w7 * t7[p];
        }
    }
    for (; j + 4 <= end; j += 4) {
        int2 e0 = csr2[j], e1 = csr2[j + 1], e2 = csr2[j + 2], e3 = csr2[j + 3];
        float w0 = __int_as_float(e0.y), w1 = __int_as_float(e1.y);
        float w2 = __int_as_float(e2.y), w3 = __int_as_float(e3.y);
        loadRow(e0.x, t0); loadRow(e1.x, t1); loadRow(e2.x, t2); loadRow(e3.x, t3);
#pragma unroll
        for (int p = 0; p < PL; ++p) {
            a0[p] += w0 * t0[p]; a1[p] += w1 * t1[p];
            a2[p] += w2 * t2[p]; a3[p] += w3 * t3[p];
        }
    }
    for (; j < end; ++j) {
        int2 e0 = csr2[j];
        float ww = __int_as_float(e0.y);
        loadRow(e0.x, t0);
#pragma unroll
        for (int p = 0; p < PL; ++p) a0[p] += ww * t0[p];
    }
    const float* bp = nullptr;
    if (BIAS) bp = (row < SPAN_P) ? b0 : ((row < NP) ? b1 : b2);
#pragma unroll
    for (int p = 0; p < PL; ++p) {
        a0[p] += (a1[p] + a2[p]) + a3[p];
        if (BIAS) a0[p] += bp[c0 + p];
    }
}

// ---------------- L0 merged gather: [0,NP) C=128, [NP,NTOT) C=256; bf16 out ----------------
__global__ __launch_bounds__(256) void k_gather_l0(const unsigned short* __restrict__ B1,
                                                   const float* __restrict__ dinv,
                                                   const int2* __restrict__ csr2,
                                                   const int* __restrict__ rowStart,
                                                   unsigned short* __restrict__ B2,
                                                   long long moff) {
    int bx = blockIdx.x;
    int grp = threadIdx.x >> 5;
    int lane = threadIdx.x & 31;
    if (bx < NP / 8) {
        int row = bx * 8 + grp;
        int c0 = lane * 4;
        float a0[4];
        gather_core<128, 0>(B1, 0, dinv, nullptr, nullptr, nullptr, csr2, rowStart, row, c0, a0);
        ushort4 ov = {f2bfu(a0[0]), f2bfu(a0[1]), f2bfu(a0[2]), f2bfu(a0[3])};
        *reinterpret_cast<ushort4*>(B2 + (size_t)row * 128 + c0) = ov;
    } else {
        int row = NP + (bx - NP / 8) * 8 + grp;
        int c0 = lane * 8;
        float a0[8];
        gather_core<256, 0>(B1, moff, dinv, nullptr, nullptr, nullptr, csr2, rowStart, row, c0, a0);
        u16x8 ov;
#pragma unroll
        for (int e = 0; e < 8; ++e) ov[e] = f2bfu(a0[e]);
        *reinterpret_cast<u16x8*>(B2 + ((size_t)row * 256 - moff) + c0) = ov;
    }
}

// ---------------- L1 gather + fused BN stats: 32 rows/block, register-accumulated ----------------
// Per-thread channel slice fixed across its 4 rows -> (S,Q) accumulate in registers;
// one LDS reduce + one bucket-atomic set per 32 rows (was per 8).
__global__ __launch_bounds__(256) void k_gather_l1s(const unsigned short* __restrict__ B2,
                                                    const float* __restrict__ dinv,
                                                    const int2* __restrict__ csr2,
                                                    const int* __restrict__ rowStart,
                                                    unsigned short* __restrict__ B1,
                                                    float* __restrict__ bnpart) {
    __shared__ float smS[8][256];
    __shared__ float smQ[8][256];
    int grp = threadIdx.x >> 5;
    int lane = threadIdx.x & 31;
    int c0 = lane * 8;
    float S8[8], Q8[8];
#pragma unroll
    for (int e = 0; e < 8; ++e) { S8[e] = 0.f; Q8[e] = 0.f; }
    int r0 = blockIdx.x * 32;
    for (int q = 0; q < 4; ++q) {
        int row = r0 + q * 8 + grp;
        float a0[8];
        gather_core<256, 0>(B2, 0, dinv, nullptr, nullptr, nullptr, csr2, rowStart, row, c0, a0);
        u16x8 ov;
#pragma unroll
        for (int e = 0; e < 8; ++e) {
            ov[e] = f2bfu(a0[e]);
            float f = bfu2f((unsigned short)ov[e]);   // stats on the stored bf16 value
            S8[e] += f;
            Q8[e] += f * f;
        }
        *reinterpret_cast<u16x8*>(B1 + (size_t)row * 256 + c0) = ov;
    }
#pragma unroll
    for (int e = 0; e < 8; ++e) { smS[grp][c0 + e] = S8[e]; smQ[grp][c0 + e] = Q8[e]; }
    __syncthreads();
    int t = threadIdx.x;
    float S = 0.f, Q = 0.f;
#pragma unroll
    for (int g2 = 0; g2 < 8; ++g2) { S += smS[g2][t]; Q += smQ[g2][t]; }
    int g3 = (r0 < SPAN_P) ? 0 : ((r0 < NP) ? 1 : 2);   // 32-row blocks never straddle
    int bucket = blockIdx.x & (NBUCK - 1);
    float* p = bnpart + ((size_t)g3 * NBUCK + bucket) * 512;
    atomAddF(&p[t], S);
    atomAddF(&p[256 + t], Q);
}

// ---------------- indexed L2 gather: only head-consumed drug/dis rows ----------------
__global__ __launch_bounds__(256) void k_gather_idx(const unsigned short* __restrict__ h,
                                                    const float* __restrict__ dinv,
                                                    const float* __restrict__ dr_b,
                                                    const float* __restrict__ di_b,
                                                    const int* __restrict__ drug_idx,
                                                    const int* __restrict__ dis_idx,
                                                    const int2* __restrict__ csr2,
                                                    const int* __restrict__ rowStart,
                                                    float* __restrict__ outc) {
    int slot = blockIdx.x * 8 + (threadIdx.x >> 5);
    if (slot >= 2 * BATCH) return;
    int row = (slot < BATCH) ? drug_idx[slot] : (dis_idx[slot - BATCH] + SPAN_P);
    int lane = threadIdx.x & 31;
    int c0 = lane * 4;
    float a0[4];
    gather_core<128, 1>(h, 0, dinv, dr_b, di_b, nullptr, csr2, rowStart, row, c0, a0);
    float4 ov = {a0[0], a0[1], a0[2], a0[3]};
    *reinterpret_cast<float4*>(outc + (size_t)slot * 128 + c0) = ov;
}

// ---------------- L2 mol gather -> f32 ----------------
__global__ __launch_bounds__(256) void k_gather_mol(const unsigned short* __restrict__ h,
                                                    const float* __restrict__ dinv,
                                                    const float* __restrict__ mo_b,
                                                    const int2* __restrict__ csr2,
                                                    const int* __restrict__ rowStart,
                                                    float* __restrict__ molf, long long moff) {
    int row = NP + blockIdx.x * 8 + (threadIdx.x >> 5);
    int lane = threadIdx.x & 31;
    int c0 = lane * 4;
    float a0[4];
    gather_core<128, 1>(h, 0, dinv, nullptr, nullptr, mo_b, csr2, rowStart, row, c0, a0);
    float4 ov = {a0[0], a0[1], a0[2], a0[3]};
    *reinterpret_cast<float4*>(molf + ((size_t)row * 128 - moff) + c0) = ov;
}

// 3-graph coef from nbuck partial sets: part[(g*nbuck+b)*512 + {j | 256+j}]
__global__ void k_bn_coef3(const float* __restrict__ part, int nbuck,
                           const float* __restrict__ g0, const float* __restrict__ be0,
                           const float* __restrict__ g1, const float* __restrict__ be1,
                           const float* __restrict__ g2, const float* __restrict__ be2,
                           float* __restrict__ coef, float invN01, float invN2) {
    int gg = blockIdx.x;
    int j = threadIdx.x;
    const float* gp = (gg == 0) ? g0 : ((gg == 1) ? g1 : g2);
    const float* bp = (gg == 0) ? be0 : ((gg == 1) ? be1 : be2);
    float invN = (gg < 2) ? invN01 : invN2;
    float S = 0.f, Q = 0.f;
    for (int b = 0; b < nbuck; ++b) {
        const float* p = part + ((size_t)gg * nbuck + b) * 512;
        S += p[j];
        Q += p[256 + j];
    }
    float m = S * invN;
    float v = Q * invN - m * m;
    float r = rsqrtf(fmaxf(v, 0.f) + 1e-5f);
    float sc = gp[j] * r;
    coef[gg * 512 + j] = sc;
    coef[gg * 512 + 256 + j] = bp[j] - m * sc;
}

// ---------------- segment pool over f32 mol features [N_MOL][128] ----------------
__global__ __launch_bounds__(128) void k_pool_seg_f(const float* __restrict__ mfeat,
                                                    const int* __restrict__ batch,
                                                    float* __restrict__ mpool) {
    __shared__ int sr[2];
    __shared__ float smS[8][128];
    int b = blockIdx.x, t = threadIdx.x;
    if (t < 2) {
        int target = b + t;
        int lo = 0, hi = N_MOL;
        while (lo < hi) {
            int mid = (lo + hi) >> 1;
            if (batch[mid] < target) lo = mid + 1; else hi = mid;
        }
        sr[t] = lo;
    }
    __syncthreads();
    int g = t >> 4;
    int lane = t & 15;
    int c0 = lane * 8;
    float s[8];
#pragma unroll
    for (int e = 0; e < 8; ++e) s[e] = 0.f;
    int e1 = sr[1];
    for (int i = sr[0] + g; i < e1; i += 8) {
        const float4 v0 = *reinterpret_cast<const float4*>(mfeat + (size_t)i * 128 + c0);
        const float4 v1 = *reinterpret_cast<const float4*>(mfeat + (size_t)i * 128 + c0 + 4);
        s[0] += v0.x; s[1] += v0.y; s[2] += v0.z; s[3] += v0.w;
        s[4] += v1.x; s[5] += v1.y; s[6] += v1.z; s[7] += v1.w;
    }
#pragma unroll
    for (int e = 0; e < 8; ++e) smS[g][c0 + e] = s[e];
    __syncthreads();
    float S = 0.f;
#pragma unroll
    for (int g2 = 0; g2 < 8; ++g2) S += smS[g2][t];
    mpool[(size_t)b * 128 + t] = S;
}

// ---------------- head: conv1 (compact dgs[8192][128]: drug @b, dis @4096+b) ----------------
__global__ __launch_bounds__(64) void k_conv1(const float* __restrict__ dgs,
                                              const float* __restrict__ mpool,
                                              const float* __restrict__ W,
                                              const float* __restrict__ bias,
                                              float* __restrict__ y1) {
    __shared__ float xs[3][128];
    __shared__ float w[54];
    __shared__ float bb[6];
    int b = blockIdx.x, t = threadIdx.x;
    const float* r0 = dgs + (size_t)b * 128;
    const float* r1 = mpool + (size_t)b * 128;
    const float* r2 = dgs + (size_t)(BATCH + b) * 128;
    xs[0][t] = r0[t]; xs[0][t + 64] = r0[t + 64];
    xs[1][t] = r1[t]; xs[1][t + 64] = r1[t + 64];
    xs[2][t] = r2[t]; xs[2][t + 64] = r2[t + 64];
    if (t < 54) w[t] = W[t];
    if (t < 6) bb[t] = bias[t];
    __syncthreads();
    int l0 = 2 * t, l1 = l0 + 1;
#pragma unroll
    for (int o = 0; o < 6; ++o) {
        float ya = bb[o], yb = bb[o];
#pragma unroll
        for (int i = 0; i < 3; ++i) {
            const float* wi = &w[(o * 3 + i) * 3];
            float xm1 = (l0 > 0) ? xs[i][l0 - 1] : 0.f;
            float x0 = xs[i][l0];
            float x1 = xs[i][l1];
            float x2 = (l1 < 127) ? xs[i][l1 + 1] : 0.f;
            ya += wi[0] * xm1 + wi[1] * x0 + wi[2] * x1;
            yb += wi[0] * x0 + wi[1] * x1 + wi[2] * x2;
        }
        y1[((size_t)b * 6 + o) * 64 + t] = fmaxf(ya, yb);
    }
}

// hb per 'which': [0..5]=sum [8..13]=sumsq [16..21]=mean [24..29]=rstd; grid (6,16)
__global__ __launch_bounds__(256) void k_head_stats(const float* __restrict__ y,
                                                    float* __restrict__ hb, int which, int L) {
    int o = blockIdx.x;
    int b0 = blockIdx.y * 256;
    int t = threadIdx.x;
    float s = 0.f, q = 0.f;
    int per = 256 * L;
    for (int idx = t; idx < per; idx += 256) {
        int b = b0 + idx / L;
        int l = idx - (idx / L) * L;
        float v = y[((size_t)b * 6 + o) * L + l];
        s += v; q += v * v;
    }
    __shared__ float sms[4], smq[4];
#pragma unroll
    for (int off = 32; off > 0; off >>= 1) {
        s += __shfl_down(s, off);
        q += __shfl_down(q, off);
    }
    if ((t & 63) == 0) { sms[t >> 6] = s; smq[t >> 6] = q; }
    __syncthreads();
    if (t == 0) {
        float S = 0.f, Q = 0.f;
        for (int i = 0; i < 4; ++i) { S += sms[i]; Q += smq[i]; }
        atomAddF(hb + which * 32 + o, S);
        atomAddF(hb + which * 32 + 8 + o, Q);
    }
}

__global__ void k_bn_fin(float* __restrict__ hb, int which, float invN) {
    int o = threadIdx.x;
    if (o >= 6) return;
    float* p = hb + which * 32;
    float m = p[o] * invN;
    float v = p[8 + o] * invN - m * m;
    p[16 + o] = m;
    p[24 + o] = rsqrtf(fmaxf(v, 0.f) + 1e-5f);
}

// ---------------- head: conv2 ----------------
__global__ __launch_bounds__(64) void k_conv2(const float* __restrict__ y1,
                                              const float* __restrict__ hb,
                                              const float* __restrict__ g1,
                                              const float* __restrict__ be1,
                                              const float* __restrict__ W,
                                              const float* __restrict__ bias,
                                              float* __restrict__ y2) {
    __shared__ float xs[6][64];
    __shared__ float w[108];
    __shared__ float bb[6];
    int b = blockIdx.x, t = threadIdx.x;
    const float* mean = hb + 16;
    const float* rstd = hb + 24;
    for (int idx = t; idx < 384; idx += 64) {
        int o = idx >> 6, l = idx & 63;
        float v = y1[((size_t)b * 6 + o) * 64 + l];
        v = g1[o] * (v - mean[o]) * rstd[o] + be1[o];
        xs[o][l] = fmaxf(v, 0.f);
    }
    for (int idx = t; idx < 108; idx += 64) w[idx] = W[idx];
    if (t < 6) bb[t] = bias[t];
    __syncthreads();
    if (t >= 32) return;
    int l0 = 2 * t, l1 = l0 + 1;
#pragma unroll
    for (int o = 0; o < 6; ++o) {
        float ya = bb[o], yb = bb[o];
#pragma unroll
        for (int i = 0; i < 6; ++i) {
            const float* wi = &w[(o * 6 + i) * 3];
            float xm1 = (l0 > 0) ? xs[i][l0 - 1] : 0.f;
            float x0 = xs[i][l0];
            float x1 = xs[i][l1];
            float x2 = (l1 < 63) ? xs[i][l1 + 1] : 0.f;
            ya += wi[0] * xm1 + wi[1] * x0 + wi[2] * x1;
            yb += wi[0] * x0 + wi[1] * x1 + wi[2] * x2;
        }
        y2[((size_t)b * 6 + o) * 32 + t] = fmaxf(ya, yb);
    }
}

// ---------------- head final ----------------
__global__ __launch_bounds__(128) void k_head(const float* __restrict__ y2,
                                              const float* __restrict__ hb,
                                              const float* __restrict__ g2,
                                              const float* __restrict__ be2,
                                              const float* __restrict__ l1W,
                                              const float* __restrict__ l1b,
                                              const float* __restrict__ l2W,
                                              const float* __restrict__ l2b,
                                              float* __restrict__ out) {
    __shared__ float fs[192];
    __shared__ float sm[2];
    int b = blockIdx.x, t = threadIdx.x;
    const float* mean = hb + 32 + 16;
    const float* rstd = hb + 32 + 24;
    for (int idx = t; idx < 192; idx += 128) {
        int o = idx >> 5, l = idx & 31;
        float v = y2[((size_t)b * 6 + o) * 32 + l];
        v = g2[o] * (v - mean[o]) * rstd[o] + be2[o];
        fs[idx] = fmaxf(v, 0.f);
    }
    __syncthreads();
    float h = l1b[t];
    for (int k = 0; k < 192; ++k)
        h += fs[k] * l1W[k * 128 + t];
    h = fmaxf(h, 0.f);
    float p = h * l2W[t];
#pragma unroll
    for (int off = 32; off > 0; off >>= 1) p += __shfl_down(p, off);
    if ((t & 63) == 0) sm[t >> 6] = p;
    __syncthreads();
    if (t == 0) out[b] = sm[0] + sm[1] + l2b[0];
}

extern "C" void kernel_launch(void* const* d_in, const int* in_sizes, int n_in,
                              void* d_out, int out_size, void* d_ws, size_t ws_size,
                              hipStream_t stream) {
    float* out = (float*)d_out;
    if (n_in != 52) { k_sentinel<<<16, 256, 0, stream>>>(out, out_size, -111.f); return; }
    if (in_sizes[0] != N_DRUG * 128 || in_sizes[29] != NF * NV * DH || in_sizes[48] != 192 * 128) {
        k_sentinel<<<16, 256, 0, stream>>>(out, out_size, -222.f); return;
    }

    char* w = (char*)d_ws;
    auto alloc = [&](size_t bytes) { char* p = w; w += (bytes + 255) & ~(size_t)255; return p; };
    unsigned short* B1 = (unsigned short*)alloc((size_t)NTOT * 256 * 2);
    unsigned short* B2 = (unsigned short*)alloc((size_t)NTOT * 256 * 2);
    float* molf = (float*)B1;                         // alias: B1 dead after L2 GEMM
    float* dgs  = molf + (size_t)N_MOL * 128;
    float* mpool = (float*)alloc((size_t)BATCH * 128 * 4);
    int*   cnt      = (int*)alloc((size_t)NTOT * 4);
    float* dinv     = (float*)alloc((size_t)NTOT * 4);
    int*   rowStart = (int*)alloc((size_t)(NTOT + 1) * 4);
    int*   cursor   = (int*)alloc((size_t)NTOT * 4);
    int2*  csr2     = (int2*)alloc((size_t)ETOT * 8);
    int*   bsum     = (int*)alloc(1024 * 4);
    float* bnbuf    = (float*)alloc(1536 * 4);        // [3][1][512] for L0 GEMM stats
    float* bnpart   = (float*)alloc((size_t)3 * NBUCK * 512 * 4);  // contiguous after bnbuf
    float* coef     = (float*)alloc(1536 * 4);
    unsigned short* drT0 = (unsigned short*)alloc((size_t)128 * 256 * 2);
    unsigned short* drT1 = (unsigned short*)alloc((size_t)256 * 256 * 2);
    unsigned short* drT2 = (unsigned short*)alloc((size_t)256 * 128 * 2);
    unsigned short* diT0 = (unsigned short*)alloc((size_t)128 * 256 * 2);
    unsigned short* diT1 = (unsigned short*)alloc((size_t)256 * 256 * 2);
    unsigned short* diT2 = (unsigned short*)alloc((size_t)256 * 128 * 2);
    unsigned short* moT0 = (unsigned short*)alloc((size_t)256 * 256 * 2);
    unsigned short* moT1 = (unsigned short*)alloc((size_t)256 * 256 * 2);
    unsigned short* moT2 = (unsigned short*)alloc((size_t)256 * 128 * 2);
    float* hstat = (float*)alloc(64 * 4);
    float* y1    = (float*)alloc((size_t)BATCH * 6 * 64 * 4);
    float* y2    = (float*)alloc((size_t)BATCH * 6 * 32 * 4);
    if ((size_t)(w - (char*)d_ws) > ws_size) {
        k_sentinel<<<16, 256, 0, stream>>>(out, out_size, -333.f); return;
    }

    const float* drug_x  = (const float*)d_in[0];
    const int* drug_ei   = (const int*)d_in[1];
    const int* drug_idx  = (const int*)d_in[2];
    const float* dis_x   = (const float*)d_in[3];
    const int* dis_ei    = (const int*)d_in[4];
    const int* dis_idx   = (const int*)d_in[5];
    const int* mol_x     = (const int*)d_in[6];
    const int* mol_ei    = (const int*)d_in[7];
    const int* mol_b     = (const int*)d_in[8];
    const float *dr_W0 = (const float*)d_in[9], *dr_W1 = (const float*)d_in[10], *dr_W2 = (const float*)d_in[11];
    const float *dr_b2 = (const float*)d_in[14];
    const float *dr_g0 = (const float*)d_in[15], *dr_g1 = (const float*)d_in[16];
    const float *dr_be0 = (const float*)d_in[17], *dr_be1 = (const float*)d_in[18];
    const float *di_W0 = (const float*)d_in[19], *di_W1 = (const float*)d_in[20], *di_W2 = (const float*)d_in[21];
    const float *di_b2 = (const float*)d_in[24];
    const float *di_g0 = (const float*)d_in[25], *di_g1 = (const float*)d_in[26];
    const float *di_be0 = (const float*)d_in[27], *di_be1 = (const float*)d_in[28];
    const float* mol_emb = (const float*)d_in[29];
    const float *mo_W0 = (const float*)d_in[30], *mo_W1 = (const float*)d_in[31], *mo_W2 = (const float*)d_in[32];
    const float *mo_b2 = (const float*)d_in[35];
    const float *mo_g0 = (const float*)d_in[36], *mo_g1 = (const float*)d_in[37];
    const float *mo_be0 = (const float*)d_in[38], *mo_be1 = (const float*)d_in[39];
    const float *c1_W = (const float*)d_in[40], *c1_b = (const float*)d_in[41];
    const float *c1_g = (const float*)d_in[42], *c1_be = (const float*)d_in[43];
    const float *c2_W = (const float*)d_in[44], *c2_b = (const float*)d_in[45];
    const float *c2_g = (const float*)d_in[46], *c2_be = (const float*)d_in[47];
    const float *l1_W = (const float*)d_in[48], *l1_b = (const float*)d_in[49];
    const float *l2_W = (const float*)d_in[50], *l2_b = (const float*)d_in[51];

    const float invN01 = 1.0f / (float)N_DRUG;
    const float invNM  = 1.0f / (float)N_MOL;
    const long long MOFF = (long long)NP * 128;

    // zero bnbuf + bnpart (contiguous, both 256B-aligned sizes)
    hipMemsetAsync(bnbuf, 0, (1536 + (size_t)3 * NBUCK * 512) * sizeof(float), stream);

    // ---- inputs (merged cast+atom_enc) ----
    k_in_prep<<<NP * 32 / 256 + N_MOL / 4, 256, 0, stream>>>(drug_x, dis_x, mol_x, mol_emb,
                                                             B1, B1 + MOFF);

    // ---- merged CSR ----
    hipMemsetAsync(cnt, 0, (size_t)NTOT * sizeof(int), stream);
    k_count3<<<(ETOT + 255) / 256, 256, 0, stream>>>(drug_ei, dis_ei, mol_ei, cnt);
    int nb = (NTOT + 255) / 256;
    k_scan1<<<nb, 256, 0, stream>>>(cnt, rowStart, bsum, dinv, NTOT);
    k_scan2b<<<1, 256, 0, stream>>>(bsum, nb);
    k_scan3<<<nb, 256, 0, stream>>>(rowStart, cursor, bsum, NTOT, ETOT);
    k_fill3<<<(ETOT + 255) / 256, 256, 0, stream>>>(drug_ei, dis_ei, mol_ei, dinv, cursor, csr2);

    // ---- all weights in one dispatch ----
    k_wcast9<<<(425984 + 255) / 256, 256, 0, stream>>>(dr_W0, dr_W1, dr_W2, di_W0, di_W1, di_W2,
                                                       mo_W0, mo_W1, mo_W2,
                                                       drT0, drT1, drT2, diT0, diT1, diT2,
                                                       moT0, moT1, moT2);

    // ---- L0: merged gather (agg-first) B1 -> B2, merged GEMM B2 -> B1[NTOT][256] (+stats) ----
    k_gather_l0<<<NTOT / 8, 256, 0, stream>>>(B1, dinv, csr2, rowStart, B2, MOFF);
    k_gemm_mfma<0, 1><<<dim3(2, 826), 256, 0, stream>>>(B2, drT0, diT0, moT0, nullptr,
        B1, bnbuf, 157, 314, SPAN_P, NP, N_DRUG, N_DIS, N_MOL, 0, 128, 256, MOFF, NP, 256);
    k_bn_coef3<<<3, 256, 0, stream>>>(bnbuf, 1, dr_g0, dr_be0, di_g0, di_be0, mo_g0, mo_be0,
                                      coef, invN01, invNM);
    // ---- L1: merged GEMM, gather with fused BN stats (32 rows/block), coef ----
    k_gemm_mfma<1, 0><<<dim3(2, 826), 256, 0, stream>>>(B1, drT1, diT1, moT1, coef,
        B2, nullptr, 157, 314, SPAN_P, NP, N_DRUG, N_DIS, N_MOL, 0, 256, 256, 0, 0, 256);
    k_gather_l1s<<<NTOT / 32, 256, 0, stream>>>(B2, dinv, csr2, rowStart, B1, bnpart);
    k_bn_coef3<<<3, 256, 0, stream>>>(bnpart, NBUCK, dr_g1, dr_be1, di_g1, di_be1, mo_g1, mo_be1,
                                      coef, invN01, invNM);
    // ---- L2: GEMM; sparse gathers (only consumed rows) ----
    k_gemm_mfma<1, 0><<<dim3(1, 826), 256, 0, stream>>>(B1, drT2, diT2, moT2, coef,
        B2, nullptr, 157, 314, SPAN_P, NP, N_DRUG, N_DIS, N_MOL, 0, 256, 256, 0, 0, 128);
    k_gather_idx<<<2 * BATCH / 8, 256, 0, stream>>>(B2, dinv, dr_b2, di_b2, drug_idx, dis_idx,
                                                    csr2, rowStart, dgs);
    k_gather_mol<<<N_MOL / 8, 256, 0, stream>>>(B2, dinv, mo_b2, csr2, rowStart, molf, MOFF);
    k_pool_seg_f<<<BATCH, 128, 0, stream>>>(molf, mol_b, mpool);

    // ---- head ----
    hipMemsetAsync(hstat, 0, 64 * 4, stream);
    k_conv1<<<BATCH, 64, 0, stream>>>(dgs, mpool, c1_W, c1_b, y1);
    k_head_stats<<<dim3(6, BATCH / 256), 256, 0, stream>>>(y1, hstat, 0, 64);
    k_bn_fin<<<1, 8, 0, stream>>>(hstat, 0, 1.0f / (BATCH * 64.0f));
    k_conv2<<<BATCH, 64, 0, stream>>>(y1, hstat, c1_g, c1_be, c2_W, c2_b, y2);
    k_head_stats<<<dim3(6, BATCH / 256), 256, 0, stream>>>(y2, hstat, 1, 32);
    k_bn_fin<<<1, 8, 0, stream>>>(hstat, 1, 1.0f / (BATCH * 32.0f));
    k_head<<<BATCH, 128, 0, stream>>>(y2, hstat, c2_g, c2_be, l1_W, l1_b, l2_W, l2_b, out);
}